// Round 2
// baseline (7934.221 us; speedup 1.0000x reference)
//
#include <hip/hip_runtime.h>

#define N_NODES 10000
#define H_DIM   128
#define E_EDGES 160000
#define R_DIM   32
#define IN_DIM  34

__device__ __forceinline__ float silu_f(float z) {
    return z / (1.0f + __expf(-z));
}

// ---------------------------------------------------------------------------
// Kernel 1: per-node prep.
// Xn = X/(||X||^2+1); decompose -> 9 comps [I, a0,a1,a2, s00,s01,s02,s11,s12];
// channel-mix with Wt0 (I), Wt1 (A), Wt2 (S); write Y comps to [N][H][12].
// 4 nodes per 256-thread block.
// ---------------------------------------------------------------------------
__global__ __launch_bounds__(256) void k_prep(
    const float* __restrict__ X,
    const float* __restrict__ Wt0, const float* __restrict__ Wt1,
    const float* __restrict__ Wt2,
    float* __restrict__ Y)
{
    __shared__ __align__(16) float dec[4 * 128 * 12];
    const int n0  = blockIdx.x * 4;
    const int tid = threadIdx.x;

    for (int idx = tid; idx < 512; idx += 256) {
        const int nl = idx >> 7, h = idx & 127;
        const float* t = X + ((size_t)((n0 + nl) * H_DIM + h)) * 9;
        float T[9];
#pragma unroll
        for (int i = 0; i < 9; i++) T[i] = t[i];
        float nrm = 0.f;
#pragma unroll
        for (int i = 0; i < 9; i++) nrm = fmaf(T[i], T[i], nrm);
        const float inv = 1.0f / (nrm + 1.0f);
#pragma unroll
        for (int i = 0; i < 9; i++) T[i] *= inv;
        const float I = (T[0] + T[4] + T[8]) * (1.0f / 3.0f);
        float* d = dec + idx * 12;
        d[0] = I;
        d[1] = 0.5f * (T[7] - T[5]);   // a0 = A21
        d[2] = 0.5f * (T[2] - T[6]);   // a1 = A02
        d[3] = 0.5f * (T[3] - T[1]);   // a2 = A10
        d[4] = T[0] - I;               // s00
        d[5] = 0.5f * (T[1] + T[3]);   // s01
        d[6] = 0.5f * (T[2] + T[6]);   // s02
        d[7] = T[4] - I;               // s11
        d[8] = 0.5f * (T[5] + T[7]);   // s12
    }
    __syncthreads();

    for (int idx = tid; idx < 512; idx += 256) {
        const int nl = idx >> 7, o = idx & 127;
        float acc[9];
#pragma unroll
        for (int c = 0; c < 9; c++) acc[c] = 0.f;
        const float* d = dec + nl * 128 * 12;
#pragma unroll 4
        for (int h = 0; h < 128; h++) {
            const float w0 = Wt0[o * 128 + h];
            const float w1 = Wt1[o * 128 + h];
            const float w2 = Wt2[o * 128 + h];
            const float* dh = d + h * 12;
            acc[0] = fmaf(dh[0], w0, acc[0]);
            acc[1] = fmaf(dh[1], w1, acc[1]);
            acc[2] = fmaf(dh[2], w1, acc[2]);
            acc[3] = fmaf(dh[3], w1, acc[3]);
            acc[4] = fmaf(dh[4], w2, acc[4]);
            acc[5] = fmaf(dh[5], w2, acc[5]);
            acc[6] = fmaf(dh[6], w2, acc[6]);
            acc[7] = fmaf(dh[7], w2, acc[7]);
            acc[8] = fmaf(dh[8], w2, acc[8]);
        }
        float* y = Y + ((size_t)((n0 + nl) * H_DIM + o)) * 12;
#pragma unroll
        for (int c = 0; c < 9; c++) y[c] = acc[c];
    }
}

// ---------------------------------------------------------------------------
// Kernel 2: fused edge MLP + message passing. 32 edges per 256-thread block.
// ---------------------------------------------------------------------------
__global__ __launch_bounds__(256) void k_edge(
    const float* __restrict__ EA, const float* __restrict__ CH,
    const float* __restrict__ EW, const int*   __restrict__ EI,
    const float* __restrict__ W1, const float* __restrict__ b1,
    const float* __restrict__ W2, const float* __restrict__ b2,
    const float* __restrict__ W3, const float* __restrict__ b3,
    const float* __restrict__ Y,  float* __restrict__ MSG)
{
    __shared__ __align__(16) float sIn[32 * 35];
    __shared__ __align__(16) float sH1[32 * 132];
    __shared__ __align__(16) float sH2[32 * 260];
    __shared__ __align__(16) float sXc[32 * 132];
    __shared__ float sC[32];
    __shared__ int   sS[32], sD[32];

    const int e0  = blockIdx.x * 32;
    const int tid = threadIdx.x;

    {   // edge_attr: 32 edges x 32 floats, contiguous -> one float4 per thread
        const float4 v = ((const float4*)(EA + (size_t)e0 * R_DIM))[tid];
        const int e = tid >> 3;
        const int k = (tid & 7) * 4;
        float* p = sIn + e * 35 + k;
        p[0] = v.x; p[1] = v.y; p[2] = v.z; p[3] = v.w;
    }
    if (tid < 32) {
        const int e = tid;
        const int s = EI[e0 + e];
        const int d = EI[E_EDGES + e0 + e];
        sS[e] = s; sD[e] = d;
        sIn[e * 35 + 32] = CH[s];
        sIn[e * 35 + 33] = CH[d];
        const float w = EW[e0 + e];
        sC[e] = (w < 5.0f) ? 0.5f * (__cosf(0.62831853071795864769f * w) + 1.0f)
                           : 0.0f;
    }
    __syncthreads();

    const int e  = tid & 31;
    const int og = tid >> 5;   // 8 output groups

    // ---- layer 1: 34 -> 128 (16 outputs/thread) ----
    {
        float acc[16];
#pragma unroll
        for (int j = 0; j < 16; j++) acc[j] = b1[og * 16 + j];
        for (int k = 0; k < IN_DIM; k++) {
            const float v = sIn[e * 35 + k];
#pragma unroll
            for (int j = 0; j < 16; j++)
                acc[j] = fmaf(v, W1[(og * 16 + j) * IN_DIM + k], acc[j]);
        }
#pragma unroll
        for (int j = 0; j < 16; j++)
            sH1[e * 132 + og * 16 + j] = silu_f(acc[j]);
    }
    __syncthreads();

    // ---- layer 2: 128 -> 256 (32 outputs/thread) ----
    {
        float acc[32];
#pragma unroll
        for (int j = 0; j < 32; j++) acc[j] = b2[og * 32 + j];
        for (int hq = 0; hq < 32; hq++) {
            const float4 v = *(const float4*)&sH1[e * 132 + hq * 4];
#pragma unroll
            for (int j = 0; j < 32; j++) {
                const float4 w =
                    *(const float4*)&W2[(size_t)(og * 32 + j) * 128 + hq * 4];
                acc[j] = fmaf(v.x, w.x,
                         fmaf(v.y, w.y,
                         fmaf(v.z, w.z,
                         fmaf(v.w, w.w, acc[j]))));
            }
        }
#pragma unroll
        for (int j = 0; j < 32; j++)
            sH2[e * 260 + og * 32 + j] = silu_f(acc[j]);
    }
    __syncthreads();

    // ---- layer 3 (per class) + message passing ----
    for (int c = 0; c < 3; c++) {
        {
            float acc[16];
#pragma unroll
            for (int j = 0; j < 16; j++) acc[j] = b3[c * 128 + og * 16 + j];
            for (int hq = 0; hq < 64; hq++) {
                const float4 v = *(const float4*)&sH2[e * 260 + hq * 4];
#pragma unroll
                for (int j = 0; j < 16; j++) {
                    const float4 w = *(const float4*)
                        &W3[(size_t)(c * 128 + og * 16 + j) * 256 + hq * 4];
                    acc[j] = fmaf(v.x, w.x,
                             fmaf(v.y, w.y,
                             fmaf(v.z, w.z,
                             fmaf(v.w, w.w, acc[j]))));
                }
            }
            const float cc = sC[e];
#pragma unroll
            for (int j = 0; j < 16; j++)
                sXc[e * 132 + og * 16 + j] = silu_f(acc[j]) * cc;
        }
        __syncthreads();
        {
            const int h  = tid & 127;
            const int eh = tid >> 7;
#pragma unroll 4
            for (int i = 0; i < 16; i++) {
                const int ee = (eh << 4) | i;
                const int s = sS[ee], d = sD[ee];
                const float xv = sXc[ee * 132 + h];
                const float* yb = Y   + ((size_t)(d * H_DIM + h)) * 12;
                float*       mb = MSG + ((size_t)(s * H_DIM + h)) * 12;
                if (c == 0) {
                    atomicAdd(mb + 0, xv * yb[0]);
                } else if (c == 1) {
                    atomicAdd(mb + 1, xv * yb[1]);
                    atomicAdd(mb + 2, xv * yb[2]);
                    atomicAdd(mb + 3, xv * yb[3]);
                } else {
                    atomicAdd(mb + 4, xv * yb[4]);
                    atomicAdd(mb + 5, xv * yb[5]);
                    atomicAdd(mb + 6, xv * yb[6]);
                    atomicAdd(mb + 7, xv * yb[7]);
                    atomicAdd(mb + 8, xv * yb[8]);
                }
            }
        }
        __syncthreads();
    }
}

// ---------------------------------------------------------------------------
// Kernel 3: per-node finish.
// M = msg*Y + Y*msg; decompose; /(norm+1); mix Wt3/4/5; out = Xn + dX + dX*dX.
// ---------------------------------------------------------------------------
__global__ __launch_bounds__(256) void k_finish(
    const float* __restrict__ X,
    const float* __restrict__ Y, const float* __restrict__ MSG,
    const float* __restrict__ Wt3, const float* __restrict__ Wt4,
    const float* __restrict__ Wt5,
    float* __restrict__ out)
{
    __shared__ __align__(16) float dec[4 * 128 * 12];
    const int n0  = blockIdx.x * 4;
    const int tid = threadIdx.x;

    for (int idx = tid; idx < 512; idx += 256) {
        const size_t base =
            ((size_t)((n0 + (idx >> 7)) * H_DIM + (idx & 127))) * 12;
        const float* y = Y + base;
        const float* m = MSG + base;
        float Yt[9], G[9];
        {
            const float I = y[0], a0 = y[1], a1 = y[2], a2 = y[3];
            const float s00 = y[4], s01 = y[5], s02 = y[6], s11 = y[7], s12 = y[8];
            const float s22 = -s00 - s11;
            Yt[0] = I + s00; Yt[1] = s01 - a2; Yt[2] = s02 + a1;
            Yt[3] = s01 + a2; Yt[4] = I + s11; Yt[5] = s12 - a0;
            Yt[6] = s02 - a1; Yt[7] = s12 + a0; Yt[8] = I + s22;
        }
        {
            const float I = m[0], a0 = m[1], a1 = m[2], a2 = m[3];
            const float s00 = m[4], s01 = m[5], s02 = m[6], s11 = m[7], s12 = m[8];
            const float s22 = -s00 - s11;
            G[0] = I + s00; G[1] = s01 - a2; G[2] = s02 + a1;
            G[3] = s01 + a2; G[4] = I + s11; G[5] = s12 - a0;
            G[6] = s02 - a1; G[7] = s12 + a0; G[8] = I + s22;
        }
        float M[9];
#pragma unroll
        for (int i = 0; i < 3; i++)
#pragma unroll
            for (int j = 0; j < 3; j++) {
                float acc = 0.f;
#pragma unroll
                for (int k = 0; k < 3; k++)
                    acc += G[i * 3 + k] * Yt[k * 3 + j]
                         + Yt[i * 3 + k] * G[k * 3 + j];
                M[i * 3 + j] = acc;
            }
        const float I2 = (M[0] + M[4] + M[8]) * (1.0f / 3.0f);
        const float a0 = 0.5f * (M[7] - M[5]);
        const float a1 = 0.5f * (M[2] - M[6]);
        const float a2 = 0.5f * (M[3] - M[1]);
        const float s00 = M[0] - I2, s11 = M[4] - I2;
        const float s01 = 0.5f * (M[1] + M[3]);
        const float s02 = 0.5f * (M[2] + M[6]);
        const float s12 = 0.5f * (M[5] + M[7]);
        const float s22 = -s00 - s11;
        const float nrm = 2.f * (a0 * a0 + a1 * a1 + a2 * a2)
                        + (s00 * s00 + s11 * s11 + s22 * s22)
                        + 2.f * (s01 * s01 + s02 * s02 + s12 * s12)
                        + 3.f * I2 * I2;
        const float inv = 1.0f / (nrm + 1.0f);
        float* dd = dec + idx * 12;
        dd[0] = I2 * inv;  dd[1] = a0 * inv;  dd[2] = a1 * inv;  dd[3] = a2 * inv;
        dd[4] = s00 * inv; dd[5] = s01 * inv; dd[6] = s02 * inv;
        dd[7] = s11 * inv; dd[8] = s12 * inv;
    }
    __syncthreads();

    for (int idx = tid; idx < 512; idx += 256) {
        const int nl = idx >> 7, o = idx & 127;
        float acc[9];
#pragma unroll
        for (int c = 0; c < 9; c++) acc[c] = 0.f;
        const float* d = dec + nl * 128 * 12;
#pragma unroll 4
        for (int h = 0; h < 128; h++) {
            const float w3 = Wt3[o * 128 + h];
            const float w4 = Wt4[o * 128 + h];
            const float w5 = Wt5[o * 128 + h];
            const float* dh = d + h * 12;
            acc[0] = fmaf(dh[0], w3, acc[0]);
            acc[1] = fmaf(dh[1], w4, acc[1]);
            acc[2] = fmaf(dh[2], w4, acc[2]);
            acc[3] = fmaf(dh[3], w4, acc[3]);
            acc[4] = fmaf(dh[4], w5, acc[4]);
            acc[5] = fmaf(dh[5], w5, acc[5]);
            acc[6] = fmaf(dh[6], w5, acc[6]);
            acc[7] = fmaf(dh[7], w5, acc[7]);
            acc[8] = fmaf(dh[8], w5, acc[8]);
        }
        float D[9];
        {
            const float I = acc[0], a0 = acc[1], a1 = acc[2], a2 = acc[3];
            const float s00 = acc[4], s01 = acc[5], s02 = acc[6];
            const float s11 = acc[7], s12 = acc[8];
            const float s22 = -s00 - s11;
            D[0] = I + s00; D[1] = s01 - a2; D[2] = s02 + a1;
            D[3] = s01 + a2; D[4] = I + s11; D[5] = s12 - a0;
            D[6] = s02 - a1; D[7] = s12 + a0; D[8] = I + s22;
        }
        const size_t xbase = ((size_t)((n0 + nl) * H_DIM + o)) * 9;
        float T[9];
#pragma unroll
        for (int i = 0; i < 9; i++) T[i] = X[xbase + i];
        float nrm = 0.f;
#pragma unroll
        for (int i = 0; i < 9; i++) nrm = fmaf(T[i], T[i], nrm);
        const float inv = 1.0f / (nrm + 1.0f);
        float* op = out + xbase;
#pragma unroll
        for (int i = 0; i < 3; i++)
#pragma unroll
            for (int j = 0; j < 3; j++) {
                float dd2 = 0.f;
#pragma unroll
                for (int k = 0; k < 3; k++)
                    dd2 = fmaf(D[i * 3 + k], D[k * 3 + j], dd2);
                op[i * 3 + j] = T[i * 3 + j] * inv + D[i * 3 + j] + dd2;
            }
    }
}

// ---------------------------------------------------------------------------
extern "C" void kernel_launch(void* const* d_in, const int* in_sizes, int n_in,
                              void* d_out, int out_size, void* d_ws, size_t ws_size,
                              hipStream_t stream)
{
    const float* X   = (const float*)d_in[0];
    const float* CH  = (const float*)d_in[1];
    const float* EA  = (const float*)d_in[2];
    const float* EW  = (const float*)d_in[3];
    const float* W1  = (const float*)d_in[4];
    const float* b1  = (const float*)d_in[5];
    const float* W2  = (const float*)d_in[6];
    const float* b2  = (const float*)d_in[7];
    const float* W3  = (const float*)d_in[8];
    const float* b3  = (const float*)d_in[9];
    const float* Wt0 = (const float*)d_in[10];
    const float* Wt1 = (const float*)d_in[11];
    const float* Wt2 = (const float*)d_in[12];
    const float* Wt3 = (const float*)d_in[13];
    const float* Wt4 = (const float*)d_in[14];
    const float* Wt5 = (const float*)d_in[15];
    const int*   EI  = (const int*)d_in[16];
    float* out = (float*)d_out;

    float* Ybuf = (float*)d_ws;                       // [N][H][12]
    float* MSG  = Ybuf + (size_t)N_NODES * H_DIM * 12; // [N][H][12]

    hipMemsetAsync(MSG, 0, (size_t)N_NODES * H_DIM * 12 * sizeof(float), stream);

    k_prep<<<N_NODES / 4, 256, 0, stream>>>(X, Wt0, Wt1, Wt2, Ybuf);
    k_edge<<<E_EDGES / 32, 256, 0, stream>>>(EA, CH, EW, EI,
                                             W1, b1, W2, b2, W3, b3,
                                             Ybuf, MSG);
    k_finish<<<N_NODES / 4, 256, 0, stream>>>(X, Ybuf, MSG,
                                              Wt3, Wt4, Wt5, out);
}

// Round 3
// 3377.427 us; speedup vs baseline: 2.3492x; 2.3492x over previous
//
#include <hip/hip_runtime.h>
#include <hip/hip_bf16.h>

#define NN  10000
#define HD  128
#define EE  160000
#define RD  32
#define IND 34
#define NH  (NN * HD)

__device__ __forceinline__ float silu_f(float z) {
    return z / (1.0f + __expf(-z));
}

__device__ __forceinline__ void  xc_st(float* p, float v)            { *p = v; }
__device__ __forceinline__ void  xc_st(__hip_bfloat16* p, float v)   { *p = __float2bfloat16(v); }
__device__ __forceinline__ float xc_ld(const float* p)               { return *p; }
__device__ __forceinline__ float xc_ld(const __hip_bfloat16* p)      { return __bfloat162float(*p); }

// ---------------------------------------------------------------------------
// Kernel 1: per-node prep.  Y layout comp-major: [9][N*H].
// ---------------------------------------------------------------------------
__global__ __launch_bounds__(256) void k_prep(
    const float* __restrict__ X,
    const float* __restrict__ Wt0, const float* __restrict__ Wt1,
    const float* __restrict__ Wt2,
    float* __restrict__ Y)
{
    __shared__ __align__(16) float dec[4 * 128 * 12];
    const int n0  = blockIdx.x * 4;
    const int tid = threadIdx.x;

    for (int idx = tid; idx < 512; idx += 256) {
        const int nl = idx >> 7, h = idx & 127;
        const float* t = X + ((size_t)((n0 + nl) * HD + h)) * 9;
        float T[9];
#pragma unroll
        for (int i = 0; i < 9; i++) T[i] = t[i];
        float nrm = 0.f;
#pragma unroll
        for (int i = 0; i < 9; i++) nrm = fmaf(T[i], T[i], nrm);
        const float inv = 1.0f / (nrm + 1.0f);
#pragma unroll
        for (int i = 0; i < 9; i++) T[i] *= inv;
        const float I = (T[0] + T[4] + T[8]) * (1.0f / 3.0f);
        float* d = dec + idx * 12;
        d[0] = I;
        d[1] = 0.5f * (T[7] - T[5]);   // a0
        d[2] = 0.5f * (T[2] - T[6]);   // a1
        d[3] = 0.5f * (T[3] - T[1]);   // a2
        d[4] = T[0] - I;               // s00
        d[5] = 0.5f * (T[1] + T[3]);   // s01
        d[6] = 0.5f * (T[2] + T[6]);   // s02
        d[7] = T[4] - I;               // s11
        d[8] = 0.5f * (T[5] + T[7]);   // s12
    }
    __syncthreads();

    for (int idx = tid; idx < 512; idx += 256) {
        const int nl = idx >> 7, o = idx & 127;
        float acc[9];
#pragma unroll
        for (int c = 0; c < 9; c++) acc[c] = 0.f;
        const float* d = dec + nl * 128 * 12;
#pragma unroll 4
        for (int h = 0; h < 128; h++) {
            const float w0 = Wt0[o * 128 + h];
            const float w1 = Wt1[o * 128 + h];
            const float w2 = Wt2[o * 128 + h];
            const float* dh = d + h * 12;
            acc[0] = fmaf(dh[0], w0, acc[0]);
            acc[1] = fmaf(dh[1], w1, acc[1]);
            acc[2] = fmaf(dh[2], w1, acc[2]);
            acc[3] = fmaf(dh[3], w1, acc[3]);
            acc[4] = fmaf(dh[4], w2, acc[4]);
            acc[5] = fmaf(dh[5], w2, acc[5]);
            acc[6] = fmaf(dh[6], w2, acc[6]);
            acc[7] = fmaf(dh[7], w2, acc[7]);
            acc[8] = fmaf(dh[8], w2, acc[8]);
        }
        const int base = (n0 + nl) * HD + o;
#pragma unroll
        for (int c = 0; c < 9; c++) Y[(size_t)c * NH + base] = acc[c];
    }
}

// ---------------------------------------------------------------------------
// CSR build: histogram -> scan -> fill (edge ids grouped by src).
// ---------------------------------------------------------------------------
__global__ __launch_bounds__(256) void k_count(const int* __restrict__ EI,
                                               int* __restrict__ cnt)
{
    const int e = blockIdx.x * 256 + threadIdx.x;
    atomicAdd(&cnt[EI[e]], 1);
}

__global__ __launch_bounds__(256) void k_scan(const int* __restrict__ cnt,
                                              int* __restrict__ offs,
                                              int* __restrict__ cur)
{
    __shared__ int part[256];
    const int tid = threadIdx.x;
    const int per = (NN + 255) / 256;   // 40
    int s = 0;
    for (int i = 0; i < per; i++) {
        const int idx = tid * per + i;
        if (idx < NN) s += cnt[idx];
    }
    part[tid] = s;
    __syncthreads();
    if (tid == 0) {
        int r = 0;
        for (int i = 0; i < 256; i++) { const int t = part[i]; part[i] = r; r += t; }
        offs[NN] = r;
    }
    __syncthreads();
    int run = part[tid];
    for (int i = 0; i < per; i++) {
        const int idx = tid * per + i;
        if (idx < NN) {
            offs[idx] = run;
            cur[idx]  = run;
            run += cnt[idx];
        }
    }
}

__global__ __launch_bounds__(256) void k_fill(const int* __restrict__ EI,
                                              int* __restrict__ cur,
                                              int* __restrict__ EIDS,
                                              int* __restrict__ DSTS)
{
    const int e = blockIdx.x * 256 + threadIdx.x;
    const int s = EI[e];
    const int pos = atomicAdd(&cur[s], 1);
    EIDS[pos] = e;
    DSTS[pos] = EI[EE + e];
}

// ---------------------------------------------------------------------------
// Kernel 2: fused edge MLP.  32 edges / 256-thread block.
// USE_XC: write per-edge outputs XC[e][3][128] (no atomics).
// !USE_XC: fallback atomic scatter into MSG[9][N*H].
// ---------------------------------------------------------------------------
template <typename XCT, bool USE_XC>
__global__ __launch_bounds__(256) void k_edge(
    const float* __restrict__ EA, const float* __restrict__ CH,
    const float* __restrict__ EW, const int*   __restrict__ EI,
    const float* __restrict__ W1, const float* __restrict__ b1,
    const float* __restrict__ W2, const float* __restrict__ b2,
    const float* __restrict__ W3, const float* __restrict__ b3,
    const float* __restrict__ Y,  XCT* __restrict__ XC,
    float* __restrict__ MSG)
{
    __shared__ __align__(16) float sIn[32 * 35];
    __shared__ __align__(16) float sH1[32 * 132];
    __shared__ __align__(16) float sH2[32 * 260];
    __shared__ __align__(16) float sXc[32 * 132];
    __shared__ float sC[32];
    __shared__ int   sS[32], sD[32];

    const int e0  = blockIdx.x * 32;
    const int tid = threadIdx.x;

    {
        const float4 v = ((const float4*)(EA + (size_t)e0 * RD))[tid];
        const int e = tid >> 3;
        const int k = (tid & 7) * 4;
        float* p = sIn + e * 35 + k;
        p[0] = v.x; p[1] = v.y; p[2] = v.z; p[3] = v.w;
    }
    if (tid < 32) {
        const int e = tid;
        const int s = EI[e0 + e];
        const int d = EI[EE + e0 + e];
        sS[e] = s; sD[e] = d;
        sIn[e * 35 + 32] = CH[s];
        sIn[e * 35 + 33] = CH[d];
        const float w = EW[e0 + e];
        sC[e] = (w < 5.0f) ? 0.5f * (__cosf(0.62831853071795864769f * w) + 1.0f)
                           : 0.0f;
    }
    __syncthreads();

    const int e  = tid & 31;
    const int og = tid >> 5;

    // ---- layer 1: 34 -> 128 ----
    {
        float acc[16];
#pragma unroll
        for (int j = 0; j < 16; j++) acc[j] = b1[og * 16 + j];
        for (int k = 0; k < IND; k++) {
            const float v = sIn[e * 35 + k];
#pragma unroll
            for (int j = 0; j < 16; j++)
                acc[j] = fmaf(v, W1[(og * 16 + j) * IND + k], acc[j]);
        }
#pragma unroll
        for (int j = 0; j < 16; j++)
            sH1[e * 132 + og * 16 + j] = silu_f(acc[j]);
    }
    __syncthreads();

    // ---- layer 2: 128 -> 256 ----
    {
        float acc[32];
#pragma unroll
        for (int j = 0; j < 32; j++) acc[j] = b2[og * 32 + j];
        for (int hq = 0; hq < 32; hq++) {
            const float4 v = *(const float4*)&sH1[e * 132 + hq * 4];
#pragma unroll
            for (int j = 0; j < 32; j++) {
                const float4 w =
                    *(const float4*)&W2[(size_t)(og * 32 + j) * 128 + hq * 4];
                acc[j] = fmaf(v.x, w.x,
                         fmaf(v.y, w.y,
                         fmaf(v.z, w.z,
                         fmaf(v.w, w.w, acc[j]))));
            }
        }
#pragma unroll
        for (int j = 0; j < 32; j++)
            sH2[e * 260 + og * 32 + j] = silu_f(acc[j]);
    }
    __syncthreads();

    // ---- layer 3 (3 classes) ----
    for (int c = 0; c < 3; c++) {
        {
            float acc[16];
#pragma unroll
            for (int j = 0; j < 16; j++) acc[j] = b3[c * 128 + og * 16 + j];
            for (int hq = 0; hq < 64; hq++) {
                const float4 v = *(const float4*)&sH2[e * 260 + hq * 4];
#pragma unroll
                for (int j = 0; j < 16; j++) {
                    const float4 w = *(const float4*)
                        &W3[(size_t)(c * 128 + og * 16 + j) * 256 + hq * 4];
                    acc[j] = fmaf(v.x, w.x,
                             fmaf(v.y, w.y,
                             fmaf(v.z, w.z,
                             fmaf(v.w, w.w, acc[j]))));
                }
            }
            const float cc = sC[e];
#pragma unroll
            for (int j = 0; j < 16; j++)
                sXc[e * 132 + og * 16 + j] = silu_f(acc[j]) * cc;
        }
        __syncthreads();

        if constexpr (USE_XC) {
            // coalesced write XC[(e0+ee)][c][h]
            for (int i = tid; i < 4096; i += 256) {
                const int ee = i >> 7, hh = i & 127;
                xc_st(XC + ((size_t)(e0 + ee) * 384 + c * 128 + hh),
                      sXc[ee * 132 + hh]);
            }
        } else {
            const int h  = tid & 127;
            const int eh = tid >> 7;
#pragma unroll 4
            for (int i = 0; i < 16; i++) {
                const int ee = (eh << 4) | i;
                const int s = sS[ee], d = sD[ee];
                const float xv = sXc[ee * 132 + h];
                const int sb = s * HD + h, db = d * HD + h;
                if (c == 0) {
                    atomicAdd(&MSG[0 * (size_t)NH + sb], xv * Y[0 * (size_t)NH + db]);
                } else if (c == 1) {
                    atomicAdd(&MSG[1 * (size_t)NH + sb], xv * Y[1 * (size_t)NH + db]);
                    atomicAdd(&MSG[2 * (size_t)NH + sb], xv * Y[2 * (size_t)NH + db]);
                    atomicAdd(&MSG[3 * (size_t)NH + sb], xv * Y[3 * (size_t)NH + db]);
                } else {
#pragma unroll
                    for (int cc2 = 4; cc2 < 9; cc2++)
                        atomicAdd(&MSG[(size_t)cc2 * NH + sb],
                                  xv * Y[(size_t)cc2 * NH + db]);
                }
            }
        }
        __syncthreads();
    }
}

// ---------------------------------------------------------------------------
// Kernel 2b: node-major gather (no atomics).  2 nodes / block, thread = (nl,h).
// ---------------------------------------------------------------------------
template <typename XCT>
__global__ __launch_bounds__(256) void k_gather(
    const XCT* __restrict__ XC, const float* __restrict__ Y,
    const int* __restrict__ offs, const int* __restrict__ EIDS,
    const int* __restrict__ DSTS, float* __restrict__ MSG)
{
    const int tid = threadIdx.x;
    const int nl  = tid >> 7, h = tid & 127;
    const int n   = blockIdx.x * 2 + nl;
    const int beg = offs[n], end = offs[n + 1];

    float m[9];
#pragma unroll
    for (int c = 0; c < 9; c++) m[c] = 0.f;

    for (int p = beg; p < end; ++p) {
        const int eid = EIDS[p];
        const int dst = DSTS[p];
        const size_t xb = (size_t)eid * 384;
        const float x0 = xc_ld(XC + xb + h);
        const float x1 = xc_ld(XC + xb + 128 + h);
        const float x2 = xc_ld(XC + xb + 256 + h);
        const int yb = dst * HD + h;
        m[0] = fmaf(x0, Y[0 * (size_t)NH + yb], m[0]);
        m[1] = fmaf(x1, Y[1 * (size_t)NH + yb], m[1]);
        m[2] = fmaf(x1, Y[2 * (size_t)NH + yb], m[2]);
        m[3] = fmaf(x1, Y[3 * (size_t)NH + yb], m[3]);
        m[4] = fmaf(x2, Y[4 * (size_t)NH + yb], m[4]);
        m[5] = fmaf(x2, Y[5 * (size_t)NH + yb], m[5]);
        m[6] = fmaf(x2, Y[6 * (size_t)NH + yb], m[6]);
        m[7] = fmaf(x2, Y[7 * (size_t)NH + yb], m[7]);
        m[8] = fmaf(x2, Y[8 * (size_t)NH + yb], m[8]);
    }
    const int base = n * HD + h;
#pragma unroll
    for (int c = 0; c < 9; c++) MSG[(size_t)c * NH + base] = m[c];
}

// ---------------------------------------------------------------------------
// Kernel 3: per-node finish.
// ---------------------------------------------------------------------------
__global__ __launch_bounds__(256) void k_finish(
    const float* __restrict__ X,
    const float* __restrict__ Y, const float* __restrict__ MSG,
    const float* __restrict__ Wt3, const float* __restrict__ Wt4,
    const float* __restrict__ Wt5,
    float* __restrict__ out)
{
    __shared__ __align__(16) float dec[4 * 128 * 12];
    const int n0  = blockIdx.x * 4;
    const int tid = threadIdx.x;

    for (int idx = tid; idx < 512; idx += 256) {
        const int nl = idx >> 7, h = idx & 127;
        const int base = (n0 + nl) * HD + h;
        float yv[9], mv[9];
#pragma unroll
        for (int c = 0; c < 9; c++) {
            yv[c] = Y[(size_t)c * NH + base];
            mv[c] = MSG[(size_t)c * NH + base];
        }
        float Yt[9], G[9];
        {
            const float I = yv[0], a0 = yv[1], a1 = yv[2], a2 = yv[3];
            const float s00 = yv[4], s01 = yv[5], s02 = yv[6], s11 = yv[7], s12 = yv[8];
            const float s22 = -s00 - s11;
            Yt[0] = I + s00; Yt[1] = s01 - a2; Yt[2] = s02 + a1;
            Yt[3] = s01 + a2; Yt[4] = I + s11; Yt[5] = s12 - a0;
            Yt[6] = s02 - a1; Yt[7] = s12 + a0; Yt[8] = I + s22;
        }
        {
            const float I = mv[0], a0 = mv[1], a1 = mv[2], a2 = mv[3];
            const float s00 = mv[4], s01 = mv[5], s02 = mv[6], s11 = mv[7], s12 = mv[8];
            const float s22 = -s00 - s11;
            G[0] = I + s00; G[1] = s01 - a2; G[2] = s02 + a1;
            G[3] = s01 + a2; G[4] = I + s11; G[5] = s12 - a0;
            G[6] = s02 - a1; G[7] = s12 + a0; G[8] = I + s22;
        }
        float M[9];
#pragma unroll
        for (int i = 0; i < 3; i++)
#pragma unroll
            for (int j = 0; j < 3; j++) {
                float acc = 0.f;
#pragma unroll
                for (int k = 0; k < 3; k++)
                    acc += G[i * 3 + k] * Yt[k * 3 + j]
                         + Yt[i * 3 + k] * G[k * 3 + j];
                M[i * 3 + j] = acc;
            }
        const float I2 = (M[0] + M[4] + M[8]) * (1.0f / 3.0f);
        const float a0 = 0.5f * (M[7] - M[5]);
        const float a1 = 0.5f * (M[2] - M[6]);
        const float a2 = 0.5f * (M[3] - M[1]);
        const float s00 = M[0] - I2, s11 = M[4] - I2;
        const float s01 = 0.5f * (M[1] + M[3]);
        const float s02 = 0.5f * (M[2] + M[6]);
        const float s12 = 0.5f * (M[5] + M[7]);
        const float s22 = -s00 - s11;
        const float nrm = 2.f * (a0 * a0 + a1 * a1 + a2 * a2)
                        + (s00 * s00 + s11 * s11 + s22 * s22)
                        + 2.f * (s01 * s01 + s02 * s02 + s12 * s12)
                        + 3.f * I2 * I2;
        const float inv = 1.0f / (nrm + 1.0f);
        float* dd = dec + idx * 12;
        dd[0] = I2 * inv;  dd[1] = a0 * inv;  dd[2] = a1 * inv;  dd[3] = a2 * inv;
        dd[4] = s00 * inv; dd[5] = s01 * inv; dd[6] = s02 * inv;
        dd[7] = s11 * inv; dd[8] = s12 * inv;
    }
    __syncthreads();

    for (int idx = tid; idx < 512; idx += 256) {
        const int nl = idx >> 7, o = idx & 127;
        float acc[9];
#pragma unroll
        for (int c = 0; c < 9; c++) acc[c] = 0.f;
        const float* d = dec + nl * 128 * 12;
#pragma unroll 4
        for (int h = 0; h < 128; h++) {
            const float w3 = Wt3[o * 128 + h];
            const float w4 = Wt4[o * 128 + h];
            const float w5 = Wt5[o * 128 + h];
            const float* dh = d + h * 12;
            acc[0] = fmaf(dh[0], w3, acc[0]);
            acc[1] = fmaf(dh[1], w4, acc[1]);
            acc[2] = fmaf(dh[2], w4, acc[2]);
            acc[3] = fmaf(dh[3], w4, acc[3]);
            acc[4] = fmaf(dh[4], w5, acc[4]);
            acc[5] = fmaf(dh[5], w5, acc[5]);
            acc[6] = fmaf(dh[6], w5, acc[6]);
            acc[7] = fmaf(dh[7], w5, acc[7]);
            acc[8] = fmaf(dh[8], w5, acc[8]);
        }
        float D[9];
        {
            const float I = acc[0], a0 = acc[1], a1 = acc[2], a2 = acc[3];
            const float s00 = acc[4], s01 = acc[5], s02 = acc[6];
            const float s11 = acc[7], s12 = acc[8];
            const float s22 = -s00 - s11;
            D[0] = I + s00; D[1] = s01 - a2; D[2] = s02 + a1;
            D[3] = s01 + a2; D[4] = I + s11; D[5] = s12 - a0;
            D[6] = s02 - a1; D[7] = s12 + a0; D[8] = I + s22;
        }
        const size_t xbase = ((size_t)((n0 + nl) * HD + o)) * 9;
        float T[9];
#pragma unroll
        for (int i = 0; i < 9; i++) T[i] = X[xbase + i];
        float nrm = 0.f;
#pragma unroll
        for (int i = 0; i < 9; i++) nrm = fmaf(T[i], T[i], nrm);
        const float inv = 1.0f / (nrm + 1.0f);
        float* op = out + xbase;
#pragma unroll
        for (int i = 0; i < 3; i++)
#pragma unroll
            for (int j = 0; j < 3; j++) {
                float dd2 = 0.f;
#pragma unroll
                for (int k = 0; k < 3; k++)
                    dd2 = fmaf(D[i * 3 + k], D[k * 3 + j], dd2);
                op[i * 3 + j] = T[i * 3 + j] * inv + D[i * 3 + j] + dd2;
            }
    }
}

// ---------------------------------------------------------------------------
extern "C" void kernel_launch(void* const* d_in, const int* in_sizes, int n_in,
                              void* d_out, int out_size, void* d_ws, size_t ws_size,
                              hipStream_t stream)
{
    const float* X   = (const float*)d_in[0];
    const float* CH  = (const float*)d_in[1];
    const float* EA  = (const float*)d_in[2];
    const float* EW  = (const float*)d_in[3];
    const float* W1  = (const float*)d_in[4];
    const float* b1  = (const float*)d_in[5];
    const float* W2  = (const float*)d_in[6];
    const float* b2  = (const float*)d_in[7];
    const float* W3  = (const float*)d_in[8];
    const float* b3  = (const float*)d_in[9];
    const float* Wt0 = (const float*)d_in[10];
    const float* Wt1 = (const float*)d_in[11];
    const float* Wt2 = (const float*)d_in[12];
    const float* Wt3 = (const float*)d_in[13];
    const float* Wt4 = (const float*)d_in[14];
    const float* Wt5 = (const float*)d_in[15];
    const int*   EI  = (const int*)d_in[16];
    float* out = (float*)d_out;

    char* p = (char*)d_ws;
    float* Y    = (float*)p;  p += (size_t)9 * NH * sizeof(float);
    float* MSG  = (float*)p;  p += (size_t)9 * NH * sizeof(float);
    int*   cnt  = (int*)p;    p += (size_t)NN * sizeof(int);
    int*   cur  = (int*)p;    p += (size_t)NN * sizeof(int);
    int*   offs = (int*)p;    p += (size_t)(NN + 1) * sizeof(int);
    int*   EIDS = (int*)p;    p += (size_t)EE * sizeof(int);
    int*   DSTS = (int*)p;    p += (size_t)EE * sizeof(int);
    void*  XCp  = (void*)p;
    const size_t used   = (size_t)(p - (char*)d_ws);
    const size_t need32 = used + (size_t)EE * 384 * sizeof(float);
    const size_t need16 = used + (size_t)EE * 384 * sizeof(__hip_bfloat16);

    k_prep<<<NN / 4, 256, 0, stream>>>(X, Wt0, Wt1, Wt2, Y);

    if (ws_size >= need32) {
        hipMemsetAsync(cnt, 0, (size_t)NN * sizeof(int), stream);
        k_count<<<EE / 256, 256, 0, stream>>>(EI, cnt);
        k_scan<<<1, 256, 0, stream>>>(cnt, offs, cur);
        k_fill<<<EE / 256, 256, 0, stream>>>(EI, cur, EIDS, DSTS);
        k_edge<float, true><<<EE / 32, 256, 0, stream>>>(
            EA, CH, EW, EI, W1, b1, W2, b2, W3, b3, Y, (float*)XCp, MSG);
        k_gather<float><<<NN / 2, 256, 0, stream>>>(
            (float*)XCp, Y, offs, EIDS, DSTS, MSG);
    } else if (ws_size >= need16) {
        hipMemsetAsync(cnt, 0, (size_t)NN * sizeof(int), stream);
        k_count<<<EE / 256, 256, 0, stream>>>(EI, cnt);
        k_scan<<<1, 256, 0, stream>>>(cnt, offs, cur);
        k_fill<<<EE / 256, 256, 0, stream>>>(EI, cur, EIDS, DSTS);
        k_edge<__hip_bfloat16, true><<<EE / 32, 256, 0, stream>>>(
            EA, CH, EW, EI, W1, b1, W2, b2, W3, b3, Y,
            (__hip_bfloat16*)XCp, MSG);
        k_gather<__hip_bfloat16><<<NN / 2, 256, 0, stream>>>(
            (__hip_bfloat16*)XCp, Y, offs, EIDS, DSTS, MSG);
    } else {
        hipMemsetAsync(MSG, 0, (size_t)9 * NH * sizeof(float), stream);
        k_edge<float, false><<<EE / 32, 256, 0, stream>>>(
            EA, CH, EW, EI, W1, b1, W2, b2, W3, b3, Y, (float*)XCp, MSG);
    }

    k_finish<<<NN / 4, 256, 0, stream>>>(X, Y, MSG, Wt3, Wt4, Wt5, out);
}

// Round 4
// 1312.997 us; speedup vs baseline: 6.0428x; 2.5723x over previous
//
#include <hip/hip_runtime.h>

#define NN  10000
#define HD  128
#define EE  160000
#define RD  32
#define NH  (NN * HD)

typedef __attribute__((ext_vector_type(8))) short short8_t;
typedef __attribute__((ext_vector_type(4))) float f32x4_t;
typedef __attribute__((ext_vector_type(4))) int   int4_t;

__device__ __forceinline__ float silu_f(float z) {
    return z / (1.0f + __expf(-z));
}
__device__ __forceinline__ short f2b(float v) {   // RNE fp32->bf16
    unsigned u = __float_as_uint(v);
    unsigned r = (u + 0x7FFFu + ((u >> 16) & 1u)) >> 16;
    return (short)r;
}
__device__ __forceinline__ float b2f(short s) {
    return __uint_as_float(((unsigned)(unsigned short)s) << 16);
}

// ---------------------------------------------------------------------------
// Weight conversion: fp32 -> bf16 (W1 zero-padded K 34->64).
// ---------------------------------------------------------------------------
__global__ __launch_bounds__(256) void k_wconv(
    const float* __restrict__ W1, const float* __restrict__ W2,
    const float* __restrict__ W3,
    short* __restrict__ W1b, short* __restrict__ W2b, short* __restrict__ W3b)
{
    const int i = blockIdx.x * 256 + threadIdx.x;
    if (i < 128 * 64) {
        const int o = i >> 6, k = i & 63;
        W1b[i] = (k < 34) ? f2b(W1[o * 34 + k]) : (short)0;
        return;
    }
    const int j = i - 128 * 64;
    if (j < 256 * 128) { W2b[j] = f2b(W2[j]); return; }
    const int l = j - 256 * 128;
    if (l < 384 * 256) { W3b[l] = f2b(W3[l]); }
}

// ---------------------------------------------------------------------------
// Kernel 1: per-node prep.  Y layout comp-major: [9][N*H].
// ---------------------------------------------------------------------------
__global__ __launch_bounds__(256) void k_prep(
    const float* __restrict__ X,
    const float* __restrict__ Wt0, const float* __restrict__ Wt1,
    const float* __restrict__ Wt2,
    float* __restrict__ Y)
{
    __shared__ __align__(16) float dec[4 * 128 * 12];
    const int n0  = blockIdx.x * 4;
    const int tid = threadIdx.x;

    for (int idx = tid; idx < 512; idx += 256) {
        const int nl = idx >> 7, h = idx & 127;
        const float* t = X + ((size_t)((n0 + nl) * HD + h)) * 9;
        float T[9];
#pragma unroll
        for (int i = 0; i < 9; i++) T[i] = t[i];
        float nrm = 0.f;
#pragma unroll
        for (int i = 0; i < 9; i++) nrm = fmaf(T[i], T[i], nrm);
        const float inv = 1.0f / (nrm + 1.0f);
#pragma unroll
        for (int i = 0; i < 9; i++) T[i] *= inv;
        const float I = (T[0] + T[4] + T[8]) * (1.0f / 3.0f);
        float* d = dec + idx * 12;
        d[0] = I;
        d[1] = 0.5f * (T[7] - T[5]);
        d[2] = 0.5f * (T[2] - T[6]);
        d[3] = 0.5f * (T[3] - T[1]);
        d[4] = T[0] - I;
        d[5] = 0.5f * (T[1] + T[3]);
        d[6] = 0.5f * (T[2] + T[6]);
        d[7] = T[4] - I;
        d[8] = 0.5f * (T[5] + T[7]);
    }
    __syncthreads();

    for (int idx = tid; idx < 512; idx += 256) {
        const int nl = idx >> 7, o = idx & 127;
        float acc[9];
#pragma unroll
        for (int c = 0; c < 9; c++) acc[c] = 0.f;
        const float* d = dec + nl * 128 * 12;
#pragma unroll 4
        for (int h = 0; h < 128; h++) {
            const float w0 = Wt0[o * 128 + h];
            const float w1 = Wt1[o * 128 + h];
            const float w2 = Wt2[o * 128 + h];
            const float* dh = d + h * 12;
            acc[0] = fmaf(dh[0], w0, acc[0]);
            acc[1] = fmaf(dh[1], w1, acc[1]);
            acc[2] = fmaf(dh[2], w1, acc[2]);
            acc[3] = fmaf(dh[3], w1, acc[3]);
            acc[4] = fmaf(dh[4], w2, acc[4]);
            acc[5] = fmaf(dh[5], w2, acc[5]);
            acc[6] = fmaf(dh[6], w2, acc[6]);
            acc[7] = fmaf(dh[7], w2, acc[7]);
            acc[8] = fmaf(dh[8], w2, acc[8]);
        }
        const int base = (n0 + nl) * HD + o;
#pragma unroll
        for (int c = 0; c < 9; c++) Y[(size_t)c * NH + base] = acc[c];
    }
}

// ---------------------------------------------------------------------------
// CSR build.
// ---------------------------------------------------------------------------
__global__ __launch_bounds__(256) void k_count(const int* __restrict__ EI,
                                               int* __restrict__ cnt)
{
    const int e = blockIdx.x * 256 + threadIdx.x;
    atomicAdd(&cnt[EI[e]], 1);
}

__global__ __launch_bounds__(256) void k_scan(const int* __restrict__ cnt,
                                              int* __restrict__ offs,
                                              int* __restrict__ cur)
{
    __shared__ int part[256];
    const int tid = threadIdx.x;
    const int per = (NN + 255) / 256;
    int s = 0;
    for (int i = 0; i < per; i++) {
        const int idx = tid * per + i;
        if (idx < NN) s += cnt[idx];
    }
    part[tid] = s;
    __syncthreads();
    if (tid == 0) {
        int r = 0;
        for (int i = 0; i < 256; i++) { const int t = part[i]; part[i] = r; r += t; }
        offs[NN] = r;
    }
    __syncthreads();
    int run = part[tid];
    for (int i = 0; i < per; i++) {
        const int idx = tid * per + i;
        if (idx < NN) {
            offs[idx] = run;
            cur[idx]  = run;
            run += cnt[idx];
        }
    }
}

__global__ __launch_bounds__(256) void k_fill(const int* __restrict__ EI,
                                              int* __restrict__ cur,
                                              int* __restrict__ EIDS,
                                              int* __restrict__ DSTS)
{
    const int e = blockIdx.x * 256 + threadIdx.x;
    const int s = EI[e];
    const int pos = atomicAdd(&cur[s], 1);
    EIDS[pos] = e;
    DSTS[pos] = EI[EE + e];
}

// ---------------------------------------------------------------------------
// Kernel 2: MFMA edge MLP.  64 edges/block, 4 waves; wave w owns edges
// [w*16, w*16+16).  bf16 A/B, fp32 accum.  LDS tiles XOR-swizzled:
// short_idx(r,k,C) = r*C + (k ^ ((r&7)<<3))  -> conflict-free ds_read_b128.
// Writes XC[e][384] bf16 (silu * cutoff applied).
// ---------------------------------------------------------------------------
__global__ __launch_bounds__(256) void k_edge_mfma(
    const float* __restrict__ EA, const float* __restrict__ CH,
    const float* __restrict__ EW, const int*   __restrict__ EI,
    const short* __restrict__ W1b, const float* __restrict__ b1,
    const short* __restrict__ W2b, const float* __restrict__ b2,
    const short* __restrict__ W3b, const float* __restrict__ b3,
    short* __restrict__ XC)
{
    __shared__ __align__(16) short sIn[64 * 64];    //  8 KB
    __shared__ __align__(16) short sH1[64 * 128];   // 16 KB
    __shared__ __align__(16) short sH2[64 * 256];   // 32 KB
    __shared__ float sB1[128], sB2[256], sB3[384], sC[64];

    const int tid = threadIdx.x;
    const int e0  = blockIdx.x * 64;

    {   // zero-fill sIn (pad region), stage biases
        int4_t z = {0, 0, 0, 0};
        ((int4_t*)sIn)[tid]       = z;
        ((int4_t*)sIn)[tid + 256] = z;
        if (tid < 128) sB1[tid] = b1[tid];
        sB2[tid] = b2[tid];
        sB3[tid] = b3[tid];
        if (tid < 128) sB3[256 + tid] = b3[256 + tid];
    }
    __syncthreads();

    {   // stage edge_attr -> bf16 swizzled
        for (int i = tid; i < 512; i += 256) {
            const float4 v = ((const float4*)(EA + (size_t)e0 * RD))[i];
            const int e = i >> 3;
            const int k = (i & 7) * 4;
            const int idx = e * 64 + (k ^ ((e & 7) << 3));
            short4 sv;
            sv.x = f2b(v.x); sv.y = f2b(v.y); sv.z = f2b(v.z); sv.w = f2b(v.w);
            *(short4*)&sIn[idx] = sv;
        }
        if (tid < 64) {
            const int e = tid;
            const int s = EI[e0 + e];
            const int d = EI[EE + e0 + e];
            const int sw = (e & 7) << 3;
            sIn[e * 64 + (32 ^ sw)] = f2b(CH[s]);
            sIn[e * 64 + (33 ^ sw)] = f2b(CH[d]);
            const float w = EW[e0 + e];
            sC[e] = (w < 5.0f)
                  ? 0.5f * (__cosf(0.62831853071795864769f * w) + 1.0f) : 0.0f;
        }
    }
    __syncthreads();

    const int lane = tid & 63;
    const int wid  = tid >> 6;
    const int l15  = lane & 15;
    const int g    = lane >> 4;            // k-group 0..3
    const int arow = wid * 16 + l15;       // A-operand edge row
    const int axor = (arow & 7) << 3;

    int crow[4];
#pragma unroll
    for (int r = 0; r < 4; r++) crow[r] = wid * 16 + g * 4 + r;

    // ---- layer 1: [64x64] @ W1b^T(64->128) ----
    {
        const short8_t a0 = *(const short8_t*)&sIn[arow * 64 + ((g * 8) ^ axor)];
        const short8_t a1 = *(const short8_t*)&sIn[arow * 64 + ((32 + g * 8) ^ axor)];
#pragma unroll
        for (int ct = 0; ct < 8; ct++) {
            const int n = ct * 16 + l15;
            const short8_t bv0 = *(const short8_t*)(W1b + n * 64 + g * 8);
            const short8_t bv1 = *(const short8_t*)(W1b + n * 64 + 32 + g * 8);
            const float bias = sB1[n];
            f32x4_t acc = {bias, bias, bias, bias};
            acc = __builtin_amdgcn_mfma_f32_16x16x32_bf16(a0, bv0, acc, 0, 0, 0);
            acc = __builtin_amdgcn_mfma_f32_16x16x32_bf16(a1, bv1, acc, 0, 0, 0);
#pragma unroll
            for (int r = 0; r < 4; r++) {
                const int row = crow[r];
                sH1[row * 128 + (n ^ ((row & 7) << 3))] = f2b(silu_f(acc[r]));
            }
        }
    }
    // no barrier: wave reads only the rows it wrote (lgkmcnt handled by compiler)

    // ---- layer 2: [64x128] @ W2b^T(128->256) ----
    {
        short8_t a2[4];
#pragma unroll
        for (int kb = 0; kb < 4; kb++)
            a2[kb] = *(const short8_t*)&sH1[arow * 128 + ((kb * 32 + g * 8) ^ axor)];
#pragma unroll 4
        for (int ct = 0; ct < 16; ct++) {
            const int n = ct * 16 + l15;
            const float bias = sB2[n];
            f32x4_t acc = {bias, bias, bias, bias};
#pragma unroll
            for (int kb = 0; kb < 4; kb++) {
                const short8_t bv = *(const short8_t*)(W2b + n * 128 + kb * 32 + g * 8);
                acc = __builtin_amdgcn_mfma_f32_16x16x32_bf16(a2[kb], bv, acc, 0, 0, 0);
            }
#pragma unroll
            for (int r = 0; r < 4; r++) {
                const int row = crow[r];
                sH2[row * 256 + (n ^ ((row & 7) << 3))] = f2b(silu_f(acc[r]));
            }
        }
    }

    // ---- layer 3: [64x256] @ W3b^T(256->384), silu * cutoff, store XC ----
    {
        short8_t a3[8];
#pragma unroll
        for (int kb = 0; kb < 8; kb++)
            a3[kb] = *(const short8_t*)&sH2[arow * 256 + ((kb * 32 + g * 8) ^ axor)];
        float cv[4];
#pragma unroll
        for (int r = 0; r < 4; r++) cv[r] = sC[crow[r]];
#pragma unroll 2
        for (int ct = 0; ct < 24; ct++) {
            const int n = ct * 16 + l15;
            const float bias = sB3[n];
            f32x4_t acc = {bias, bias, bias, bias};
#pragma unroll
            for (int kb = 0; kb < 8; kb++) {
                const short8_t bv = *(const short8_t*)(W3b + n * 256 + kb * 32 + g * 8);
                acc = __builtin_amdgcn_mfma_f32_16x16x32_bf16(a3[kb], bv, acc, 0, 0, 0);
            }
#pragma unroll
            for (int r = 0; r < 4; r++) {
                const float v = silu_f(acc[r]) * cv[r];
                XC[(size_t)(e0 + crow[r]) * 384 + n] = f2b(v);
            }
        }
    }
}

// ---------------------------------------------------------------------------
// Fallback (small ws): fused VALU edge MLP + atomic scatter (round-2 path).
// ---------------------------------------------------------------------------
__global__ __launch_bounds__(256) void k_edge_atomic(
    const float* __restrict__ EA, const float* __restrict__ CH,
    const float* __restrict__ EW, const int*   __restrict__ EI,
    const float* __restrict__ W1, const float* __restrict__ b1,
    const float* __restrict__ W2, const float* __restrict__ b2,
    const float* __restrict__ W3, const float* __restrict__ b3,
    const float* __restrict__ Y,  float* __restrict__ MSG)
{
    __shared__ __align__(16) float sInf[32 * 35];
    __shared__ __align__(16) float sH1f[32 * 132];
    __shared__ __align__(16) float sH2f[32 * 260];
    __shared__ __align__(16) float sXcf[32 * 132];
    __shared__ float sCc[32];
    __shared__ int   sS[32], sD[32];

    const int e0  = blockIdx.x * 32;
    const int tid = threadIdx.x;

    {
        const float4 v = ((const float4*)(EA + (size_t)e0 * RD))[tid];
        const int e = tid >> 3;
        const int k = (tid & 7) * 4;
        float* p = sInf + e * 35 + k;
        p[0] = v.x; p[1] = v.y; p[2] = v.z; p[3] = v.w;
    }
    if (tid < 32) {
        const int e = tid;
        const int s = EI[e0 + e];
        const int d = EI[EE + e0 + e];
        sS[e] = s; sD[e] = d;
        sInf[e * 35 + 32] = CH[s];
        sInf[e * 35 + 33] = CH[d];
        const float w = EW[e0 + e];
        sCc[e] = (w < 5.0f) ? 0.5f * (__cosf(0.62831853071795864769f * w) + 1.0f)
                            : 0.0f;
    }
    __syncthreads();

    const int e  = tid & 31;
    const int og = tid >> 5;

    {
        float acc[16];
#pragma unroll
        for (int j = 0; j < 16; j++) acc[j] = b1[og * 16 + j];
        for (int k = 0; k < 34; k++) {
            const float v = sInf[e * 35 + k];
#pragma unroll
            for (int j = 0; j < 16; j++)
                acc[j] = fmaf(v, W1[(og * 16 + j) * 34 + k], acc[j]);
        }
#pragma unroll
        for (int j = 0; j < 16; j++)
            sH1f[e * 132 + og * 16 + j] = silu_f(acc[j]);
    }
    __syncthreads();

    {
        float acc[32];
#pragma unroll
        for (int j = 0; j < 32; j++) acc[j] = b2[og * 32 + j];
        for (int hq = 0; hq < 32; hq++) {
            const float4 v = *(const float4*)&sH1f[e * 132 + hq * 4];
#pragma unroll
            for (int j = 0; j < 32; j++) {
                const float4 w =
                    *(const float4*)&W2[(size_t)(og * 32 + j) * 128 + hq * 4];
                acc[j] = fmaf(v.x, w.x, fmaf(v.y, w.y,
                         fmaf(v.z, w.z, fmaf(v.w, w.w, acc[j]))));
            }
        }
#pragma unroll
        for (int j = 0; j < 32; j++)
            sH2f[e * 260 + og * 32 + j] = silu_f(acc[j]);
    }
    __syncthreads();

    for (int c = 0; c < 3; c++) {
        {
            float acc[16];
#pragma unroll
            for (int j = 0; j < 16; j++) acc[j] = b3[c * 128 + og * 16 + j];
            for (int hq = 0; hq < 64; hq++) {
                const float4 v = *(const float4*)&sH2f[e * 260 + hq * 4];
#pragma unroll
                for (int j = 0; j < 16; j++) {
                    const float4 w = *(const float4*)
                        &W3[(size_t)(c * 128 + og * 16 + j) * 256 + hq * 4];
                    acc[j] = fmaf(v.x, w.x, fmaf(v.y, w.y,
                             fmaf(v.z, w.z, fmaf(v.w, w.w, acc[j]))));
                }
            }
            const float cc = sCc[e];
#pragma unroll
            for (int j = 0; j < 16; j++)
                sXcf[e * 132 + og * 16 + j] = silu_f(acc[j]) * cc;
        }
        __syncthreads();
        {
            const int h  = tid & 127;
            const int eh = tid >> 7;
#pragma unroll 4
            for (int i = 0; i < 16; i++) {
                const int ee = (eh << 4) | i;
                const int s = sS[ee], d = sD[ee];
                const float xv = sXcf[ee * 132 + h];
                const int sb = s * HD + h, db = d * HD + h;
                if (c == 0) {
                    atomicAdd(&MSG[0 * (size_t)NH + sb], xv * Y[0 * (size_t)NH + db]);
                } else if (c == 1) {
#pragma unroll
                    for (int cc2 = 1; cc2 < 4; cc2++)
                        atomicAdd(&MSG[(size_t)cc2 * NH + sb],
                                  xv * Y[(size_t)cc2 * NH + db]);
                } else {
#pragma unroll
                    for (int cc2 = 4; cc2 < 9; cc2++)
                        atomicAdd(&MSG[(size_t)cc2 * NH + sb],
                                  xv * Y[(size_t)cc2 * NH + db]);
                }
            }
        }
        __syncthreads();
    }
}

// ---------------------------------------------------------------------------
// Kernel 2b: node-major gather.  XC bf16.
// ---------------------------------------------------------------------------
__global__ __launch_bounds__(256) void k_gather(
    const short* __restrict__ XC, const float* __restrict__ Y,
    const int* __restrict__ offs, const int* __restrict__ EIDS,
    const int* __restrict__ DSTS, float* __restrict__ MSG)
{
    const int tid = threadIdx.x;
    const int nl  = tid >> 7, h = tid & 127;
    const int n   = blockIdx.x * 2 + nl;
    const int beg = offs[n], end = offs[n + 1];

    float m[9];
#pragma unroll
    for (int c = 0; c < 9; c++) m[c] = 0.f;

    for (int p = beg; p < end; ++p) {
        const int eid = EIDS[p];
        const int dst = DSTS[p];
        const size_t xb = (size_t)eid * 384;
        const float x0 = b2f(XC[xb + h]);
        const float x1 = b2f(XC[xb + 128 + h]);
        const float x2 = b2f(XC[xb + 256 + h]);
        const int yb = dst * HD + h;
        m[0] = fmaf(x0, Y[0 * (size_t)NH + yb], m[0]);
        m[1] = fmaf(x1, Y[1 * (size_t)NH + yb], m[1]);
        m[2] = fmaf(x1, Y[2 * (size_t)NH + yb], m[2]);
        m[3] = fmaf(x1, Y[3 * (size_t)NH + yb], m[3]);
        m[4] = fmaf(x2, Y[4 * (size_t)NH + yb], m[4]);
        m[5] = fmaf(x2, Y[5 * (size_t)NH + yb], m[5]);
        m[6] = fmaf(x2, Y[6 * (size_t)NH + yb], m[6]);
        m[7] = fmaf(x2, Y[7 * (size_t)NH + yb], m[7]);
        m[8] = fmaf(x2, Y[8 * (size_t)NH + yb], m[8]);
    }
    const int base = n * HD + h;
#pragma unroll
    for (int c = 0; c < 9; c++) MSG[(size_t)c * NH + base] = m[c];
}

// ---------------------------------------------------------------------------
// Kernel 3: per-node finish.
// ---------------------------------------------------------------------------
__global__ __launch_bounds__(256) void k_finish(
    const float* __restrict__ X,
    const float* __restrict__ Y, const float* __restrict__ MSG,
    const float* __restrict__ Wt3, const float* __restrict__ Wt4,
    const float* __restrict__ Wt5,
    float* __restrict__ out)
{
    __shared__ __align__(16) float dec[4 * 128 * 12];
    const int n0  = blockIdx.x * 4;
    const int tid = threadIdx.x;

    for (int idx = tid; idx < 512; idx += 256) {
        const int nl = idx >> 7, h = idx & 127;
        const int base = (n0 + nl) * HD + h;
        float yv[9], mv[9];
#pragma unroll
        for (int c = 0; c < 9; c++) {
            yv[c] = Y[(size_t)c * NH + base];
            mv[c] = MSG[(size_t)c * NH + base];
        }
        float Yt[9], G[9];
        {
            const float I = yv[0], a0 = yv[1], a1 = yv[2], a2 = yv[3];
            const float s00 = yv[4], s01 = yv[5], s02 = yv[6], s11 = yv[7], s12 = yv[8];
            const float s22 = -s00 - s11;
            Yt[0] = I + s00; Yt[1] = s01 - a2; Yt[2] = s02 + a1;
            Yt[3] = s01 + a2; Yt[4] = I + s11; Yt[5] = s12 - a0;
            Yt[6] = s02 - a1; Yt[7] = s12 + a0; Yt[8] = I + s22;
        }
        {
            const float I = mv[0], a0 = mv[1], a1 = mv[2], a2 = mv[3];
            const float s00 = mv[4], s01 = mv[5], s02 = mv[6], s11 = mv[7], s12 = mv[8];
            const float s22 = -s00 - s11;
            G[0] = I + s00; G[1] = s01 - a2; G[2] = s02 + a1;
            G[3] = s01 + a2; G[4] = I + s11; G[5] = s12 - a0;
            G[6] = s02 - a1; G[7] = s12 + a0; G[8] = I + s22;
        }
        float M[9];
#pragma unroll
        for (int i = 0; i < 3; i++)
#pragma unroll
            for (int j = 0; j < 3; j++) {
                float acc = 0.f;
#pragma unroll
                for (int k = 0; k < 3; k++)
                    acc += G[i * 3 + k] * Yt[k * 3 + j]
                         + Yt[i * 3 + k] * G[k * 3 + j];
                M[i * 3 + j] = acc;
            }
        const float I2 = (M[0] + M[4] + M[8]) * (1.0f / 3.0f);
        const float a0 = 0.5f * (M[7] - M[5]);
        const float a1 = 0.5f * (M[2] - M[6]);
        const float a2 = 0.5f * (M[3] - M[1]);
        const float s00 = M[0] - I2, s11 = M[4] - I2;
        const float s01 = 0.5f * (M[1] + M[3]);
        const float s02 = 0.5f * (M[2] + M[6]);
        const float s12 = 0.5f * (M[5] + M[7]);
        const float s22 = -s00 - s11;
        const float nrm = 2.f * (a0 * a0 + a1 * a1 + a2 * a2)
                        + (s00 * s00 + s11 * s11 + s22 * s22)
                        + 2.f * (s01 * s01 + s02 * s02 + s12 * s12)
                        + 3.f * I2 * I2;
        const float inv = 1.0f / (nrm + 1.0f);
        float* dd = dec + idx * 12;
        dd[0] = I2 * inv;  dd[1] = a0 * inv;  dd[2] = a1 * inv;  dd[3] = a2 * inv;
        dd[4] = s00 * inv; dd[5] = s01 * inv; dd[6] = s02 * inv;
        dd[7] = s11 * inv; dd[8] = s12 * inv;
    }
    __syncthreads();

    for (int idx = tid; idx < 512; idx += 256) {
        const int nl = idx >> 7, o = idx & 127;
        float acc[9];
#pragma unroll
        for (int c = 0; c < 9; c++) acc[c] = 0.f;
        const float* d = dec + nl * 128 * 12;
#pragma unroll 4
        for (int h = 0; h < 128; h++) {
            const float w3 = Wt3[o * 128 + h];
            const float w4 = Wt4[o * 128 + h];
            const float w5 = Wt5[o * 128 + h];
            const float* dh = d + h * 12;
            acc[0] = fmaf(dh[0], w3, acc[0]);
            acc[1] = fmaf(dh[1], w4, acc[1]);
            acc[2] = fmaf(dh[2], w4, acc[2]);
            acc[3] = fmaf(dh[3], w4, acc[3]);
            acc[4] = fmaf(dh[4], w5, acc[4]);
            acc[5] = fmaf(dh[5], w5, acc[5]);
            acc[6] = fmaf(dh[6], w5, acc[6]);
            acc[7] = fmaf(dh[7], w5, acc[7]);
            acc[8] = fmaf(dh[8], w5, acc[8]);
        }
        float D[9];
        {
            const float I = acc[0], a0 = acc[1], a1 = acc[2], a2 = acc[3];
            const float s00 = acc[4], s01 = acc[5], s02 = acc[6];
            const float s11 = acc[7], s12 = acc[8];
            const float s22 = -s00 - s11;
            D[0] = I + s00; D[1] = s01 - a2; D[2] = s02 + a1;
            D[3] = s01 + a2; D[4] = I + s11; D[5] = s12 - a0;
            D[6] = s02 - a1; D[7] = s12 + a0; D[8] = I + s22;
        }
        const size_t xbase = ((size_t)((n0 + nl) * HD + o)) * 9;
        float T[9];
#pragma unroll
        for (int i = 0; i < 9; i++) T[i] = X[xbase + i];
        float nrm = 0.f;
#pragma unroll
        for (int i = 0; i < 9; i++) nrm = fmaf(T[i], T[i], nrm);
        const float inv = 1.0f / (nrm + 1.0f);
        float* op = out + xbase;
#pragma unroll
        for (int i = 0; i < 3; i++)
#pragma unroll
            for (int j = 0; j < 3; j++) {
                float dd2 = 0.f;
#pragma unroll
                for (int k = 0; k < 3; k++)
                    dd2 = fmaf(D[i * 3 + k], D[k * 3 + j], dd2);
                op[i * 3 + j] = T[i * 3 + j] * inv + D[i * 3 + j] + dd2;
            }
    }
}

// ---------------------------------------------------------------------------
static inline size_t align_up(size_t v, size_t a) { return (v + a - 1) & ~(a - 1); }

extern "C" void kernel_launch(void* const* d_in, const int* in_sizes, int n_in,
                              void* d_out, int out_size, void* d_ws, size_t ws_size,
                              hipStream_t stream)
{
    const float* X   = (const float*)d_in[0];
    const float* CH  = (const float*)d_in[1];
    const float* EA  = (const float*)d_in[2];
    const float* EW  = (const float*)d_in[3];
    const float* W1  = (const float*)d_in[4];
    const float* b1  = (const float*)d_in[5];
    const float* W2  = (const float*)d_in[6];
    const float* b2  = (const float*)d_in[7];
    const float* W3  = (const float*)d_in[8];
    const float* b3  = (const float*)d_in[9];
    const float* Wt0 = (const float*)d_in[10];
    const float* Wt1 = (const float*)d_in[11];
    const float* Wt2 = (const float*)d_in[12];
    const float* Wt3 = (const float*)d_in[13];
    const float* Wt4 = (const float*)d_in[14];
    const float* Wt5 = (const float*)d_in[15];
    const int*   EI  = (const int*)d_in[16];
    float* out = (float*)d_out;

    size_t off = 0;
    float* Y    = (float*)((char*)d_ws + off); off = align_up(off + (size_t)9 * NH * 4, 64);
    float* MSG  = (float*)((char*)d_ws + off); off = align_up(off + (size_t)9 * NH * 4, 64);
    int*   cnt  = (int*)((char*)d_ws + off);   off = align_up(off + (size_t)NN * 4, 64);
    int*   cur  = (int*)((char*)d_ws + off);   off = align_up(off + (size_t)NN * 4, 64);
    int*   offs = (int*)((char*)d_ws + off);   off = align_up(off + (size_t)(NN + 1) * 4, 64);
    int*   EIDS = (int*)((char*)d_ws + off);   off = align_up(off + (size_t)EE * 4, 64);
    int*   DSTS = (int*)((char*)d_ws + off);   off = align_up(off + (size_t)EE * 4, 64);
    short* W1b  = (short*)((char*)d_ws + off); off = align_up(off + (size_t)128 * 64 * 2, 64);
    short* W2b  = (short*)((char*)d_ws + off); off = align_up(off + (size_t)256 * 128 * 2, 64);
    short* W3b  = (short*)((char*)d_ws + off); off = align_up(off + (size_t)384 * 256 * 2, 64);
    short* XC   = (short*)((char*)d_ws + off);
    const size_t need = off + (size_t)EE * 384 * 2;

    k_prep<<<NN / 4, 256, 0, stream>>>(X, Wt0, Wt1, Wt2, Y);

    if (ws_size >= need) {
        k_wconv<<<544, 256, 0, stream>>>(W1, W2, W3, W1b, W2b, W3b);
        hipMemsetAsync(cnt, 0, (size_t)NN * sizeof(int), stream);
        k_count<<<EE / 256, 256, 0, stream>>>(EI, cnt);
        k_scan<<<1, 256, 0, stream>>>(cnt, offs, cur);
        k_fill<<<EE / 256, 256, 0, stream>>>(EI, cur, EIDS, DSTS);
        k_edge_mfma<<<EE / 64, 256, 0, stream>>>(EA, CH, EW, EI,
                                                 W1b, b1, W2b, b2, W3b, b3, XC);
        k_gather<<<NN / 2, 256, 0, stream>>>(XC, Y, offs, EIDS, DSTS, MSG);
    } else {
        hipMemsetAsync(MSG, 0, (size_t)9 * NH * sizeof(float), stream);
        k_edge_atomic<<<EE / 32, 256, 0, stream>>>(EA, CH, EW, EI,
                                                   W1, b1, W2, b2, W3, b3, Y, MSG);
    }

    k_finish<<<NN / 4, 256, 0, stream>>>(X, Y, MSG, Wt3, Wt4, Wt5, out);
}

// Round 5
// 602.237 us; speedup vs baseline: 13.1746x; 2.1802x over previous
//
#include <hip/hip_runtime.h>

#define NN  10000
#define HD  128
#define EE  160000
#define RD  32
#define NH  (NN * HD)

typedef __attribute__((ext_vector_type(8))) short short8_t;
typedef __attribute__((ext_vector_type(4))) float f32x4_t;
typedef __attribute__((ext_vector_type(4))) int   int4_t;

__device__ __forceinline__ float silu_f(float z) {
    return z / (1.0f + __expf(-z));
}
__device__ __forceinline__ short f2b(float v) {   // RNE fp32->bf16
    unsigned u = __float_as_uint(v);
    unsigned r = (u + 0x7FFFu + ((u >> 16) & 1u)) >> 16;
    return (short)r;
}
__device__ __forceinline__ float b2f(short s) {
    return __uint_as_float(((unsigned)(unsigned short)s) << 16);
}

// ---------------------------------------------------------------------------
// Weight conversion:
//  - edge MLP weights -> single bf16 (W1 zero-padded K 34->64)
//  - mix weights Wt0..Wt5 -> bf16 hi/lo split pairs (prep: Wt0-2, fin: Wt3-5)
// ---------------------------------------------------------------------------
__global__ __launch_bounds__(256) void k_wconv(
    const float* __restrict__ W1, const float* __restrict__ W2,
    const float* __restrict__ W3,
    const float* __restrict__ Wt0, const float* __restrict__ Wt1,
    const float* __restrict__ Wt2, const float* __restrict__ Wt3,
    const float* __restrict__ Wt4, const float* __restrict__ Wt5,
    short* __restrict__ W1b, short* __restrict__ W2b, short* __restrict__ W3b,
    short* __restrict__ WtPh, short* __restrict__ WtPl,
    short* __restrict__ WtFh, short* __restrict__ WtFl)
{
    const int i = blockIdx.x * 256 + threadIdx.x;
    if (i < 128 * 64) {
        const int o = i >> 6, k = i & 63;
        W1b[i] = (k < 34) ? f2b(W1[o * 34 + k]) : (short)0;
        return;
    }
    int j = i - 128 * 64;
    if (j < 256 * 128) { W2b[j] = f2b(W2[j]); return; }
    j -= 256 * 128;
    if (j < 384 * 256) { W3b[j] = f2b(W3[j]); return; }
    j -= 384 * 256;
    if (j < 6 * 16384) {
        const int m = j >> 14, idx = j & 16383;
        const float* src = (m == 0) ? Wt0 : (m == 1) ? Wt1 : (m == 2) ? Wt2
                         : (m == 3) ? Wt3 : (m == 4) ? Wt4 : Wt5;
        const float w = src[idx];
        const short hi = f2b(w);
        const short lo = f2b(w - b2f(hi));
        if (m < 3) { WtPh[m * 16384 + idx] = hi; WtPl[m * 16384 + idx] = lo; }
        else       { WtFh[(m - 3) * 16384 + idx] = hi; WtFl[(m - 3) * 16384 + idx] = lo; }
    }
}

// ---------------------------------------------------------------------------
// k_mix<FIN>: channel-mix as MFMA GEMM with bf16 hi/lo 3-term split.
// 16 nodes/block, 256 threads (4 waves).  B = dec^T in LDS [144 cols][128 h]
// (col = comp*16 + node_local), XOR-swizzled.  A = weight rows (hi/lo bf16,
// L2-resident).  C routed through LDS for the epilogue.
//  FIN=false (prep):  dec from X-normalize/decompose; out = Y planes [9][NH].
//  FIN=true  (finish): dec from M=msg*Y+Y*msg decompose/normalize;
//                      out[n][h][9] = Xn + dX + dX^2.
// ---------------------------------------------------------------------------
template <bool FIN>
__global__ __launch_bounds__(256) void k_mix(
    const float* __restrict__ X,
    const float* __restrict__ Yin, const float* __restrict__ MSGin,
    const short* __restrict__ Wh,  const short* __restrict__ Wl,
    float* __restrict__ outp)
{
    extern __shared__ __align__(16) char smem[];   // 73728 B
    short* sBh = (short*)smem;                     // [144][128] bf16 hi
    short* sBl = sBh + 144 * 128;                  // [144][128] bf16 lo
    float* sC  = (float*)smem;                     // [144][128] f32 (after GEMM)

    const int tid = threadIdx.x;
    const int n0  = blockIdx.x * 16;

    // ---- stage B = dec^T (hi/lo, swizzled) ----
#pragma unroll 2
    for (int i = 0; i < 8; i++) {
        const int p  = i * 256 + tid;
        const int nl = p >> 7, h = p & 127;
        float dec[9];
        if constexpr (!FIN) {
            const float* t = X + ((size_t)((n0 + nl) * HD + h)) * 9;
            float T[9];
#pragma unroll
            for (int q = 0; q < 9; q++) T[q] = t[q];
            float nrm = 0.f;
#pragma unroll
            for (int q = 0; q < 9; q++) nrm = fmaf(T[q], T[q], nrm);
            const float inv = 1.0f / (nrm + 1.0f);
#pragma unroll
            for (int q = 0; q < 9; q++) T[q] *= inv;
            const float I = (T[0] + T[4] + T[8]) * (1.0f / 3.0f);
            dec[0] = I;
            dec[1] = 0.5f * (T[7] - T[5]);
            dec[2] = 0.5f * (T[2] - T[6]);
            dec[3] = 0.5f * (T[3] - T[1]);
            dec[4] = T[0] - I;
            dec[5] = 0.5f * (T[1] + T[3]);
            dec[6] = 0.5f * (T[2] + T[6]);
            dec[7] = T[4] - I;
            dec[8] = 0.5f * (T[5] + T[7]);
        } else {
            const int basep = (n0 + nl) * HD + h;
            float yv[9], mv[9];
#pragma unroll
            for (int c = 0; c < 9; c++) {
                yv[c] = Yin[(size_t)c * NH + basep];
                mv[c] = MSGin[(size_t)c * NH + basep];
            }
            float Yt[9], G[9];
            {
                const float I = yv[0], a0 = yv[1], a1 = yv[2], a2 = yv[3];
                const float s00 = yv[4], s01 = yv[5], s02 = yv[6], s11 = yv[7], s12 = yv[8];
                const float s22 = -s00 - s11;
                Yt[0] = I + s00; Yt[1] = s01 - a2; Yt[2] = s02 + a1;
                Yt[3] = s01 + a2; Yt[4] = I + s11; Yt[5] = s12 - a0;
                Yt[6] = s02 - a1; Yt[7] = s12 + a0; Yt[8] = I + s22;
            }
            {
                const float I = mv[0], a0 = mv[1], a1 = mv[2], a2 = mv[3];
                const float s00 = mv[4], s01 = mv[5], s02 = mv[6], s11 = mv[7], s12 = mv[8];
                const float s22 = -s00 - s11;
                G[0] = I + s00; G[1] = s01 - a2; G[2] = s02 + a1;
                G[3] = s01 + a2; G[4] = I + s11; G[5] = s12 - a0;
                G[6] = s02 - a1; G[7] = s12 + a0; G[8] = I + s22;
            }
            float M[9];
#pragma unroll
            for (int r = 0; r < 3; r++)
#pragma unroll
                for (int cc = 0; cc < 3; cc++) {
                    float a = 0.f;
#pragma unroll
                    for (int k = 0; k < 3; k++)
                        a += G[r * 3 + k] * Yt[k * 3 + cc]
                           + Yt[r * 3 + k] * G[k * 3 + cc];
                    M[r * 3 + cc] = a;
                }
            const float I2 = (M[0] + M[4] + M[8]) * (1.0f / 3.0f);
            const float a0 = 0.5f * (M[7] - M[5]);
            const float a1 = 0.5f * (M[2] - M[6]);
            const float a2 = 0.5f * (M[3] - M[1]);
            const float s00 = M[0] - I2, s11 = M[4] - I2;
            const float s01 = 0.5f * (M[1] + M[3]);
            const float s02 = 0.5f * (M[2] + M[6]);
            const float s12 = 0.5f * (M[5] + M[7]);
            const float s22 = -s00 - s11;
            const float nrm = 2.f * (a0 * a0 + a1 * a1 + a2 * a2)
                            + (s00 * s00 + s11 * s11 + s22 * s22)
                            + 2.f * (s01 * s01 + s02 * s02 + s12 * s12)
                            + 3.f * I2 * I2;
            const float inv = 1.0f / (nrm + 1.0f);
            dec[0] = I2 * inv;  dec[1] = a0 * inv;  dec[2] = a1 * inv;
            dec[3] = a2 * inv;  dec[4] = s00 * inv; dec[5] = s01 * inv;
            dec[6] = s02 * inv; dec[7] = s11 * inv; dec[8] = s12 * inv;
        }
        const int sw = (nl & 7) << 3;
        const int hx = h ^ sw;
#pragma unroll
        for (int c = 0; c < 9; c++) {
            const float v  = dec[c];
            const short hi = f2b(v);
            const short lo = f2b(v - b2f(hi));
            const int idx = (c * 16 + nl) * 128 + hx;
            sBh[idx] = hi;
            sBl[idx] = lo;
        }
    }
    __syncthreads();

    // ---- GEMM: C[o][col] = sum_h W[o][h] * dec^T[col][h] ----
    const int lane = tid & 63, wid = tid >> 6;
    const int l15 = lane & 15, g = lane >> 4;
    f32x4_t acc[2][9];
#pragma unroll
    for (int t = 0; t < 2; t++)
#pragma unroll
        for (int c = 0; c < 9; c++) acc[t][c] = {0.f, 0.f, 0.f, 0.f};

    const int bsw = (l15 & 7) << 3;
#pragma unroll
    for (int k = 0; k < 4; k++) {
        const int k0  = k * 32 + g * 8;
        const int ksw = k0 ^ bsw;
#pragma unroll
        for (int w = 0; w < 3; w++) {
            short8_t Ah[2], Al[2];
#pragma unroll
            for (int t = 0; t < 2; t++) {
                const int o = (wid * 2 + t) * 16 + l15;
                const size_t aoff = (size_t)w * 16384 + (size_t)o * 128 + k0;
                Ah[t] = *(const short8_t*)(Wh + aoff);
                Al[t] = *(const short8_t*)(Wl + aoff);
            }
            const int ct0 = (w == 0) ? 0 : (w == 1 ? 1 : 4);
            const int ctn = (w == 0) ? 1 : (w == 1 ? 3 : 5);
            for (int cc = 0; cc < ctn; cc++) {
                const int ct = ct0 + cc;
                const int boff = (ct * 16 + l15) * 128 + ksw;
                const short8_t Bh = *(const short8_t*)&sBh[boff];
                const short8_t Bl = *(const short8_t*)&sBl[boff];
#pragma unroll
                for (int t = 0; t < 2; t++) {
                    acc[t][ct] = __builtin_amdgcn_mfma_f32_16x16x32_bf16(Al[t], Bh, acc[t][ct], 0, 0, 0);
                    acc[t][ct] = __builtin_amdgcn_mfma_f32_16x16x32_bf16(Ah[t], Bl, acc[t][ct], 0, 0, 0);
                    acc[t][ct] = __builtin_amdgcn_mfma_f32_16x16x32_bf16(Ah[t], Bh, acc[t][ct], 0, 0, 0);
                }
            }
        }
    }
    __syncthreads();   // all B reads done -> safe to alias sC over sB

    // ---- C -> LDS (swizzled: o ^ ((col&7)<<2)) ----
    const int csw = (l15 & 7) << 2;
#pragma unroll
    for (int t = 0; t < 2; t++) {
        const int o0 = (wid * 2 + t) * 16 + g * 4;
#pragma unroll
        for (int ct = 0; ct < 9; ct++)
            *(f32x4_t*)&sC[(ct * 16 + l15) * 128 + (o0 ^ csw)] = acc[t][ct];
    }
    __syncthreads();

    if constexpr (!FIN) {
        // coalesced write of Y comp-planes
        for (int i = tid; i < 144 * 32; i += 256) {
            const int row = i >> 5, q = i & 31;
            const int c = row >> 4, nl = row & 15;
            const int sw = (nl & 7) << 2;
            const f32x4_t v = *(const f32x4_t*)&sC[row * 128 + ((q * 4) ^ sw)];
            *(f32x4_t*)&outp[(size_t)c * NH + (size_t)(n0 + nl) * HD + q * 4] = v;
        }
    } else {
#pragma unroll 2
        for (int i = 0; i < 8; i++) {
            const int p  = i * 256 + tid;
            const int nl = p >> 7, o = p & 127;
            const int sw = (nl & 7) << 2;
            const int ox = o ^ sw;
            float a9[9];
#pragma unroll
            for (int c = 0; c < 9; c++) a9[c] = sC[(c * 16 + nl) * 128 + ox];
            float D[9];
            {
                const float I = a9[0], a0 = a9[1], a1 = a9[2], a2 = a9[3];
                const float s00 = a9[4], s01 = a9[5], s02 = a9[6];
                const float s11 = a9[7], s12 = a9[8];
                const float s22 = -s00 - s11;
                D[0] = I + s00; D[1] = s01 - a2; D[2] = s02 + a1;
                D[3] = s01 + a2; D[4] = I + s11; D[5] = s12 - a0;
                D[6] = s02 - a1; D[7] = s12 + a0; D[8] = I + s22;
            }
            const size_t xbase = ((size_t)((n0 + nl) * HD + o)) * 9;
            float T[9];
#pragma unroll
            for (int q = 0; q < 9; q++) T[q] = X[xbase + q];
            float nrm = 0.f;
#pragma unroll
            for (int q = 0; q < 9; q++) nrm = fmaf(T[q], T[q], nrm);
            const float inv = 1.0f / (nrm + 1.0f);
            float* op = outp + xbase;
#pragma unroll
            for (int r = 0; r < 3; r++)
#pragma unroll
                for (int cc = 0; cc < 3; cc++) {
                    float dd2 = 0.f;
#pragma unroll
                    for (int k = 0; k < 3; k++)
                        dd2 = fmaf(D[r * 3 + k], D[k * 3 + cc], dd2);
                    op[r * 3 + cc] = T[r * 3 + cc] * inv + D[r * 3 + cc] + dd2;
                }
        }
    }
}

// ---------------------------------------------------------------------------
// CSR build.
// ---------------------------------------------------------------------------
__global__ __launch_bounds__(256) void k_count(const int* __restrict__ EI,
                                               int* __restrict__ cnt)
{
    const int e = blockIdx.x * 256 + threadIdx.x;
    atomicAdd(&cnt[EI[e]], 1);
}

__global__ __launch_bounds__(256) void k_scan(const int* __restrict__ cnt,
                                              int* __restrict__ offs,
                                              int* __restrict__ cur)
{
    __shared__ int part[256];
    const int tid = threadIdx.x;
    const int per = (NN + 255) / 256;
    int s = 0;
    for (int i = 0; i < per; i++) {
        const int idx = tid * per + i;
        if (idx < NN) s += cnt[idx];
    }
    part[tid] = s;
    __syncthreads();
    if (tid == 0) {
        int r = 0;
        for (int i = 0; i < 256; i++) { const int t = part[i]; part[i] = r; r += t; }
        offs[NN] = r;
    }
    __syncthreads();
    int run = part[tid];
    for (int i = 0; i < per; i++) {
        const int idx = tid * per + i;
        if (idx < NN) {
            offs[idx] = run;
            cur[idx]  = run;
            run += cnt[idx];
        }
    }
}

__global__ __launch_bounds__(256) void k_fill(const int* __restrict__ EI,
                                              int* __restrict__ cur,
                                              int* __restrict__ EIDS,
                                              int* __restrict__ DSTS)
{
    const int e = blockIdx.x * 256 + threadIdx.x;
    const int s = EI[e];
    const int pos = atomicAdd(&cur[s], 1);
    EIDS[pos] = e;
    DSTS[pos] = EI[EE + e];
}

// ---------------------------------------------------------------------------
// Kernel 2: MFMA edge MLP (unchanged from round 3).
// ---------------------------------------------------------------------------
__global__ __launch_bounds__(256) void k_edge_mfma(
    const float* __restrict__ EA, const float* __restrict__ CH,
    const float* __restrict__ EW, const int*   __restrict__ EI,
    const short* __restrict__ W1b, const float* __restrict__ b1,
    const short* __restrict__ W2b, const float* __restrict__ b2,
    const short* __restrict__ W3b, const float* __restrict__ b3,
    short* __restrict__ XC)
{
    __shared__ __align__(16) short sIn[64 * 64];
    __shared__ __align__(16) short sH1[64 * 128];
    __shared__ __align__(16) short sH2[64 * 256];
    __shared__ float sB1[128], sB2[256], sB3[384], sC[64];

    const int tid = threadIdx.x;
    const int e0  = blockIdx.x * 64;

    {
        int4_t z = {0, 0, 0, 0};
        ((int4_t*)sIn)[tid]       = z;
        ((int4_t*)sIn)[tid + 256] = z;
        if (tid < 128) sB1[tid] = b1[tid];
        sB2[tid] = b2[tid];
        sB3[tid] = b3[tid];
        if (tid < 128) sB3[256 + tid] = b3[256 + tid];
    }
    __syncthreads();

    {
        for (int i = tid; i < 512; i += 256) {
            const float4 v = ((const float4*)(EA + (size_t)e0 * RD))[i];
            const int e = i >> 3;
            const int k = (i & 7) * 4;
            const int idx = e * 64 + (k ^ ((e & 7) << 3));
            short4 sv;
            sv.x = f2b(v.x); sv.y = f2b(v.y); sv.z = f2b(v.z); sv.w = f2b(v.w);
            *(short4*)&sIn[idx] = sv;
        }
        if (tid < 64) {
            const int e = tid;
            const int s = EI[e0 + e];
            const int d = EI[EE + e0 + e];
            const int sw = (e & 7) << 3;
            sIn[e * 64 + (32 ^ sw)] = f2b(CH[s]);
            sIn[e * 64 + (33 ^ sw)] = f2b(CH[d]);
            const float w = EW[e0 + e];
            sC[e] = (w < 5.0f)
                  ? 0.5f * (__cosf(0.62831853071795864769f * w) + 1.0f) : 0.0f;
        }
    }
    __syncthreads();

    const int lane = tid & 63;
    const int wid  = tid >> 6;
    const int l15  = lane & 15;
    const int g    = lane >> 4;
    const int arow = wid * 16 + l15;
    const int axor = (arow & 7) << 3;

    int crow[4];
#pragma unroll
    for (int r = 0; r < 4; r++) crow[r] = wid * 16 + g * 4 + r;

    {
        const short8_t a0 = *(const short8_t*)&sIn[arow * 64 + ((g * 8) ^ axor)];
        const short8_t a1 = *(const short8_t*)&sIn[arow * 64 + ((32 + g * 8) ^ axor)];
#pragma unroll
        for (int ct = 0; ct < 8; ct++) {
            const int n = ct * 16 + l15;
            const short8_t bv0 = *(const short8_t*)(W1b + n * 64 + g * 8);
            const short8_t bv1 = *(const short8_t*)(W1b + n * 64 + 32 + g * 8);
            const float bias = sB1[n];
            f32x4_t acc = {bias, bias, bias, bias};
            acc = __builtin_amdgcn_mfma_f32_16x16x32_bf16(a0, bv0, acc, 0, 0, 0);
            acc = __builtin_amdgcn_mfma_f32_16x16x32_bf16(a1, bv1, acc, 0, 0, 0);
#pragma unroll
            for (int r = 0; r < 4; r++) {
                const int row = crow[r];
                sH1[row * 128 + (n ^ ((row & 7) << 3))] = f2b(silu_f(acc[r]));
            }
        }
    }

    {
        short8_t a2[4];
#pragma unroll
        for (int kb = 0; kb < 4; kb++)
            a2[kb] = *(const short8_t*)&sH1[arow * 128 + ((kb * 32 + g * 8) ^ axor)];
#pragma unroll 4
        for (int ct = 0; ct < 16; ct++) {
            const int n = ct * 16 + l15;
            const float bias = sB2[n];
            f32x4_t acc = {bias, bias, bias, bias};
#pragma unroll
            for (int kb = 0; kb < 4; kb++) {
                const short8_t bv = *(const short8_t*)(W2b + n * 128 + kb * 32 + g * 8);
                acc = __builtin_amdgcn_mfma_f32_16x16x32_bf16(a2[kb], bv, acc, 0, 0, 0);
            }
#pragma unroll
            for (int r = 0; r < 4; r++) {
                const int row = crow[r];
                sH2[row * 256 + (n ^ ((row & 7) << 3))] = f2b(silu_f(acc[r]));
            }
        }
    }

    {
        short8_t a3[8];
#pragma unroll
        for (int kb = 0; kb < 8; kb++)
            a3[kb] = *(const short8_t*)&sH2[arow * 256 + ((kb * 32 + g * 8) ^ axor)];
        float cv[4];
#pragma unroll
        for (int r = 0; r < 4; r++) cv[r] = sC[crow[r]];
#pragma unroll 2
        for (int ct = 0; ct < 24; ct++) {
            const int n = ct * 16 + l15;
            const float bias = sB3[n];
            f32x4_t acc = {bias, bias, bias, bias};
#pragma unroll
            for (int kb = 0; kb < 8; kb++) {
                const short8_t bv = *(const short8_t*)(W3b + n * 256 + kb * 32 + g * 8);
                acc = __builtin_amdgcn_mfma_f32_16x16x32_bf16(a3[kb], bv, acc, 0, 0, 0);
            }
#pragma unroll
            for (int r = 0; r < 4; r++) {
                const float v = silu_f(acc[r]) * cv[r];
                XC[(size_t)(e0 + crow[r]) * 384 + n] = f2b(v);
            }
        }
    }
}

// ---------------------------------------------------------------------------
// Fallback (small ws): fused VALU edge MLP + atomic scatter.
// ---------------------------------------------------------------------------
__global__ __launch_bounds__(256) void k_edge_atomic(
    const float* __restrict__ EA, const float* __restrict__ CH,
    const float* __restrict__ EW, const int*   __restrict__ EI,
    const float* __restrict__ W1, const float* __restrict__ b1,
    const float* __restrict__ W2, const float* __restrict__ b2,
    const float* __restrict__ W3, const float* __restrict__ b3,
    const float* __restrict__ Y,  float* __restrict__ MSG)
{
    __shared__ __align__(16) float sInf[32 * 35];
    __shared__ __align__(16) float sH1f[32 * 132];
    __shared__ __align__(16) float sH2f[32 * 260];
    __shared__ __align__(16) float sXcf[32 * 132];
    __shared__ float sCc[32];
    __shared__ int   sS[32], sD[32];

    const int e0  = blockIdx.x * 32;
    const int tid = threadIdx.x;

    {
        const float4 v = ((const float4*)(EA + (size_t)e0 * RD))[tid];
        const int e = tid >> 3;
        const int k = (tid & 7) * 4;
        float* p = sInf + e * 35 + k;
        p[0] = v.x; p[1] = v.y; p[2] = v.z; p[3] = v.w;
    }
    if (tid < 32) {
        const int e = tid;
        const int s = EI[e0 + e];
        const int d = EI[EE + e0 + e];
        sS[e] = s; sD[e] = d;
        sInf[e * 35 + 32] = CH[s];
        sInf[e * 35 + 33] = CH[d];
        const float w = EW[e0 + e];
        sCc[e] = (w < 5.0f) ? 0.5f * (__cosf(0.62831853071795864769f * w) + 1.0f)
                            : 0.0f;
    }
    __syncthreads();

    const int e  = tid & 31;
    const int og = tid >> 5;

    {
        float acc[16];
#pragma unroll
        for (int j = 0; j < 16; j++) acc[j] = b1[og * 16 + j];
        for (int k = 0; k < 34; k++) {
            const float v = sInf[e * 35 + k];
#pragma unroll
            for (int j = 0; j < 16; j++)
                acc[j] = fmaf(v, W1[(og * 16 + j) * 34 + k], acc[j]);
        }
#pragma unroll
        for (int j = 0; j < 16; j++)
            sH1f[e * 132 + og * 16 + j] = silu_f(acc[j]);
    }
    __syncthreads();

    {
        float acc[32];
#pragma unroll
        for (int j = 0; j < 32; j++) acc[j] = b2[og * 32 + j];
        for (int hq = 0; hq < 32; hq++) {
            const float4 v = *(const float4*)&sH1f[e * 132 + hq * 4];
#pragma unroll
            for (int j = 0; j < 32; j++) {
                const float4 w =
                    *(const float4*)&W2[(size_t)(og * 32 + j) * 128 + hq * 4];
                acc[j] = fmaf(v.x, w.x, fmaf(v.y, w.y,
                         fmaf(v.z, w.z, fmaf(v.w, w.w, acc[j]))));
            }
        }
#pragma unroll
        for (int j = 0; j < 32; j++)
            sH2f[e * 260 + og * 32 + j] = silu_f(acc[j]);
    }
    __syncthreads();

    for (int c = 0; c < 3; c++) {
        {
            float acc[16];
#pragma unroll
            for (int j = 0; j < 16; j++) acc[j] = b3[c * 128 + og * 16 + j];
            for (int hq = 0; hq < 64; hq++) {
                const float4 v = *(const float4*)&sH2f[e * 260 + hq * 4];
#pragma unroll
                for (int j = 0; j < 16; j++) {
                    const float4 w = *(const float4*)
                        &W3[(size_t)(c * 128 + og * 16 + j) * 256 + hq * 4];
                    acc[j] = fmaf(v.x, w.x, fmaf(v.y, w.y,
                             fmaf(v.z, w.z, fmaf(v.w, w.w, acc[j]))));
                }
            }
            const float cc = sCc[e];
#pragma unroll
            for (int j = 0; j < 16; j++)
                sXcf[e * 132 + og * 16 + j] = silu_f(acc[j]) * cc;
        }
        __syncthreads();
        {
            const int h  = tid & 127;
            const int eh = tid >> 7;
#pragma unroll 4
            for (int i = 0; i < 16; i++) {
                const int ee = (eh << 4) | i;
                const int s = sS[ee], d = sD[ee];
                const float xv = sXcf[ee * 132 + h];
                const int sb = s * HD + h, db = d * HD + h;
                if (c == 0) {
                    atomicAdd(&MSG[0 * (size_t)NH + sb], xv * Y[0 * (size_t)NH + db]);
                } else if (c == 1) {
#pragma unroll
                    for (int cc2 = 1; cc2 < 4; cc2++)
                        atomicAdd(&MSG[(size_t)cc2 * NH + sb],
                                  xv * Y[(size_t)cc2 * NH + db]);
                } else {
#pragma unroll
                    for (int cc2 = 4; cc2 < 9; cc2++)
                        atomicAdd(&MSG[(size_t)cc2 * NH + sb],
                                  xv * Y[(size_t)cc2 * NH + db]);
                }
            }
        }
        __syncthreads();
    }
}

// ---------------------------------------------------------------------------
// Kernel 2b: node-major gather.  XC bf16.
// ---------------------------------------------------------------------------
__global__ __launch_bounds__(256) void k_gather(
    const short* __restrict__ XC, const float* __restrict__ Y,
    const int* __restrict__ offs, const int* __restrict__ EIDS,
    const int* __restrict__ DSTS, float* __restrict__ MSG)
{
    const int tid = threadIdx.x;
    const int nl  = tid >> 7, h = tid & 127;
    const int n   = blockIdx.x * 2 + nl;
    const int beg = offs[n], end = offs[n + 1];

    float m[9];
#pragma unroll
    for (int c = 0; c < 9; c++) m[c] = 0.f;

    for (int p = beg; p < end; ++p) {
        const int eid = EIDS[p];
        const int dst = DSTS[p];
        const size_t xb = (size_t)eid * 384;
        const float x0 = b2f(XC[xb + h]);
        const float x1 = b2f(XC[xb + 128 + h]);
        const float x2 = b2f(XC[xb + 256 + h]);
        const int yb = dst * HD + h;
        m[0] = fmaf(x0, Y[0 * (size_t)NH + yb], m[0]);
        m[1] = fmaf(x1, Y[1 * (size_t)NH + yb], m[1]);
        m[2] = fmaf(x1, Y[2 * (size_t)NH + yb], m[2]);
        m[3] = fmaf(x1, Y[3 * (size_t)NH + yb], m[3]);
        m[4] = fmaf(x2, Y[4 * (size_t)NH + yb], m[4]);
        m[5] = fmaf(x2, Y[5 * (size_t)NH + yb], m[5]);
        m[6] = fmaf(x2, Y[6 * (size_t)NH + yb], m[6]);
        m[7] = fmaf(x2, Y[7 * (size_t)NH + yb], m[7]);
        m[8] = fmaf(x2, Y[8 * (size_t)NH + yb], m[8]);
    }
    const int base = n * HD + h;
#pragma unroll
    for (int c = 0; c < 9; c++) MSG[(size_t)c * NH + base] = m[c];
}

// ---------------------------------------------------------------------------
static inline size_t align_up(size_t v, size_t a) { return (v + a - 1) & ~(a - 1); }

extern "C" void kernel_launch(void* const* d_in, const int* in_sizes, int n_in,
                              void* d_out, int out_size, void* d_ws, size_t ws_size,
                              hipStream_t stream)
{
    const float* X   = (const float*)d_in[0];
    const float* CH  = (const float*)d_in[1];
    const float* EA  = (const float*)d_in[2];
    const float* EW  = (const float*)d_in[3];
    const float* W1  = (const float*)d_in[4];
    const float* b1  = (const float*)d_in[5];
    const float* W2  = (const float*)d_in[6];
    const float* b2  = (const float*)d_in[7];
    const float* W3  = (const float*)d_in[8];
    const float* b3  = (const float*)d_in[9];
    const float* Wt0 = (const float*)d_in[10];
    const float* Wt1 = (const float*)d_in[11];
    const float* Wt2 = (const float*)d_in[12];
    const float* Wt3 = (const float*)d_in[13];
    const float* Wt4 = (const float*)d_in[14];
    const float* Wt5 = (const float*)d_in[15];
    const int*   EI  = (const int*)d_in[16];
    float* out = (float*)d_out;

    size_t off = 0;
    float* Y    = (float*)((char*)d_ws + off); off = align_up(off + (size_t)9 * NH * 4, 64);
    float* MSG  = (float*)((char*)d_ws + off); off = align_up(off + (size_t)9 * NH * 4, 64);
    int*   cnt  = (int*)((char*)d_ws + off);   off = align_up(off + (size_t)NN * 4, 64);
    int*   cur  = (int*)((char*)d_ws + off);   off = align_up(off + (size_t)NN * 4, 64);
    int*   offs = (int*)((char*)d_ws + off);   off = align_up(off + (size_t)(NN + 1) * 4, 64);
    int*   EIDS = (int*)((char*)d_ws + off);   off = align_up(off + (size_t)EE * 4, 64);
    int*   DSTS = (int*)((char*)d_ws + off);   off = align_up(off + (size_t)EE * 4, 64);
    short* W1b  = (short*)((char*)d_ws + off); off = align_up(off + (size_t)128 * 64 * 2, 64);
    short* W2b  = (short*)((char*)d_ws + off); off = align_up(off + (size_t)256 * 128 * 2, 64);
    short* W3b  = (short*)((char*)d_ws + off); off = align_up(off + (size_t)384 * 256 * 2, 64);
    short* WtPh = (short*)((char*)d_ws + off); off = align_up(off + (size_t)3 * 16384 * 2, 64);
    short* WtPl = (short*)((char*)d_ws + off); off = align_up(off + (size_t)3 * 16384 * 2, 64);
    short* WtFh = (short*)((char*)d_ws + off); off = align_up(off + (size_t)3 * 16384 * 2, 64);
    short* WtFl = (short*)((char*)d_ws + off); off = align_up(off + (size_t)3 * 16384 * 2, 64);
    short* XC   = (short*)((char*)d_ws + off);
    const size_t need = off + (size_t)EE * 384 * 2;

    k_wconv<<<928, 256, 0, stream>>>(W1, W2, W3, Wt0, Wt1, Wt2, Wt3, Wt4, Wt5,
                                     W1b, W2b, W3b, WtPh, WtPl, WtFh, WtFl);
    k_mix<false><<<NN / 16, 256, 73728, stream>>>(X, Y, Y, WtPh, WtPl, Y);

    if (ws_size >= need) {
        hipMemsetAsync(cnt, 0, (size_t)NN * sizeof(int), stream);
        k_count<<<EE / 256, 256, 0, stream>>>(EI, cnt);
        k_scan<<<1, 256, 0, stream>>>(cnt, offs, cur);
        k_fill<<<EE / 256, 256, 0, stream>>>(EI, cur, EIDS, DSTS);
        k_edge_mfma<<<EE / 64, 256, 0, stream>>>(EA, CH, EW, EI,
                                                 W1b, b1, W2b, b2, W3b, b3, XC);
        k_gather<<<NN / 2, 256, 0, stream>>>(XC, Y, offs, EIDS, DSTS, MSG);
    } else {
        hipMemsetAsync(MSG, 0, (size_t)9 * NH * sizeof(float), stream);
        k_edge_atomic<<<EE / 32, 256, 0, stream>>>(EA, CH, EW, EI,
                                                   W1, b1, W2, b2, W3, b3, Y, MSG);
    }

    k_mix<true><<<NN / 16, 256, 73728, stream>>>(X, Y, MSG, WtFh, WtFl, out);
}

// Round 6
// 390.426 us; speedup vs baseline: 20.3220x; 1.5425x over previous
//
#include <hip/hip_runtime.h>

#define NN  10000
#define HD  128
#define EE  160000
#define RD  32
#define NH  (NN * HD)

typedef __attribute__((ext_vector_type(8))) short short8_t;
typedef __attribute__((ext_vector_type(4))) float f32x4_t;
typedef __attribute__((ext_vector_type(4))) int   int4_t;

__device__ __forceinline__ float silu_f(float z) {
    return z / (1.0f + __expf(-z));
}
__device__ __forceinline__ short f2b(float v) {   // RNE fp32->bf16
    unsigned u = __float_as_uint(v);
    unsigned r = (u + 0x7FFFu + ((u >> 16) & 1u)) >> 16;
    return (short)r;
}
__device__ __forceinline__ float b2f(short s) {
    return __uint_as_float(((unsigned)(unsigned short)s) << 16);
}

// ---------------------------------------------------------------------------
// Weight conversion.
//  Edge MLP weights -> bf16 in MFMA-fragment order: element
//  [(ct*KB + kb)*64 + lane]*8 + j  holds  W[n=ct*16+(lane&15)][k=kb*32+(lane>>4)*8+j]
//  so a wave's B-fragment load is one coalesced dwordx4 at base+lane*16B.
//  Mix weights Wt0..Wt5 -> bf16 hi/lo split pairs.
// ---------------------------------------------------------------------------
__global__ __launch_bounds__(256) void k_wconv(
    const float* __restrict__ W1, const float* __restrict__ W2,
    const float* __restrict__ W3,
    const float* __restrict__ Wt0, const float* __restrict__ Wt1,
    const float* __restrict__ Wt2, const float* __restrict__ Wt3,
    const float* __restrict__ Wt4, const float* __restrict__ Wt5,
    short* __restrict__ W1b, short* __restrict__ W2b, short* __restrict__ W3b,
    short* __restrict__ WtPh, short* __restrict__ WtPl,
    short* __restrict__ WtFh, short* __restrict__ WtFl)
{
    const int i = blockIdx.x * 256 + threadIdx.x;
    if (i < 8192) {                       // layer1: ct<8, kb<2, K_in=34
        const int j = i & 7, lane = (i >> 3) & 63;
        const int kb = (i >> 9) & 1, ct = i >> 10;
        const int n = ct * 16 + (lane & 15);
        const int k = kb * 32 + (lane >> 4) * 8 + j;
        W1b[i] = (k < 34) ? f2b(W1[n * 34 + k]) : (short)0;
        return;
    }
    int j2 = i - 8192;
    if (j2 < 32768) {                     // layer2: ct<16, kb<4, K_in=128
        const int j = j2 & 7, lane = (j2 >> 3) & 63;
        const int kb = (j2 >> 9) & 3, ct = j2 >> 11;
        const int n = ct * 16 + (lane & 15);
        const int k = kb * 32 + (lane >> 4) * 8 + j;
        W2b[j2] = f2b(W2[n * 128 + k]);
        return;
    }
    j2 -= 32768;
    if (j2 < 98304) {                     // layer3: ct<24, kb<8, K_in=256
        const int j = j2 & 7, lane = (j2 >> 3) & 63;
        const int kb = (j2 >> 9) & 7, ct = j2 >> 12;
        const int n = ct * 16 + (lane & 15);
        const int k = kb * 32 + (lane >> 4) * 8 + j;
        W3b[j2] = f2b(W3[n * 256 + k]);
        return;
    }
    j2 -= 98304;
    if (j2 < 6 * 16384) {
        const int m = j2 >> 14, idx = j2 & 16383;
        const float* src = (m == 0) ? Wt0 : (m == 1) ? Wt1 : (m == 2) ? Wt2
                         : (m == 3) ? Wt3 : (m == 4) ? Wt4 : Wt5;
        const float w = src[idx];
        const short hi = f2b(w);
        const short lo = f2b(w - b2f(hi));
        if (m < 3) { WtPh[m * 16384 + idx] = hi; WtPl[m * 16384 + idx] = lo; }
        else       { WtFh[(m - 3) * 16384 + idx] = hi; WtFl[(m - 3) * 16384 + idx] = lo; }
    }
}

// ---------------------------------------------------------------------------
// k_mix<FIN>: channel-mix as MFMA GEMM with bf16 hi/lo 3-term split.
// (unchanged from round 4)
// ---------------------------------------------------------------------------
template <bool FIN>
__global__ __launch_bounds__(256) void k_mix(
    const float* __restrict__ X,
    const float* __restrict__ Yin, const float* __restrict__ MSGin,
    const short* __restrict__ Wh,  const short* __restrict__ Wl,
    float* __restrict__ outp)
{
    extern __shared__ __align__(16) char smem[];   // 73728 B
    short* sBh = (short*)smem;                     // [144][128] bf16 hi
    short* sBl = sBh + 144 * 128;                  // [144][128] bf16 lo
    float* sC  = (float*)smem;                     // [144][128] f32 (after GEMM)

    const int tid = threadIdx.x;
    const int n0  = blockIdx.x * 16;

#pragma unroll 2
    for (int i = 0; i < 8; i++) {
        const int p  = i * 256 + tid;
        const int nl = p >> 7, h = p & 127;
        float dec[9];
        if constexpr (!FIN) {
            const float* t = X + ((size_t)((n0 + nl) * HD + h)) * 9;
            float T[9];
#pragma unroll
            for (int q = 0; q < 9; q++) T[q] = t[q];
            float nrm = 0.f;
#pragma unroll
            for (int q = 0; q < 9; q++) nrm = fmaf(T[q], T[q], nrm);
            const float inv = 1.0f / (nrm + 1.0f);
#pragma unroll
            for (int q = 0; q < 9; q++) T[q] *= inv;
            const float I = (T[0] + T[4] + T[8]) * (1.0f / 3.0f);
            dec[0] = I;
            dec[1] = 0.5f * (T[7] - T[5]);
            dec[2] = 0.5f * (T[2] - T[6]);
            dec[3] = 0.5f * (T[3] - T[1]);
            dec[4] = T[0] - I;
            dec[5] = 0.5f * (T[1] + T[3]);
            dec[6] = 0.5f * (T[2] + T[6]);
            dec[7] = T[4] - I;
            dec[8] = 0.5f * (T[5] + T[7]);
        } else {
            const int basep = (n0 + nl) * HD + h;
            float yv[9], mv[9];
#pragma unroll
            for (int c = 0; c < 9; c++) {
                yv[c] = Yin[(size_t)c * NH + basep];
                mv[c] = MSGin[(size_t)c * NH + basep];
            }
            float Yt[9], G[9];
            {
                const float I = yv[0], a0 = yv[1], a1 = yv[2], a2 = yv[3];
                const float s00 = yv[4], s01 = yv[5], s02 = yv[6], s11 = yv[7], s12 = yv[8];
                const float s22 = -s00 - s11;
                Yt[0] = I + s00; Yt[1] = s01 - a2; Yt[2] = s02 + a1;
                Yt[3] = s01 + a2; Yt[4] = I + s11; Yt[5] = s12 - a0;
                Yt[6] = s02 - a1; Yt[7] = s12 + a0; Yt[8] = I + s22;
            }
            {
                const float I = mv[0], a0 = mv[1], a1 = mv[2], a2 = mv[3];
                const float s00 = mv[4], s01 = mv[5], s02 = mv[6], s11 = mv[7], s12 = mv[8];
                const float s22 = -s00 - s11;
                G[0] = I + s00; G[1] = s01 - a2; G[2] = s02 + a1;
                G[3] = s01 + a2; G[4] = I + s11; G[5] = s12 - a0;
                G[6] = s02 - a1; G[7] = s12 + a0; G[8] = I + s22;
            }
            float M[9];
#pragma unroll
            for (int r = 0; r < 3; r++)
#pragma unroll
                for (int cc = 0; cc < 3; cc++) {
                    float a = 0.f;
#pragma unroll
                    for (int k = 0; k < 3; k++)
                        a += G[r * 3 + k] * Yt[k * 3 + cc]
                           + Yt[r * 3 + k] * G[k * 3 + cc];
                    M[r * 3 + cc] = a;
                }
            const float I2 = (M[0] + M[4] + M[8]) * (1.0f / 3.0f);
            const float a0 = 0.5f * (M[7] - M[5]);
            const float a1 = 0.5f * (M[2] - M[6]);
            const float a2 = 0.5f * (M[3] - M[1]);
            const float s00 = M[0] - I2, s11 = M[4] - I2;
            const float s01 = 0.5f * (M[1] + M[3]);
            const float s02 = 0.5f * (M[2] + M[6]);
            const float s12 = 0.5f * (M[5] + M[7]);
            const float s22 = -s00 - s11;
            const float nrm = 2.f * (a0 * a0 + a1 * a1 + a2 * a2)
                            + (s00 * s00 + s11 * s11 + s22 * s22)
                            + 2.f * (s01 * s01 + s02 * s02 + s12 * s12)
                            + 3.f * I2 * I2;
            const float inv = 1.0f / (nrm + 1.0f);
            dec[0] = I2 * inv;  dec[1] = a0 * inv;  dec[2] = a1 * inv;
            dec[3] = a2 * inv;  dec[4] = s00 * inv; dec[5] = s01 * inv;
            dec[6] = s02 * inv; dec[7] = s11 * inv; dec[8] = s12 * inv;
        }
        const int sw = (nl & 7) << 3;
        const int hx = h ^ sw;
#pragma unroll
        for (int c = 0; c < 9; c++) {
            const float v  = dec[c];
            const short hi = f2b(v);
            const short lo = f2b(v - b2f(hi));
            const int idx = (c * 16 + nl) * 128 + hx;
            sBh[idx] = hi;
            sBl[idx] = lo;
        }
    }
    __syncthreads();

    const int lane = tid & 63, wid = tid >> 6;
    const int l15 = lane & 15, g = lane >> 4;
    f32x4_t acc[2][9];
#pragma unroll
    for (int t = 0; t < 2; t++)
#pragma unroll
        for (int c = 0; c < 9; c++) acc[t][c] = {0.f, 0.f, 0.f, 0.f};

    const int bsw = (l15 & 7) << 3;
#pragma unroll
    for (int k = 0; k < 4; k++) {
        const int k0  = k * 32 + g * 8;
        const int ksw = k0 ^ bsw;
#pragma unroll
        for (int w = 0; w < 3; w++) {
            short8_t Ah[2], Al[2];
#pragma unroll
            for (int t = 0; t < 2; t++) {
                const int o = (wid * 2 + t) * 16 + l15;
                const size_t aoff = (size_t)w * 16384 + (size_t)o * 128 + k0;
                Ah[t] = *(const short8_t*)(Wh + aoff);
                Al[t] = *(const short8_t*)(Wl + aoff);
            }
            const int ct0 = (w == 0) ? 0 : (w == 1 ? 1 : 4);
            const int ctn = (w == 0) ? 1 : (w == 1 ? 3 : 5);
            for (int cc = 0; cc < ctn; cc++) {
                const int ct = ct0 + cc;
                const int boff = (ct * 16 + l15) * 128 + ksw;
                const short8_t Bh = *(const short8_t*)&sBh[boff];
                const short8_t Bl = *(const short8_t*)&sBl[boff];
#pragma unroll
                for (int t = 0; t < 2; t++) {
                    acc[t][ct] = __builtin_amdgcn_mfma_f32_16x16x32_bf16(Al[t], Bh, acc[t][ct], 0, 0, 0);
                    acc[t][ct] = __builtin_amdgcn_mfma_f32_16x16x32_bf16(Ah[t], Bl, acc[t][ct], 0, 0, 0);
                    acc[t][ct] = __builtin_amdgcn_mfma_f32_16x16x32_bf16(Ah[t], Bh, acc[t][ct], 0, 0, 0);
                }
            }
        }
    }
    __syncthreads();

    const int csw = (l15 & 7) << 2;
#pragma unroll
    for (int t = 0; t < 2; t++) {
        const int o0 = (wid * 2 + t) * 16 + g * 4;
#pragma unroll
        for (int ct = 0; ct < 9; ct++)
            *(f32x4_t*)&sC[(ct * 16 + l15) * 128 + (o0 ^ csw)] = acc[t][ct];
    }
    __syncthreads();

    if constexpr (!FIN) {
        for (int i = tid; i < 144 * 32; i += 256) {
            const int row = i >> 5, q = i & 31;
            const int c = row >> 4, nl = row & 15;
            const int sw = (nl & 7) << 2;
            const f32x4_t v = *(const f32x4_t*)&sC[row * 128 + ((q * 4) ^ sw)];
            *(f32x4_t*)&outp[(size_t)c * NH + (size_t)(n0 + nl) * HD + q * 4] = v;
        }
    } else {
#pragma unroll 2
        for (int i = 0; i < 8; i++) {
            const int p  = i * 256 + tid;
            const int nl = p >> 7, o = p & 127;
            const int sw = (nl & 7) << 2;
            const int ox = o ^ sw;
            float a9[9];
#pragma unroll
            for (int c = 0; c < 9; c++) a9[c] = sC[(c * 16 + nl) * 128 + ox];
            float D[9];
            {
                const float I = a9[0], a0 = a9[1], a1 = a9[2], a2 = a9[3];
                const float s00 = a9[4], s01 = a9[5], s02 = a9[6];
                const float s11 = a9[7], s12 = a9[8];
                const float s22 = -s00 - s11;
                D[0] = I + s00; D[1] = s01 - a2; D[2] = s02 + a1;
                D[3] = s01 + a2; D[4] = I + s11; D[5] = s12 - a0;
                D[6] = s02 - a1; D[7] = s12 + a0; D[8] = I + s22;
            }
            const size_t xbase = ((size_t)((n0 + nl) * HD + o)) * 9;
            float T[9];
#pragma unroll
            for (int q = 0; q < 9; q++) T[q] = X[xbase + q];
            float nrm = 0.f;
#pragma unroll
            for (int q = 0; q < 9; q++) nrm = fmaf(T[q], T[q], nrm);
            const float inv = 1.0f / (nrm + 1.0f);
            float* op = outp + xbase;
#pragma unroll
            for (int r = 0; r < 3; r++)
#pragma unroll
                for (int cc = 0; cc < 3; cc++) {
                    float dd2 = 0.f;
#pragma unroll
                    for (int k = 0; k < 3; k++)
                        dd2 = fmaf(D[r * 3 + k], D[k * 3 + cc], dd2);
                    op[r * 3 + cc] = T[r * 3 + cc] * inv + D[r * 3 + cc] + dd2;
                }
        }
    }
}

// ---------------------------------------------------------------------------
// CSR build.
// ---------------------------------------------------------------------------
__global__ __launch_bounds__(256) void k_count(const int* __restrict__ EI,
                                               int* __restrict__ cnt)
{
    const int e = blockIdx.x * 256 + threadIdx.x;
    atomicAdd(&cnt[EI[e]], 1);
}

__global__ __launch_bounds__(256) void k_scan(const int* __restrict__ cnt,
                                              int* __restrict__ offs,
                                              int* __restrict__ cur)
{
    __shared__ int part[256];
    const int tid = threadIdx.x;
    const int per = (NN + 255) / 256;
    int s = 0;
    for (int i = 0; i < per; i++) {
        const int idx = tid * per + i;
        if (idx < NN) s += cnt[idx];
    }
    part[tid] = s;
    __syncthreads();
    if (tid == 0) {
        int r = 0;
        for (int i = 0; i < 256; i++) { const int t = part[i]; part[i] = r; r += t; }
        offs[NN] = r;
    }
    __syncthreads();
    int run = part[tid];
    for (int i = 0; i < per; i++) {
        const int idx = tid * per + i;
        if (idx < NN) {
            offs[idx] = run;
            cur[idx]  = run;
            run += cnt[idx];
        }
    }
}

__global__ __launch_bounds__(256) void k_fill(const int* __restrict__ EI,
                                              int* __restrict__ cur,
                                              int* __restrict__ EIDS,
                                              int* __restrict__ DSTS)
{
    const int e = blockIdx.x * 256 + threadIdx.x;
    const int s = EI[e];
    const int pos = atomicAdd(&cur[s], 1);
    EIDS[pos] = e;
    DSTS[pos] = EI[EE + e];
}

// ---------------------------------------------------------------------------
// Kernel 2: MFMA edge MLP, ct-parallel waves.
// 64 edges/block, 4 waves.  Each wave holds A-fragments for ALL 64 edges in
// registers and computes an output-column slice (ct = c*4 + wid), so each
// B-fragment load (coalesced, MFMA-order layout) feeds 4 MFMAs and each
// weight byte is fetched once per BLOCK.  LDS: sIn aliases sH2 (dead after
// layer 1) -> 48.3 KB -> 3 blocks/CU.
// ---------------------------------------------------------------------------
__global__ __launch_bounds__(256, 2) void k_edge_mfma(
    const float* __restrict__ EA, const float* __restrict__ CH,
    const float* __restrict__ EW, const int*   __restrict__ EI,
    const short* __restrict__ W1b, const float* __restrict__ b1,
    const short* __restrict__ W2b, const float* __restrict__ b2,
    const short* __restrict__ W3b, const float* __restrict__ b3,
    short* __restrict__ XC)
{
    __shared__ __align__(16) short sH2[64 * 256];   // 32 KB; first 8 KB = sIn
    __shared__ __align__(16) short sH1[64 * 128];   // 16 KB
    __shared__ float sCut[64];

    short* sIn = sH2;                               // [64][64] alias
    const int tid = threadIdx.x;
    const int e0  = blockIdx.x * 64;

    {   // zero-fill sIn (pad cols 34..63)
        int4_t z = {0, 0, 0, 0};
        ((int4_t*)sIn)[tid]       = z;
        ((int4_t*)sIn)[tid + 256] = z;
    }
    __syncthreads();
    {   // stage edge_attr + charges (bf16, row-XOR swizzle) + cutoff
        for (int i = tid; i < 512; i += 256) {
            const float4 v = ((const float4*)(EA + (size_t)e0 * RD))[i];
            const int e = i >> 3;
            const int k = (i & 7) * 4;
            short4 sv;
            sv.x = f2b(v.x); sv.y = f2b(v.y); sv.z = f2b(v.z); sv.w = f2b(v.w);
            *(short4*)&sIn[e * 64 + (k ^ ((e & 7) << 3))] = sv;
        }
        if (tid < 64) {
            const int e = tid;
            const int s = EI[e0 + e];
            const int d = EI[EE + e0 + e];
            const int sw = (e & 7) << 3;
            sIn[e * 64 + (32 ^ sw)] = f2b(CH[s]);
            sIn[e * 64 + (33 ^ sw)] = f2b(CH[d]);
            const float w = EW[e0 + e];
            sCut[e] = (w < 5.0f)
                    ? 0.5f * (__cosf(0.62831853071795864769f * w) + 1.0f) : 0.0f;
        }
    }
    __syncthreads();

    const int lane = tid & 63;
    const int wid  = tid >> 6;
    const int l15  = lane & 15;
    const int g    = lane >> 4;

    // ---- layer 1: 64x64 @ W1 (64->128); wave does cts {wid, wid+4} ----
    {
        short8_t A1[4][2];
#pragma unroll
        for (int at = 0; at < 4; at++) {
            const int row = at * 16 + l15;
            const int x = (row & 7) << 3;
            A1[at][0] = *(const short8_t*)&sIn[row * 64 + ((g * 8) ^ x)];
            A1[at][1] = *(const short8_t*)&sIn[row * 64 + ((32 + g * 8) ^ x)];
        }
#pragma unroll
        for (int c = 0; c < 2; c++) {
            const int ct = c * 4 + wid;
            const int n  = ct * 16 + l15;
            const float bias = b1[n];
            const short8_t bv0 = *(const short8_t*)(W1b + (size_t)((ct * 2 + 0) * 64 + lane) * 8);
            const short8_t bv1 = *(const short8_t*)(W1b + (size_t)((ct * 2 + 1) * 64 + lane) * 8);
            f32x4_t acc[4];
#pragma unroll
            for (int at = 0; at < 4; at++) {
                acc[at] = {bias, bias, bias, bias};
                acc[at] = __builtin_amdgcn_mfma_f32_16x16x32_bf16(A1[at][0], bv0, acc[at], 0, 0, 0);
                acc[at] = __builtin_amdgcn_mfma_f32_16x16x32_bf16(A1[at][1], bv1, acc[at], 0, 0, 0);
            }
#pragma unroll
            for (int at = 0; at < 4; at++)
#pragma unroll
                for (int r = 0; r < 4; r++) {
                    const int row = at * 16 + g * 4 + r;
                    sH1[row * 128 + (n ^ ((row & 7) << 3))] = f2b(silu_f(acc[at][r]));
                }
        }
    }
    __syncthreads();

    // ---- layer 2: 64x128 @ W2 (128->256); wave does 4 cts ----
    {
        short8_t A2[4][4];
#pragma unroll
        for (int at = 0; at < 4; at++) {
            const int row = at * 16 + l15;
            const int x = (row & 7) << 3;
#pragma unroll
            for (int kb = 0; kb < 4; kb++)
                A2[at][kb] = *(const short8_t*)&sH1[row * 128 + ((kb * 32 + g * 8) ^ x)];
        }
#pragma unroll
        for (int c = 0; c < 4; c++) {
            const int ct = c * 4 + wid;
            const int n  = ct * 16 + l15;
            const float bias = b2[n];
            f32x4_t acc[4];
#pragma unroll
            for (int at = 0; at < 4; at++) acc[at] = {bias, bias, bias, bias};
#pragma unroll
            for (int kb = 0; kb < 4; kb++) {
                const short8_t bv = *(const short8_t*)(W2b + (size_t)((ct * 4 + kb) * 64 + lane) * 8);
#pragma unroll
                for (int at = 0; at < 4; at++)
                    acc[at] = __builtin_amdgcn_mfma_f32_16x16x32_bf16(A2[at][kb], bv, acc[at], 0, 0, 0);
            }
#pragma unroll
            for (int at = 0; at < 4; at++)
#pragma unroll
                for (int r = 0; r < 4; r++) {
                    const int row = at * 16 + g * 4 + r;
                    sH2[row * 256 + (n ^ ((row & 7) << 3))] = f2b(silu_f(acc[at][r]));
                }
        }
    }
    __syncthreads();

    // ---- layer 3: 64x256 @ W3 (256->384); wave does 6 cts; silu*cutoff ----
    {
        short8_t A3[4][8];
#pragma unroll
        for (int at = 0; at < 4; at++) {
            const int row = at * 16 + l15;
            const int x = (row & 7) << 3;
#pragma unroll
            for (int kb = 0; kb < 8; kb++)
                A3[at][kb] = *(const short8_t*)&sH2[row * 256 + ((kb * 32 + g * 8) ^ x)];
        }
        for (int c = 0; c < 6; c++) {
            const int ct = c * 4 + wid;
            const int n  = ct * 16 + l15;
            const float bias = b3[n];
            f32x4_t acc[4];
#pragma unroll
            for (int at = 0; at < 4; at++) acc[at] = {bias, bias, bias, bias};
#pragma unroll
            for (int kb = 0; kb < 8; kb++) {
                const short8_t bv = *(const short8_t*)(W3b + (size_t)((ct * 8 + kb) * 64 + lane) * 8);
#pragma unroll
                for (int at = 0; at < 4; at++)
                    acc[at] = __builtin_amdgcn_mfma_f32_16x16x32_bf16(A3[at][kb], bv, acc[at], 0, 0, 0);
            }
#pragma unroll
            for (int at = 0; at < 4; at++)
#pragma unroll
                for (int r = 0; r < 4; r++) {
                    const int row = at * 16 + g * 4 + r;
                    const float v = silu_f(acc[at][r]) * sCut[row];
                    XC[(size_t)(e0 + row) * 384 + n] = f2b(v);
                }
        }
    }
}

// ---------------------------------------------------------------------------
// Fallback (small ws): fused VALU edge MLP + atomic scatter.
// ---------------------------------------------------------------------------
__global__ __launch_bounds__(256) void k_edge_atomic(
    const float* __restrict__ EA, const float* __restrict__ CH,
    const float* __restrict__ EW, const int*   __restrict__ EI,
    const float* __restrict__ W1, const float* __restrict__ b1,
    const float* __restrict__ W2, const float* __restrict__ b2,
    const float* __restrict__ W3, const float* __restrict__ b3,
    const float* __restrict__ Y,  float* __restrict__ MSG)
{
    __shared__ __align__(16) float sInf[32 * 35];
    __shared__ __align__(16) float sH1f[32 * 132];
    __shared__ __align__(16) float sH2f[32 * 260];
    __shared__ __align__(16) float sXcf[32 * 132];
    __shared__ float sCc[32];
    __shared__ int   sS[32], sD[32];

    const int e0  = blockIdx.x * 32;
    const int tid = threadIdx.x;

    {
        const float4 v = ((const float4*)(EA + (size_t)e0 * RD))[tid];
        const int e = tid >> 3;
        const int k = (tid & 7) * 4;
        float* p = sInf + e * 35 + k;
        p[0] = v.x; p[1] = v.y; p[2] = v.z; p[3] = v.w;
    }
    if (tid < 32) {
        const int e = tid;
        const int s = EI[e0 + e];
        const int d = EI[EE + e0 + e];
        sS[e] = s; sD[e] = d;
        sInf[e * 35 + 32] = CH[s];
        sInf[e * 35 + 33] = CH[d];
        const float w = EW[e0 + e];
        sCc[e] = (w < 5.0f) ? 0.5f * (__cosf(0.62831853071795864769f * w) + 1.0f)
                            : 0.0f;
    }
    __syncthreads();

    const int e  = tid & 31;
    const int og = tid >> 5;

    {
        float acc[16];
#pragma unroll
        for (int j = 0; j < 16; j++) acc[j] = b1[og * 16 + j];
        for (int k = 0; k < 34; k++) {
            const float v = sInf[e * 35 + k];
#pragma unroll
            for (int j = 0; j < 16; j++)
                acc[j] = fmaf(v, W1[(og * 16 + j) * 34 + k], acc[j]);
        }
#pragma unroll
        for (int j = 0; j < 16; j++)
            sH1f[e * 132 + og * 16 + j] = silu_f(acc[j]);
    }
    __syncthreads();

    {
        float acc[32];
#pragma unroll
        for (int j = 0; j < 32; j++) acc[j] = b2[og * 32 + j];
        for (int hq = 0; hq < 32; hq++) {
            const float4 v = *(const float4*)&sH1f[e * 132 + hq * 4];
#pragma unroll
            for (int j = 0; j < 32; j++) {
                const float4 w =
                    *(const float4*)&W2[(size_t)(og * 32 + j) * 128 + hq * 4];
                acc[j] = fmaf(v.x, w.x, fmaf(v.y, w.y,
                         fmaf(v.z, w.z, fmaf(v.w, w.w, acc[j]))));
            }
        }
#pragma unroll
        for (int j = 0; j < 32; j++)
            sH2f[e * 260 + og * 32 + j] = silu_f(acc[j]);
    }
    __syncthreads();

    for (int c = 0; c < 3; c++) {
        {
            float acc[16];
#pragma unroll
            for (int j = 0; j < 16; j++) acc[j] = b3[c * 128 + og * 16 + j];
            for (int hq = 0; hq < 64; hq++) {
                const float4 v = *(const float4*)&sH2f[e * 260 + hq * 4];
#pragma unroll
                for (int j = 0; j < 16; j++) {
                    const float4 w = *(const float4*)
                        &W3[(size_t)(c * 128 + og * 16 + j) * 256 + hq * 4];
                    acc[j] = fmaf(v.x, w.x, fmaf(v.y, w.y,
                             fmaf(v.z, w.z, fmaf(v.w, w.w, acc[j]))));
                }
            }
            const float cc = sCc[e];
#pragma unroll
            for (int j = 0; j < 16; j++)
                sXcf[e * 132 + og * 16 + j] = silu_f(acc[j]) * cc;
        }
        __syncthreads();
        {
            const int h  = tid & 127;
            const int eh = tid >> 7;
#pragma unroll 4
            for (int i = 0; i < 16; i++) {
                const int ee = (eh << 4) | i;
                const int s = sS[ee], d = sD[ee];
                const float xv = sXcf[ee * 132 + h];
                const int sb = s * HD + h, db = d * HD + h;
                if (c == 0) {
                    atomicAdd(&MSG[0 * (size_t)NH + sb], xv * Y[0 * (size_t)NH + db]);
                } else if (c == 1) {
#pragma unroll
                    for (int cc2 = 1; cc2 < 4; cc2++)
                        atomicAdd(&MSG[(size_t)cc2 * NH + sb],
                                  xv * Y[(size_t)cc2 * NH + db]);
                } else {
#pragma unroll
                    for (int cc2 = 4; cc2 < 9; cc2++)
                        atomicAdd(&MSG[(size_t)cc2 * NH + sb],
                                  xv * Y[(size_t)cc2 * NH + db]);
                }
            }
        }
        __syncthreads();
    }
}

// ---------------------------------------------------------------------------
// Kernel 2b: node-major gather.  XC bf16.
// ---------------------------------------------------------------------------
__global__ __launch_bounds__(256) void k_gather(
    const short* __restrict__ XC, const float* __restrict__ Y,
    const int* __restrict__ offs, const int* __restrict__ EIDS,
    const int* __restrict__ DSTS, float* __restrict__ MSG)
{
    const int tid = threadIdx.x;
    const int nl  = tid >> 7, h = tid & 127;
    const int n   = blockIdx.x * 2 + nl;
    const int beg = offs[n], end = offs[n + 1];

    float m[9];
#pragma unroll
    for (int c = 0; c < 9; c++) m[c] = 0.f;

    for (int p = beg; p < end; ++p) {
        const int eid = EIDS[p];
        const int dst = DSTS[p];
        const size_t xb = (size_t)eid * 384;
        const float x0 = b2f(XC[xb + h]);
        const float x1 = b2f(XC[xb + 128 + h]);
        const float x2 = b2f(XC[xb + 256 + h]);
        const int yb = dst * HD + h;
        m[0] = fmaf(x0, Y[0 * (size_t)NH + yb], m[0]);
        m[1] = fmaf(x1, Y[1 * (size_t)NH + yb], m[1]);
        m[2] = fmaf(x1, Y[2 * (size_t)NH + yb], m[2]);
        m[3] = fmaf(x1, Y[3 * (size_t)NH + yb], m[3]);
        m[4] = fmaf(x2, Y[4 * (size_t)NH + yb], m[4]);
        m[5] = fmaf(x2, Y[5 * (size_t)NH + yb], m[5]);
        m[6] = fmaf(x2, Y[6 * (size_t)NH + yb], m[6]);
        m[7] = fmaf(x2, Y[7 * (size_t)NH + yb], m[7]);
        m[8] = fmaf(x2, Y[8 * (size_t)NH + yb], m[8]);
    }
    const int base = n * HD + h;
#pragma unroll
    for (int c = 0; c < 9; c++) MSG[(size_t)c * NH + base] = m[c];
}

// ---------------------------------------------------------------------------
static inline size_t align_up(size_t v, size_t a) { return (v + a - 1) & ~(a - 1); }

extern "C" void kernel_launch(void* const* d_in, const int* in_sizes, int n_in,
                              void* d_out, int out_size, void* d_ws, size_t ws_size,
                              hipStream_t stream)
{
    const float* X   = (const float*)d_in[0];
    const float* CH  = (const float*)d_in[1];
    const float* EA  = (const float*)d_in[2];
    const float* EW  = (const float*)d_in[3];
    const float* W1  = (const float*)d_in[4];
    const float* b1  = (const float*)d_in[5];
    const float* W2  = (const float*)d_in[6];
    const float* b2  = (const float*)d_in[7];
    const float* W3  = (const float*)d_in[8];
    const float* b3  = (const float*)d_in[9];
    const float* Wt0 = (const float*)d_in[10];
    const float* Wt1 = (const float*)d_in[11];
    const float* Wt2 = (const float*)d_in[12];
    const float* Wt3 = (const float*)d_in[13];
    const float* Wt4 = (const float*)d_in[14];
    const float* Wt5 = (const float*)d_in[15];
    const int*   EI  = (const int*)d_in[16];
    float* out = (float*)d_out;

    size_t off = 0;
    float* Y    = (float*)((char*)d_ws + off); off = align_up(off + (size_t)9 * NH * 4, 64);
    float* MSG  = (float*)((char*)d_ws + off); off = align_up(off + (size_t)9 * NH * 4, 64);
    int*   cnt  = (int*)((char*)d_ws + off);   off = align_up(off + (size_t)NN * 4, 64);
    int*   cur  = (int*)((char*)d_ws + off);   off = align_up(off + (size_t)NN * 4, 64);
    int*   offs = (int*)((char*)d_ws + off);   off = align_up(off + (size_t)(NN + 1) * 4, 64);
    int*   EIDS = (int*)((char*)d_ws + off);   off = align_up(off + (size_t)EE * 4, 64);
    int*   DSTS = (int*)((char*)d_ws + off);   off = align_up(off + (size_t)EE * 4, 64);
    short* W1b  = (short*)((char*)d_ws + off); off = align_up(off + (size_t)8192 * 2, 64);
    short* W2b  = (short*)((char*)d_ws + off); off = align_up(off + (size_t)32768 * 2, 64);
    short* W3b  = (short*)((char*)d_ws + off); off = align_up(off + (size_t)98304 * 2, 64);
    short* WtPh = (short*)((char*)d_ws + off); off = align_up(off + (size_t)3 * 16384 * 2, 64);
    short* WtPl = (short*)((char*)d_ws + off); off = align_up(off + (size_t)3 * 16384 * 2, 64);
    short* WtFh = (short*)((char*)d_ws + off); off = align_up(off + (size_t)3 * 16384 * 2, 64);
    short* WtFl = (short*)((char*)d_ws + off); off = align_up(off + (size_t)3 * 16384 * 2, 64);
    short* XC   = (short*)((char*)d_ws + off);
    const size_t need = off + (size_t)EE * 384 * 2;

    k_wconv<<<928, 256, 0, stream>>>(W1, W2, W3, Wt0, Wt1, Wt2, Wt3, Wt4, Wt5,
                                     W1b, W2b, W3b, WtPh, WtPl, WtFh, WtFl);
    k_mix<false><<<NN / 16, 256, 73728, stream>>>(X, Y, Y, WtPh, WtPl, Y);

    if (ws_size >= need) {
        hipMemsetAsync(cnt, 0, (size_t)NN * sizeof(int), stream);
        k_count<<<EE / 256, 256, 0, stream>>>(EI, cnt);
        k_scan<<<1, 256, 0, stream>>>(cnt, offs, cur);
        k_fill<<<EE / 256, 256, 0, stream>>>(EI, cur, EIDS, DSTS);
        k_edge_mfma<<<EE / 64, 256, 0, stream>>>(EA, CH, EW, EI,
                                                 W1b, b1, W2b, b2, W3b, b3, XC);
        k_gather<<<NN / 2, 256, 0, stream>>>(XC, Y, offs, EIDS, DSTS, MSG);
    } else {
        hipMemsetAsync(MSG, 0, (size_t)9 * NH * sizeof(float), stream);
        k_edge_atomic<<<EE / 32, 256, 0, stream>>>(EA, CH, EW, EI,
                                                   W1, b1, W2, b2, W3, b3, Y, MSG);
    }

    k_mix<true><<<NN / 16, 256, 73728, stream>>>(X, Y, MSG, WtFh, WtFl, out);
}

// Round 7
// 348.691 us; speedup vs baseline: 22.7543x; 1.1197x over previous
//
#include <hip/hip_runtime.h>

#define NN  10000
#define HD  128
#define EE  160000
#define RD  32
#define NH  (NN * HD)

typedef __attribute__((ext_vector_type(8))) short short8_t;
typedef __attribute__((ext_vector_type(4))) float f32x4_t;
typedef __attribute__((ext_vector_type(4))) int   int4_t;

__device__ __forceinline__ float silu_f(float z) {
    return z / (1.0f + __expf(-z));
}
__device__ __forceinline__ short f2b(float v) {   // RNE fp32->bf16
    unsigned u = __float_as_uint(v);
    unsigned r = (u + 0x7FFFu + ((u >> 16) & 1u)) >> 16;
    return (short)r;
}
__device__ __forceinline__ float b2f(short s) {
    return __uint_as_float(((unsigned)(unsigned short)s) << 16);
}
// HW packed convert: bits[15:0]=bf16(lo), bits[31:16]=bf16(hi), RNE.
__device__ __forceinline__ unsigned cvt_pk(float lo, float hi) {
    unsigned r;
    asm("v_cvt_pk_bf16_f32 %0, %1, %2" : "=v"(r) : "v"(lo), "v"(hi));
    return r;
}

// ---------------------------------------------------------------------------
// Weight conversion (unchanged from round 5).
// ---------------------------------------------------------------------------
__global__ __launch_bounds__(256) void k_wconv(
    const float* __restrict__ W1, const float* __restrict__ W2,
    const float* __restrict__ W3,
    const float* __restrict__ Wt0, const float* __restrict__ Wt1,
    const float* __restrict__ Wt2, const float* __restrict__ Wt3,
    const float* __restrict__ Wt4, const float* __restrict__ Wt5,
    short* __restrict__ W1b, short* __restrict__ W2b, short* __restrict__ W3b,
    short* __restrict__ WtPh, short* __restrict__ WtPl,
    short* __restrict__ WtFh, short* __restrict__ WtFl)
{
    const int i = blockIdx.x * 256 + threadIdx.x;
    if (i < 8192) {                       // layer1: ct<8, kb<2, K_in=34
        const int j = i & 7, lane = (i >> 3) & 63;
        const int kb = (i >> 9) & 1, ct = i >> 10;
        const int n = ct * 16 + (lane & 15);
        const int k = kb * 32 + (lane >> 4) * 8 + j;
        W1b[i] = (k < 34) ? f2b(W1[n * 34 + k]) : (short)0;
        return;
    }
    int j2 = i - 8192;
    if (j2 < 32768) {                     // layer2: ct<16, kb<4, K_in=128
        const int j = j2 & 7, lane = (j2 >> 3) & 63;
        const int kb = (j2 >> 9) & 3, ct = j2 >> 11;
        const int n = ct * 16 + (lane & 15);
        const int k = kb * 32 + (lane >> 4) * 8 + j;
        W2b[j2] = f2b(W2[n * 128 + k]);
        return;
    }
    j2 -= 32768;
    if (j2 < 98304) {                     // layer3: ct<24, kb<8, K_in=256
        const int j = j2 & 7, lane = (j2 >> 3) & 63;
        const int kb = (j2 >> 9) & 7, ct = j2 >> 12;
        const int n = ct * 16 + (lane & 15);
        const int k = kb * 32 + (lane >> 4) * 8 + j;
        W3b[j2] = f2b(W3[n * 256 + k]);
        return;
    }
    j2 -= 98304;
    if (j2 < 6 * 16384) {
        const int m = j2 >> 14, idx = j2 & 16383;
        const float* src = (m == 0) ? Wt0 : (m == 1) ? Wt1 : (m == 2) ? Wt2
                         : (m == 3) ? Wt3 : (m == 4) ? Wt4 : Wt5;
        const float w = src[idx];
        const short hi = f2b(w);
        const short lo = f2b(w - b2f(hi));
        if (m < 3) { WtPh[m * 16384 + idx] = hi; WtPl[m * 16384 + idx] = lo; }
        else       { WtFh[(m - 3) * 16384 + idx] = hi; WtFl[(m - 3) * 16384 + idx] = lo; }
    }
}

// ---------------------------------------------------------------------------
// k_mix<FIN, WB>: channel-mix as MFMA GEMM with bf16 hi/lo 3-term split.
// WB: additionally emit bf16 copies of the Y planes (for the gather).
// ---------------------------------------------------------------------------
template <bool FIN, bool WB>
__global__ __launch_bounds__(256) void k_mix(
    const float* __restrict__ X,
    const float* __restrict__ Yin, const float* __restrict__ MSGin,
    const short* __restrict__ Wh,  const short* __restrict__ Wl,
    float* __restrict__ outp, short* __restrict__ ybf)
{
    extern __shared__ __align__(16) char smem[];   // 73728 B
    short* sBh = (short*)smem;                     // [144][128] bf16 hi
    short* sBl = sBh + 144 * 128;                  // [144][128] bf16 lo
    float* sC  = (float*)smem;                     // [144][128] f32 (after GEMM)

    const int tid = threadIdx.x;
    const int n0  = blockIdx.x * 16;

#pragma unroll 2
    for (int i = 0; i < 8; i++) {
        const int p  = i * 256 + tid;
        const int nl = p >> 7, h = p & 127;
        float dec[9];
        if constexpr (!FIN) {
            const float* t = X + ((size_t)((n0 + nl) * HD + h)) * 9;
            float T[9];
#pragma unroll
            for (int q = 0; q < 9; q++) T[q] = t[q];
            float nrm = 0.f;
#pragma unroll
            for (int q = 0; q < 9; q++) nrm = fmaf(T[q], T[q], nrm);
            const float inv = 1.0f / (nrm + 1.0f);
#pragma unroll
            for (int q = 0; q < 9; q++) T[q] *= inv;
            const float I = (T[0] + T[4] + T[8]) * (1.0f / 3.0f);
            dec[0] = I;
            dec[1] = 0.5f * (T[7] - T[5]);
            dec[2] = 0.5f * (T[2] - T[6]);
            dec[3] = 0.5f * (T[3] - T[1]);
            dec[4] = T[0] - I;
            dec[5] = 0.5f * (T[1] + T[3]);
            dec[6] = 0.5f * (T[2] + T[6]);
            dec[7] = T[4] - I;
            dec[8] = 0.5f * (T[5] + T[7]);
        } else {
            const int basep = (n0 + nl) * HD + h;
            float yv[9], mv[9];
#pragma unroll
            for (int c = 0; c < 9; c++) {
                yv[c] = Yin[(size_t)c * NH + basep];
                mv[c] = MSGin[(size_t)c * NH + basep];
            }
            float Yt[9], G[9];
            {
                const float I = yv[0], a0 = yv[1], a1 = yv[2], a2 = yv[3];
                const float s00 = yv[4], s01 = yv[5], s02 = yv[6], s11 = yv[7], s12 = yv[8];
                const float s22 = -s00 - s11;
                Yt[0] = I + s00; Yt[1] = s01 - a2; Yt[2] = s02 + a1;
                Yt[3] = s01 + a2; Yt[4] = I + s11; Yt[5] = s12 - a0;
                Yt[6] = s02 - a1; Yt[7] = s12 + a0; Yt[8] = I + s22;
            }
            {
                const float I = mv[0], a0 = mv[1], a1 = mv[2], a2 = mv[3];
                const float s00 = mv[4], s01 = mv[5], s02 = mv[6], s11 = mv[7], s12 = mv[8];
                const float s22 = -s00 - s11;
                G[0] = I + s00; G[1] = s01 - a2; G[2] = s02 + a1;
                G[3] = s01 + a2; G[4] = I + s11; G[5] = s12 - a0;
                G[6] = s02 - a1; G[7] = s12 + a0; G[8] = I + s22;
            }
            float M[9];
#pragma unroll
            for (int r = 0; r < 3; r++)
#pragma unroll
                for (int cc = 0; cc < 3; cc++) {
                    float a = 0.f;
#pragma unroll
                    for (int k = 0; k < 3; k++)
                        a += G[r * 3 + k] * Yt[k * 3 + cc]
                           + Yt[r * 3 + k] * G[k * 3 + cc];
                    M[r * 3 + cc] = a;
                }
            const float I2 = (M[0] + M[4] + M[8]) * (1.0f / 3.0f);
            const float a0 = 0.5f * (M[7] - M[5]);
            const float a1 = 0.5f * (M[2] - M[6]);
            const float a2 = 0.5f * (M[3] - M[1]);
            const float s00 = M[0] - I2, s11 = M[4] - I2;
            const float s01 = 0.5f * (M[1] + M[3]);
            const float s02 = 0.5f * (M[2] + M[6]);
            const float s12 = 0.5f * (M[5] + M[7]);
            const float s22 = -s00 - s11;
            const float nrm = 2.f * (a0 * a0 + a1 * a1 + a2 * a2)
                            + (s00 * s00 + s11 * s11 + s22 * s22)
                            + 2.f * (s01 * s01 + s02 * s02 + s12 * s12)
                            + 3.f * I2 * I2;
            const float inv = 1.0f / (nrm + 1.0f);
            dec[0] = I2 * inv;  dec[1] = a0 * inv;  dec[2] = a1 * inv;
            dec[3] = a2 * inv;  dec[4] = s00 * inv; dec[5] = s01 * inv;
            dec[6] = s02 * inv; dec[7] = s11 * inv; dec[8] = s12 * inv;
        }
        const int sw = (nl & 7) << 3;
        const int hx = h ^ sw;
#pragma unroll
        for (int c = 0; c < 9; c++) {
            const float v  = dec[c];
            const short hi = f2b(v);
            const short lo = f2b(v - b2f(hi));
            const int idx = (c * 16 + nl) * 128 + hx;
            sBh[idx] = hi;
            sBl[idx] = lo;
        }
    }
    __syncthreads();

    const int lane = tid & 63, wid = tid >> 6;
    const int l15 = lane & 15, g = lane >> 4;
    f32x4_t acc[2][9];
#pragma unroll
    for (int t = 0; t < 2; t++)
#pragma unroll
        for (int c = 0; c < 9; c++) acc[t][c] = {0.f, 0.f, 0.f, 0.f};

    const int bsw = (l15 & 7) << 3;
#pragma unroll
    for (int k = 0; k < 4; k++) {
        const int k0  = k * 32 + g * 8;
        const int ksw = k0 ^ bsw;
#pragma unroll
        for (int w = 0; w < 3; w++) {
            short8_t Ah[2], Al[2];
#pragma unroll
            for (int t = 0; t < 2; t++) {
                const int o = (wid * 2 + t) * 16 + l15;
                const size_t aoff = (size_t)w * 16384 + (size_t)o * 128 + k0;
                Ah[t] = *(const short8_t*)(Wh + aoff);
                Al[t] = *(const short8_t*)(Wl + aoff);
            }
            const int ct0 = (w == 0) ? 0 : (w == 1 ? 1 : 4);
            const int ctn = (w == 0) ? 1 : (w == 1 ? 3 : 5);
            for (int cc = 0; cc < ctn; cc++) {
                const int ct = ct0 + cc;
                const int boff = (ct * 16 + l15) * 128 + ksw;
                const short8_t Bh = *(const short8_t*)&sBh[boff];
                const short8_t Bl = *(const short8_t*)&sBl[boff];
#pragma unroll
                for (int t = 0; t < 2; t++) {
                    acc[t][ct] = __builtin_amdgcn_mfma_f32_16x16x32_bf16(Al[t], Bh, acc[t][ct], 0, 0, 0);
                    acc[t][ct] = __builtin_amdgcn_mfma_f32_16x16x32_bf16(Ah[t], Bl, acc[t][ct], 0, 0, 0);
                    acc[t][ct] = __builtin_amdgcn_mfma_f32_16x16x32_bf16(Ah[t], Bh, acc[t][ct], 0, 0, 0);
                }
            }
        }
    }
    __syncthreads();

    const int csw = (l15 & 7) << 2;
#pragma unroll
    for (int t = 0; t < 2; t++) {
        const int o0 = (wid * 2 + t) * 16 + g * 4;
#pragma unroll
        for (int ct = 0; ct < 9; ct++)
            *(f32x4_t*)&sC[(ct * 16 + l15) * 128 + (o0 ^ csw)] = acc[t][ct];
    }
    __syncthreads();

    if constexpr (!FIN) {
        for (int i = tid; i < 144 * 32; i += 256) {
            const int row = i >> 5, q = i & 31;
            const int c = row >> 4, nl = row & 15;
            const int sw = (nl & 7) << 2;
            const f32x4_t v = *(const f32x4_t*)&sC[row * 128 + ((q * 4) ^ sw)];
            const size_t o = (size_t)c * NH + (size_t)(n0 + nl) * HD + q * 4;
            *(f32x4_t*)&outp[o] = v;
            if constexpr (WB) {
                uint2 u;
                u.x = cvt_pk(v[0], v[1]);
                u.y = cvt_pk(v[2], v[3]);
                *(uint2*)&ybf[o] = u;
            }
        }
    } else {
#pragma unroll 2
        for (int i = 0; i < 8; i++) {
            const int p  = i * 256 + tid;
            const int nl = p >> 7, o = p & 127;
            const int sw = (nl & 7) << 2;
            const int ox = o ^ sw;
            float a9[9];
#pragma unroll
            for (int c = 0; c < 9; c++) a9[c] = sC[(c * 16 + nl) * 128 + ox];
            float D[9];
            {
                const float I = a9[0], a0 = a9[1], a1 = a9[2], a2 = a9[3];
                const float s00 = a9[4], s01 = a9[5], s02 = a9[6];
                const float s11 = a9[7], s12 = a9[8];
                const float s22 = -s00 - s11;
                D[0] = I + s00; D[1] = s01 - a2; D[2] = s02 + a1;
                D[3] = s01 + a2; D[4] = I + s11; D[5] = s12 - a0;
                D[6] = s02 - a1; D[7] = s12 + a0; D[8] = I + s22;
            }
            const size_t xbase = ((size_t)((n0 + nl) * HD + o)) * 9;
            float T[9];
#pragma unroll
            for (int q = 0; q < 9; q++) T[q] = X[xbase + q];
            float nrm = 0.f;
#pragma unroll
            for (int q = 0; q < 9; q++) nrm = fmaf(T[q], T[q], nrm);
            const float inv = 1.0f / (nrm + 1.0f);
            float* op = outp + xbase;
#pragma unroll
            for (int r = 0; r < 3; r++)
#pragma unroll
                for (int cc = 0; cc < 3; cc++) {
                    float dd2 = 0.f;
#pragma unroll
                    for (int k = 0; k < 3; k++)
                        dd2 = fmaf(D[r * 3 + k], D[k * 3 + cc], dd2);
                    op[r * 3 + cc] = T[r * 3 + cc] * inv + D[r * 3 + cc] + dd2;
                }
        }
    }
}

// ---------------------------------------------------------------------------
// CSR build.
// ---------------------------------------------------------------------------
__global__ __launch_bounds__(256) void k_count(const int* __restrict__ EI,
                                               int* __restrict__ cnt)
{
    const int e = blockIdx.x * 256 + threadIdx.x;
    atomicAdd(&cnt[EI[e]], 1);
}

__global__ __launch_bounds__(256) void k_scan(const int* __restrict__ cnt,
                                              int* __restrict__ offs,
                                              int* __restrict__ cur)
{
    __shared__ int part[256];
    const int tid = threadIdx.x;
    const int per = (NN + 255) / 256;
    int s = 0;
    for (int i = 0; i < per; i++) {
        const int idx = tid * per + i;
        if (idx < NN) s += cnt[idx];
    }
    part[tid] = s;
    __syncthreads();
    if (tid == 0) {
        int r = 0;
        for (int i = 0; i < 256; i++) { const int t = part[i]; part[i] = r; r += t; }
        offs[NN] = r;
    }
    __syncthreads();
    int run = part[tid];
    for (int i = 0; i < per; i++) {
        const int idx = tid * per + i;
        if (idx < NN) {
            offs[idx] = run;
            cur[idx]  = run;
            run += cnt[idx];
        }
    }
}

__global__ __launch_bounds__(256) void k_fill(const int* __restrict__ EI,
                                              int* __restrict__ cur,
                                              int* __restrict__ EIDS,
                                              int* __restrict__ DSTS)
{
    const int e = blockIdx.x * 256 + threadIdx.x;
    const int s = EI[e];
    const int pos = atomicAdd(&cur[s], 1);
    EIDS[pos] = e;
    DSTS[pos] = EI[EE + e];
}

// ---------------------------------------------------------------------------
// Kernel 2: MFMA edge MLP, ct-parallel waves (round-5 structure) with
//  - cvt_pk paired bf16 conversions (epilogues)
//  - (row&15)<<3 LDS swizzle on sH1/sH2 (conflict-free across 16 rows)
// ---------------------------------------------------------------------------
__global__ __launch_bounds__(256, 2) void k_edge_mfma(
    const float* __restrict__ EA, const float* __restrict__ CH,
    const float* __restrict__ EW, const int*   __restrict__ EI,
    const short* __restrict__ W1b, const float* __restrict__ b1,
    const short* __restrict__ W2b, const float* __restrict__ b2,
    const short* __restrict__ W3b, const float* __restrict__ b3,
    short* __restrict__ XC)
{
    __shared__ __align__(16) short sH2[64 * 256];   // 32 KB; first 8 KB = sIn
    __shared__ __align__(16) short sH1[64 * 128];   // 16 KB
    __shared__ float sCut[64];

    short* sIn = sH2;                               // [64][64] alias
    const int tid = threadIdx.x;
    const int e0  = blockIdx.x * 64;

    {   // zero-fill sIn (pad cols 34..63)
        int4_t z = {0, 0, 0, 0};
        ((int4_t*)sIn)[tid]       = z;
        ((int4_t*)sIn)[tid + 256] = z;
    }
    __syncthreads();
    {   // stage edge_attr + charges (bf16, (e&7)<<3 swizzle) + cutoff
        for (int i = tid; i < 512; i += 256) {
            const float4 v = ((const float4*)(EA + (size_t)e0 * RD))[i];
            const int e = i >> 3;
            const int k = (i & 7) * 4;
            short4 sv;
            sv.x = f2b(v.x); sv.y = f2b(v.y); sv.z = f2b(v.z); sv.w = f2b(v.w);
            *(short4*)&sIn[e * 64 + (k ^ ((e & 7) << 3))] = sv;
        }
        if (tid < 64) {
            const int e = tid;
            const int s = EI[e0 + e];
            const int d = EI[EE + e0 + e];
            const int sw = (e & 7) << 3;
            sIn[e * 64 + (32 ^ sw)] = f2b(CH[s]);
            sIn[e * 64 + (33 ^ sw)] = f2b(CH[d]);
            const float w = EW[e0 + e];
            sCut[e] = (w < 5.0f)
                    ? 0.5f * (__cosf(0.62831853071795864769f * w) + 1.0f) : 0.0f;
        }
    }
    __syncthreads();

    const int lane = tid & 63;
    const int wid  = tid >> 6;
    const int l15  = lane & 15;
    const int g    = lane >> 4;

    // ---- layer 1: 64x64 @ W1 (64->128); wave does cts {wid, wid+4} ----
    {
        short8_t A1[4][2];
#pragma unroll
        for (int at = 0; at < 4; at++) {
            const int row = at * 16 + l15;
            const int x = (row & 7) << 3;
            A1[at][0] = *(const short8_t*)&sIn[row * 64 + ((g * 8) ^ x)];
            A1[at][1] = *(const short8_t*)&sIn[row * 64 + ((32 + g * 8) ^ x)];
        }
#pragma unroll
        for (int c = 0; c < 2; c++) {
            const int ct = c * 4 + wid;
            const int n  = ct * 16 + l15;
            const float bias = b1[n];
            const short8_t bv0 = *(const short8_t*)(W1b + (size_t)((ct * 2 + 0) * 64 + lane) * 8);
            const short8_t bv1 = *(const short8_t*)(W1b + (size_t)((ct * 2 + 1) * 64 + lane) * 8);
            f32x4_t acc[4];
#pragma unroll
            for (int at = 0; at < 4; at++) {
                acc[at] = {bias, bias, bias, bias};
                acc[at] = __builtin_amdgcn_mfma_f32_16x16x32_bf16(A1[at][0], bv0, acc[at], 0, 0, 0);
                acc[at] = __builtin_amdgcn_mfma_f32_16x16x32_bf16(A1[at][1], bv1, acc[at], 0, 0, 0);
            }
#pragma unroll
            for (int at = 0; at < 4; at++)
#pragma unroll
                for (int rp = 0; rp < 2; rp++) {
                    const int rowA = at * 16 + g * 4 + rp * 2;
                    const int rowB = rowA + 1;
                    const unsigned pk = cvt_pk(silu_f(acc[at][rp * 2]),
                                               silu_f(acc[at][rp * 2 + 1]));
                    sH1[rowA * 128 + (n ^ ((rowA & 15) << 3))] = (short)pk;
                    sH1[rowB * 128 + (n ^ ((rowB & 15) << 3))] = (short)(pk >> 16);
                }
        }
    }
    __syncthreads();

    // ---- layer 2: 64x128 @ W2 (128->256); wave does 4 cts ----
    {
        short8_t A2[4][4];
#pragma unroll
        for (int at = 0; at < 4; at++) {
            const int row = at * 16 + l15;
            const int x = (row & 15) << 3;
#pragma unroll
            for (int kb = 0; kb < 4; kb++)
                A2[at][kb] = *(const short8_t*)&sH1[row * 128 + ((kb * 32 + g * 8) ^ x)];
        }
#pragma unroll
        for (int c = 0; c < 4; c++) {
            const int ct = c * 4 + wid;
            const int n  = ct * 16 + l15;
            const float bias = b2[n];
            f32x4_t acc[4];
#pragma unroll
            for (int at = 0; at < 4; at++) acc[at] = {bias, bias, bias, bias};
#pragma unroll
            for (int kb = 0; kb < 4; kb++) {
                const short8_t bv = *(const short8_t*)(W2b + (size_t)((ct * 4 + kb) * 64 + lane) * 8);
#pragma unroll
                for (int at = 0; at < 4; at++)
                    acc[at] = __builtin_amdgcn_mfma_f32_16x16x32_bf16(A2[at][kb], bv, acc[at], 0, 0, 0);
            }
#pragma unroll
            for (int at = 0; at < 4; at++)
#pragma unroll
                for (int rp = 0; rp < 2; rp++) {
                    const int rowA = at * 16 + g * 4 + rp * 2;
                    const int rowB = rowA + 1;
                    const unsigned pk = cvt_pk(silu_f(acc[at][rp * 2]),
                                               silu_f(acc[at][rp * 2 + 1]));
                    sH2[rowA * 256 + (n ^ ((rowA & 15) << 3))] = (short)pk;
                    sH2[rowB * 256 + (n ^ ((rowB & 15) << 3))] = (short)(pk >> 16);
                }
        }
    }
    __syncthreads();

    // ---- layer 3: 64x256 @ W3 (256->384); wave does 6 cts; silu*cutoff ----
    {
        short8_t A3[4][8];
#pragma unroll
        for (int at = 0; at < 4; at++) {
            const int row = at * 16 + l15;
            const int x = (row & 15) << 3;
#pragma unroll
            for (int kb = 0; kb < 8; kb++)
                A3[at][kb] = *(const short8_t*)&sH2[row * 256 + ((kb * 32 + g * 8) ^ x)];
        }
        for (int c = 0; c < 6; c++) {
            const int ct = c * 4 + wid;
            const int n  = ct * 16 + l15;
            const float bias = b3[n];
            f32x4_t acc[4];
#pragma unroll
            for (int at = 0; at < 4; at++) acc[at] = {bias, bias, bias, bias};
#pragma unroll
            for (int kb = 0; kb < 8; kb++) {
                const short8_t bv = *(const short8_t*)(W3b + (size_t)((ct * 8 + kb) * 64 + lane) * 8);
#pragma unroll
                for (int at = 0; at < 4; at++)
                    acc[at] = __builtin_amdgcn_mfma_f32_16x16x32_bf16(A3[at][kb], bv, acc[at], 0, 0, 0);
            }
#pragma unroll
            for (int at = 0; at < 4; at++)
#pragma unroll
                for (int rp = 0; rp < 2; rp++) {
                    const int rowA = at * 16 + g * 4 + rp * 2;
                    const int rowB = rowA + 1;
                    const float v0 = silu_f(acc[at][rp * 2])     * sCut[rowA];
                    const float v1 = silu_f(acc[at][rp * 2 + 1]) * sCut[rowB];
                    const unsigned pk = cvt_pk(v0, v1);
                    XC[(size_t)(e0 + rowA) * 384 + n] = (short)pk;
                    XC[(size_t)(e0 + rowB) * 384 + n] = (short)(pk >> 16);
                }
        }
    }
}

// ---------------------------------------------------------------------------
// Fallback (small ws): fused VALU edge MLP + atomic scatter.
// ---------------------------------------------------------------------------
__global__ __launch_bounds__(256) void k_edge_atomic(
    const float* __restrict__ EA, const float* __restrict__ CH,
    const float* __restrict__ EW, const int*   __restrict__ EI,
    const float* __restrict__ W1, const float* __restrict__ b1,
    const float* __restrict__ W2, const float* __restrict__ b2,
    const float* __restrict__ W3, const float* __restrict__ b3,
    const float* __restrict__ Y,  float* __restrict__ MSG)
{
    __shared__ __align__(16) float sInf[32 * 35];
    __shared__ __align__(16) float sH1f[32 * 132];
    __shared__ __align__(16) float sH2f[32 * 260];
    __shared__ __align__(16) float sXcf[32 * 132];
    __shared__ float sCc[32];
    __shared__ int   sS[32], sD[32];

    const int e0  = blockIdx.x * 32;
    const int tid = threadIdx.x;

    {
        const float4 v = ((const float4*)(EA + (size_t)e0 * RD))[tid];
        const int e = tid >> 3;
        const int k = (tid & 7) * 4;
        float* p = sInf + e * 35 + k;
        p[0] = v.x; p[1] = v.y; p[2] = v.z; p[3] = v.w;
    }
    if (tid < 32) {
        const int e = tid;
        const int s = EI[e0 + e];
        const int d = EI[EE + e0 + e];
        sS[e] = s; sD[e] = d;
        sInf[e * 35 + 32] = CH[s];
        sInf[e * 35 + 33] = CH[d];
        const float w = EW[e0 + e];
        sCc[e] = (w < 5.0f) ? 0.5f * (__cosf(0.62831853071795864769f * w) + 1.0f)
                            : 0.0f;
    }
    __syncthreads();

    const int e  = tid & 31;
    const int og = tid >> 5;

    {
        float acc[16];
#pragma unroll
        for (int j = 0; j < 16; j++) acc[j] = b1[og * 16 + j];
        for (int k = 0; k < 34; k++) {
            const float v = sInf[e * 35 + k];
#pragma unroll
            for (int j = 0; j < 16; j++)
                acc[j] = fmaf(v, W1[(og * 16 + j) * 34 + k], acc[j]);
        }
#pragma unroll
        for (int j = 0; j < 16; j++)
            sH1f[e * 132 + og * 16 + j] = silu_f(acc[j]);
    }
    __syncthreads();

    {
        float acc[32];
#pragma unroll
        for (int j = 0; j < 32; j++) acc[j] = b2[og * 32 + j];
        for (int hq = 0; hq < 32; hq++) {
            const float4 v = *(const float4*)&sH1f[e * 132 + hq * 4];
#pragma unroll
            for (int j = 0; j < 32; j++) {
                const float4 w =
                    *(const float4*)&W2[(size_t)(og * 32 + j) * 128 + hq * 4];
                acc[j] = fmaf(v.x, w.x, fmaf(v.y, w.y,
                         fmaf(v.z, w.z, fmaf(v.w, w.w, acc[j]))));
            }
        }
#pragma unroll
        for (int j = 0; j < 32; j++)
            sH2f[e * 260 + og * 32 + j] = silu_f(acc[j]);
    }
    __syncthreads();

    for (int c = 0; c < 3; c++) {
        {
            float acc[16];
#pragma unroll
            for (int j = 0; j < 16; j++) acc[j] = b3[c * 128 + og * 16 + j];
            for (int hq = 0; hq < 64; hq++) {
                const float4 v = *(const float4*)&sH2f[e * 260 + hq * 4];
#pragma unroll
                for (int j = 0; j < 16; j++) {
                    const float4 w = *(const float4*)
                        &W3[(size_t)(c * 128 + og * 16 + j) * 256 + hq * 4];
                    acc[j] = fmaf(v.x, w.x, fmaf(v.y, w.y,
                             fmaf(v.z, w.z, fmaf(v.w, w.w, acc[j]))));
                }
            }
            const float cc = sCc[e];
#pragma unroll
            for (int j = 0; j < 16; j++)
                sXcf[e * 132 + og * 16 + j] = silu_f(acc[j]) * cc;
        }
        __syncthreads();
        {
            const int h  = tid & 127;
            const int eh = tid >> 7;
#pragma unroll 4
            for (int i = 0; i < 16; i++) {
                const int ee = (eh << 4) | i;
                const int s = sS[ee], d = sD[ee];
                const float xv = sXcf[ee * 132 + h];
                const int sb = s * HD + h, db = d * HD + h;
                if (c == 0) {
                    atomicAdd(&MSG[0 * (size_t)NH + sb], xv * Y[0 * (size_t)NH + db]);
                } else if (c == 1) {
#pragma unroll
                    for (int cc2 = 1; cc2 < 4; cc2++)
                        atomicAdd(&MSG[(size_t)cc2 * NH + sb],
                                  xv * Y[(size_t)cc2 * NH + db]);
                } else {
#pragma unroll
                    for (int cc2 = 4; cc2 < 9; cc2++)
                        atomicAdd(&MSG[(size_t)cc2 * NH + sb],
                                  xv * Y[(size_t)cc2 * NH + db]);
                }
            }
        }
        __syncthreads();
    }
}

// ---------------------------------------------------------------------------
// Kernel 2b: node-major gather.  YT = short (bf16 planes) or float.
// ---------------------------------------------------------------------------
__device__ __forceinline__ float ldy(const float* p) { return *p; }
__device__ __forceinline__ float ldy(const short* p) { return b2f(*p); }

template <typename YT>
__global__ __launch_bounds__(256) void k_gather(
    const short* __restrict__ XC, const YT* __restrict__ Y,
    const int* __restrict__ offs, const int* __restrict__ EIDS,
    const int* __restrict__ DSTS, float* __restrict__ MSG)
{
    const int tid = threadIdx.x;
    const int nl  = tid >> 7, h = tid & 127;
    const int n   = blockIdx.x * 2 + nl;
    const int beg = offs[n], end = offs[n + 1];

    float m[9];
#pragma unroll
    for (int c = 0; c < 9; c++) m[c] = 0.f;

    for (int p = beg; p < end; ++p) {
        const int eid = EIDS[p];
        const int dst = DSTS[p];
        const size_t xb = (size_t)eid * 384;
        const float x0 = b2f(XC[xb + h]);
        const float x1 = b2f(XC[xb + 128 + h]);
        const float x2 = b2f(XC[xb + 256 + h]);
        const int yb = dst * HD + h;
        m[0] = fmaf(x0, ldy(Y + 0 * (size_t)NH + yb), m[0]);
        m[1] = fmaf(x1, ldy(Y + 1 * (size_t)NH + yb), m[1]);
        m[2] = fmaf(x1, ldy(Y + 2 * (size_t)NH + yb), m[2]);
        m[3] = fmaf(x1, ldy(Y + 3 * (size_t)NH + yb), m[3]);
        m[4] = fmaf(x2, ldy(Y + 4 * (size_t)NH + yb), m[4]);
        m[5] = fmaf(x2, ldy(Y + 5 * (size_t)NH + yb), m[5]);
        m[6] = fmaf(x2, ldy(Y + 6 * (size_t)NH + yb), m[6]);
        m[7] = fmaf(x2, ldy(Y + 7 * (size_t)NH + yb), m[7]);
        m[8] = fmaf(x2, ldy(Y + 8 * (size_t)NH + yb), m[8]);
    }
    const int base = n * HD + h;
#pragma unroll
    for (int c = 0; c < 9; c++) MSG[(size_t)c * NH + base] = m[c];
}

// ---------------------------------------------------------------------------
static inline size_t align_up(size_t v, size_t a) { return (v + a - 1) & ~(a - 1); }

extern "C" void kernel_launch(void* const* d_in, const int* in_sizes, int n_in,
                              void* d_out, int out_size, void* d_ws, size_t ws_size,
                              hipStream_t stream)
{
    const float* X   = (const float*)d_in[0];
    const float* CH  = (const float*)d_in[1];
    const float* EA  = (const float*)d_in[2];
    const float* EW  = (const float*)d_in[3];
    const float* W1  = (const float*)d_in[4];
    const float* b1  = (const float*)d_in[5];
    const float* W2  = (const float*)d_in[6];
    const float* b2  = (const float*)d_in[7];
    const float* W3  = (const float*)d_in[8];
    const float* b3  = (const float*)d_in[9];
    const float* Wt0 = (const float*)d_in[10];
    const float* Wt1 = (const float*)d_in[11];
    const float* Wt2 = (const float*)d_in[12];
    const float* Wt3 = (const float*)d_in[13];
    const float* Wt4 = (const float*)d_in[14];
    const float* Wt5 = (const float*)d_in[15];
    const int*   EI  = (const int*)d_in[16];
    float* out = (float*)d_out;

    size_t off = 0;
    float* Y    = (float*)((char*)d_ws + off); off = align_up(off + (size_t)9 * NH * 4, 64);
    float* MSG  = (float*)((char*)d_ws + off); off = align_up(off + (size_t)9 * NH * 4, 64);
    int*   cnt  = (int*)((char*)d_ws + off);   off = align_up(off + (size_t)NN * 4, 64);
    int*   cur  = (int*)((char*)d_ws + off);   off = align_up(off + (size_t)NN * 4, 64);
    int*   offs = (int*)((char*)d_ws + off);   off = align_up(off + (size_t)(NN + 1) * 4, 64);
    int*   EIDS = (int*)((char*)d_ws + off);   off = align_up(off + (size_t)EE * 4, 64);
    int*   DSTS = (int*)((char*)d_ws + off);   off = align_up(off + (size_t)EE * 4, 64);
    short* W1b  = (short*)((char*)d_ws + off); off = align_up(off + (size_t)8192 * 2, 64);
    short* W2b  = (short*)((char*)d_ws + off); off = align_up(off + (size_t)32768 * 2, 64);
    short* W3b  = (short*)((char*)d_ws + off); off = align_up(off + (size_t)98304 * 2, 64);
    short* WtPh = (short*)((char*)d_ws + off); off = align_up(off + (size_t)3 * 16384 * 2, 64);
    short* WtPl = (short*)((char*)d_ws + off); off = align_up(off + (size_t)3 * 16384 * 2, 64);
    short* WtFh = (short*)((char*)d_ws + off); off = align_up(off + (size_t)3 * 16384 * 2, 64);
    short* WtFl = (short*)((char*)d_ws + off); off = align_up(off + (size_t)3 * 16384 * 2, 64);
    short* XC   = (short*)((char*)d_ws + off); off = align_up(off + (size_t)EE * 384 * 2, 64);
    const size_t need_plain = off;
    short* Ybf  = (short*)((char*)d_ws + off); off = align_up(off + (size_t)9 * NH * 2, 64);
    const size_t need_ybf = off;

    k_wconv<<<928, 256, 0, stream>>>(W1, W2, W3, Wt0, Wt1, Wt2, Wt3, Wt4, Wt5,
                                     W1b, W2b, W3b, WtPh, WtPl, WtFh, WtFl);

    if (ws_size >= need_plain) {
        const bool use_ybf = (ws_size >= need_ybf);
        if (use_ybf)
            k_mix<false, true><<<NN / 16, 256, 73728, stream>>>(
                X, Y, Y, WtPh, WtPl, Y, Ybf);
        else
            k_mix<false, false><<<NN / 16, 256, 73728, stream>>>(
                X, Y, Y, WtPh, WtPl, Y, nullptr);

        hipMemsetAsync(cnt, 0, (size_t)NN * sizeof(int), stream);
        k_count<<<EE / 256, 256, 0, stream>>>(EI, cnt);
        k_scan<<<1, 256, 0, stream>>>(cnt, offs, cur);
        k_fill<<<EE / 256, 256, 0, stream>>>(EI, cur, EIDS, DSTS);
        k_edge_mfma<<<EE / 64, 256, 0, stream>>>(EA, CH, EW, EI,
                                                 W1b, b1, W2b, b2, W3b, b3, XC);
        if (use_ybf)
            k_gather<short><<<NN / 2, 256, 0, stream>>>(XC, Ybf, offs, EIDS, DSTS, MSG);
        else
            k_gather<float><<<NN / 2, 256, 0, stream>>>(XC, Y, offs, EIDS, DSTS, MSG);
    } else {
        k_mix<false, false><<<NN / 16, 256, 73728, stream>>>(
            X, Y, Y, WtPh, WtPl, Y, nullptr);
        hipMemsetAsync(MSG, 0, (size_t)9 * NH * sizeof(float), stream);
        k_edge_atomic<<<EE / 32, 256, 0, stream>>>(EA, CH, EW, EI,
                                                   W1, b1, W2, b2, W3, b3, Y, MSG);
    }

    k_mix<true, false><<<NN / 16, 256, 73728, stream>>>(X, Y, MSG, WtFh, WtFl, out, nullptr);
}

// Round 8
// 318.765 us; speedup vs baseline: 24.8905x; 1.0939x over previous
//
#include <hip/hip_runtime.h>

#define NN  10000
#define HD  128
#define EE  160000
#define RD  32
#define NH  (NN * HD)

typedef __attribute__((ext_vector_type(8))) short short8_t;
typedef __attribute__((ext_vector_type(4))) float f32x4_t;
typedef __attribute__((ext_vector_type(4))) int   int4_t;

// fast silu: v_rcp_f32 (~1ulp) instead of exact-div sequence
__device__ __forceinline__ float silu_f(float z) {
    return z * __builtin_amdgcn_rcpf(1.0f + __expf(-z));
}
__device__ __forceinline__ short f2b(float v) {   // RNE fp32->bf16
    unsigned u = __float_as_uint(v);
    unsigned r = (u + 0x7FFFu + ((u >> 16) & 1u)) >> 16;
    return (short)r;
}
__device__ __forceinline__ float b2f(short s) {
    return __uint_as_float(((unsigned)(unsigned short)s) << 16);
}
// HW packed convert: bits[15:0]=bf16(a), bits[31:16]=bf16(b), RNE.
__device__ __forceinline__ unsigned cvt_pk(float a, float b) {
    unsigned r;
    asm("v_cvt_pk_bf16_f32 %0, %1, %2" : "=v"(r) : "v"(a), "v"(b));
    return r;
}

// ---------------------------------------------------------------------------
// Weight conversion (unchanged).
// ---------------------------------------------------------------------------
__global__ __launch_bounds__(256) void k_wconv(
    const float* __restrict__ W1, const float* __restrict__ W2,
    const float* __restrict__ W3,
    const float* __restrict__ Wt0, const float* __restrict__ Wt1,
    const float* __restrict__ Wt2, const float* __restrict__ Wt3,
    const float* __restrict__ Wt4, const float* __restrict__ Wt5,
    short* __restrict__ W1b, short* __restrict__ W2b, short* __restrict__ W3b,
    short* __restrict__ WtPh, short* __restrict__ WtPl,
    short* __restrict__ WtFh, short* __restrict__ WtFl)
{
    const int i = blockIdx.x * 256 + threadIdx.x;
    if (i < 8192) {                       // layer1: ct<8, kb<2, K_in=34
        const int j = i & 7, lane = (i >> 3) & 63;
        const int kb = (i >> 9) & 1, ct = i >> 10;
        const int n = ct * 16 + (lane & 15);
        const int k = kb * 32 + (lane >> 4) * 8 + j;
        W1b[i] = (k < 34) ? f2b(W1[n * 34 + k]) : (short)0;
        return;
    }
    int j2 = i - 8192;
    if (j2 < 32768) {                     // layer2: ct<16, kb<4, K_in=128
        const int j = j2 & 7, lane = (j2 >> 3) & 63;
        const int kb = (j2 >> 9) & 3, ct = j2 >> 11;
        const int n = ct * 16 + (lane & 15);
        const int k = kb * 32 + (lane >> 4) * 8 + j;
        W2b[j2] = f2b(W2[n * 128 + k]);
        return;
    }
    j2 -= 32768;
    if (j2 < 98304) {                     // layer3: ct<24, kb<8, K_in=256
        const int j = j2 & 7, lane = (j2 >> 3) & 63;
        const int kb = (j2 >> 9) & 7, ct = j2 >> 12;
        const int n = ct * 16 + (lane & 15);
        const int k = kb * 32 + (lane >> 4) * 8 + j;
        W3b[j2] = f2b(W3[n * 256 + k]);
        return;
    }
    j2 -= 98304;
    if (j2 < 6 * 16384) {
        const int m = j2 >> 14, idx = j2 & 16383;
        const float* src = (m == 0) ? Wt0 : (m == 1) ? Wt1 : (m == 2) ? Wt2
                         : (m == 3) ? Wt3 : (m == 4) ? Wt4 : Wt5;
        const float w = src[idx];
        const short hi = f2b(w);
        const short lo = f2b(w - b2f(hi));
        if (m < 3) { WtPh[m * 16384 + idx] = hi; WtPl[m * 16384 + idx] = lo; }
        else       { WtFh[(m - 3) * 16384 + idx] = hi; WtFl[(m - 3) * 16384 + idx] = lo; }
    }
}

// ---------------------------------------------------------------------------
// k_mix<FIN, WB>: channel-mix as MFMA GEMM with bf16 hi/lo 3-term split.
// ---------------------------------------------------------------------------
template <bool FIN, bool WB>
__global__ __launch_bounds__(256) void k_mix(
    const float* __restrict__ X,
    const float* __restrict__ Yin, const float* __restrict__ MSGin,
    const short* __restrict__ Wh,  const short* __restrict__ Wl,
    float* __restrict__ outp, short* __restrict__ ybf)
{
    extern __shared__ __align__(16) char smem[];   // 73728 B
    short* sBh = (short*)smem;                     // [144][128] bf16 hi
    short* sBl = sBh + 144 * 128;                  // [144][128] bf16 lo
    float* sC  = (float*)smem;                     // [144][128] f32 (after GEMM)

    const int tid = threadIdx.x;
    const int n0  = blockIdx.x * 16;

#pragma unroll 2
    for (int i = 0; i < 8; i++) {
        const int p  = i * 256 + tid;
        const int nl = p >> 7, h = p & 127;
        float dec[9];
        if constexpr (!FIN) {
            const float* t = X + ((size_t)((n0 + nl) * HD + h)) * 9;
            float T[9];
#pragma unroll
            for (int q = 0; q < 9; q++) T[q] = t[q];
            float nrm = 0.f;
#pragma unroll
            for (int q = 0; q < 9; q++) nrm = fmaf(T[q], T[q], nrm);
            const float inv = 1.0f / (nrm + 1.0f);
#pragma unroll
            for (int q = 0; q < 9; q++) T[q] *= inv;
            const float I = (T[0] + T[4] + T[8]) * (1.0f / 3.0f);
            dec[0] = I;
            dec[1] = 0.5f * (T[7] - T[5]);
            dec[2] = 0.5f * (T[2] - T[6]);
            dec[3] = 0.5f * (T[3] - T[1]);
            dec[4] = T[0] - I;
            dec[5] = 0.5f * (T[1] + T[3]);
            dec[6] = 0.5f * (T[2] + T[6]);
            dec[7] = T[4] - I;
            dec[8] = 0.5f * (T[5] + T[7]);
        } else {
            const int basep = (n0 + nl) * HD + h;
            float yv[9], mv[9];
#pragma unroll
            for (int c = 0; c < 9; c++) {
                yv[c] = Yin[(size_t)c * NH + basep];
                mv[c] = MSGin[(size_t)c * NH + basep];
            }
            float Yt[9], G[9];
            {
                const float I = yv[0], a0 = yv[1], a1 = yv[2], a2 = yv[3];
                const float s00 = yv[4], s01 = yv[5], s02 = yv[6], s11 = yv[7], s12 = yv[8];
                const float s22 = -s00 - s11;
                Yt[0] = I + s00; Yt[1] = s01 - a2; Yt[2] = s02 + a1;
                Yt[3] = s01 + a2; Yt[4] = I + s11; Yt[5] = s12 - a0;
                Yt[6] = s02 - a1; Yt[7] = s12 + a0; Yt[8] = I + s22;
            }
            {
                const float I = mv[0], a0 = mv[1], a1 = mv[2], a2 = mv[3];
                const float s00 = mv[4], s01 = mv[5], s02 = mv[6], s11 = mv[7], s12 = mv[8];
                const float s22 = -s00 - s11;
                G[0] = I + s00; G[1] = s01 - a2; G[2] = s02 + a1;
                G[3] = s01 + a2; G[4] = I + s11; G[5] = s12 - a0;
                G[6] = s02 - a1; G[7] = s12 + a0; G[8] = I + s22;
            }
            float M[9];
#pragma unroll
            for (int r = 0; r < 3; r++)
#pragma unroll
                for (int cc = 0; cc < 3; cc++) {
                    float a = 0.f;
#pragma unroll
                    for (int k = 0; k < 3; k++)
                        a += G[r * 3 + k] * Yt[k * 3 + cc]
                           + Yt[r * 3 + k] * G[k * 3 + cc];
                    M[r * 3 + cc] = a;
                }
            const float I2 = (M[0] + M[4] + M[8]) * (1.0f / 3.0f);
            const float a0 = 0.5f * (M[7] - M[5]);
            const float a1 = 0.5f * (M[2] - M[6]);
            const float a2 = 0.5f * (M[3] - M[1]);
            const float s00 = M[0] - I2, s11 = M[4] - I2;
            const float s01 = 0.5f * (M[1] + M[3]);
            const float s02 = 0.5f * (M[2] + M[6]);
            const float s12 = 0.5f * (M[5] + M[7]);
            const float s22 = -s00 - s11;
            const float nrm = 2.f * (a0 * a0 + a1 * a1 + a2 * a2)
                            + (s00 * s00 + s11 * s11 + s22 * s22)
                            + 2.f * (s01 * s01 + s02 * s02 + s12 * s12)
                            + 3.f * I2 * I2;
            const float inv = 1.0f / (nrm + 1.0f);
            dec[0] = I2 * inv;  dec[1] = a0 * inv;  dec[2] = a1 * inv;
            dec[3] = a2 * inv;  dec[4] = s00 * inv; dec[5] = s01 * inv;
            dec[6] = s02 * inv; dec[7] = s11 * inv; dec[8] = s12 * inv;
        }
        const int sw = (nl & 7) << 3;
        const int hx = h ^ sw;
#pragma unroll
        for (int c = 0; c < 9; c++) {
            const float v  = dec[c];
            const short hi = f2b(v);
            const short lo = f2b(v - b2f(hi));
            const int idx = (c * 16 + nl) * 128 + hx;
            sBh[idx] = hi;
            sBl[idx] = lo;
        }
    }
    __syncthreads();

    const int lane = tid & 63, wid = tid >> 6;
    const int l15 = lane & 15, g = lane >> 4;
    f32x4_t acc[2][9];
#pragma unroll
    for (int t = 0; t < 2; t++)
#pragma unroll
        for (int c = 0; c < 9; c++) acc[t][c] = {0.f, 0.f, 0.f, 0.f};

    const int bsw = (l15 & 7) << 3;
#pragma unroll
    for (int k = 0; k < 4; k++) {
        const int k0  = k * 32 + g * 8;
        const int ksw = k0 ^ bsw;
#pragma unroll
        for (int w = 0; w < 3; w++) {
            short8_t Ah[2], Al[2];
#pragma unroll
            for (int t = 0; t < 2; t++) {
                const int o = (wid * 2 + t) * 16 + l15;
                const size_t aoff = (size_t)w * 16384 + (size_t)o * 128 + k0;
                Ah[t] = *(const short8_t*)(Wh + aoff);
                Al[t] = *(const short8_t*)(Wl + aoff);
            }
            const int ct0 = (w == 0) ? 0 : (w == 1 ? 1 : 4);
            const int ctn = (w == 0) ? 1 : (w == 1 ? 3 : 5);
            for (int cc = 0; cc < ctn; cc++) {
                const int ct = ct0 + cc;
                const int boff = (ct * 16 + l15) * 128 + ksw;
                const short8_t Bh = *(const short8_t*)&sBh[boff];
                const short8_t Bl = *(const short8_t*)&sBl[boff];
#pragma unroll
                for (int t = 0; t < 2; t++) {
                    acc[t][ct] = __builtin_amdgcn_mfma_f32_16x16x32_bf16(Al[t], Bh, acc[t][ct], 0, 0, 0);
                    acc[t][ct] = __builtin_amdgcn_mfma_f32_16x16x32_bf16(Ah[t], Bl, acc[t][ct], 0, 0, 0);
                    acc[t][ct] = __builtin_amdgcn_mfma_f32_16x16x32_bf16(Ah[t], Bh, acc[t][ct], 0, 0, 0);
                }
            }
        }
    }
    __syncthreads();

    const int csw = (l15 & 7) << 2;
#pragma unroll
    for (int t = 0; t < 2; t++) {
        const int o0 = (wid * 2 + t) * 16 + g * 4;
#pragma unroll
        for (int ct = 0; ct < 9; ct++)
            *(f32x4_t*)&sC[(ct * 16 + l15) * 128 + (o0 ^ csw)] = acc[t][ct];
    }
    __syncthreads();

    if constexpr (!FIN) {
        for (int i = tid; i < 144 * 32; i += 256) {
            const int row = i >> 5, q = i & 31;
            const int c = row >> 4, nl = row & 15;
            const int sw = (nl & 7) << 2;
            const f32x4_t v = *(const f32x4_t*)&sC[row * 128 + ((q * 4) ^ sw)];
            const size_t o = (size_t)c * NH + (size_t)(n0 + nl) * HD + q * 4;
            *(f32x4_t*)&outp[o] = v;
            if constexpr (WB) {
                uint2 u;
                u.x = cvt_pk(v[0], v[1]);
                u.y = cvt_pk(v[2], v[3]);
                *(uint2*)&ybf[o] = u;
            }
        }
    } else {
#pragma unroll 2
        for (int i = 0; i < 8; i++) {
            const int p  = i * 256 + tid;
            const int nl = p >> 7, o = p & 127;
            const int sw = (nl & 7) << 2;
            const int ox = o ^ sw;
            float a9[9];
#pragma unroll
            for (int c = 0; c < 9; c++) a9[c] = sC[(c * 16 + nl) * 128 + ox];
            float D[9];
            {
                const float I = a9[0], a0 = a9[1], a1 = a9[2], a2 = a9[3];
                const float s00 = a9[4], s01 = a9[5], s02 = a9[6];
                const float s11 = a9[7], s12 = a9[8];
                const float s22 = -s00 - s11;
                D[0] = I + s00; D[1] = s01 - a2; D[2] = s02 + a1;
                D[3] = s01 + a2; D[4] = I + s11; D[5] = s12 - a0;
                D[6] = s02 - a1; D[7] = s12 + a0; D[8] = I + s22;
            }
            const size_t xbase = ((size_t)((n0 + nl) * HD + o)) * 9;
            float T[9];
#pragma unroll
            for (int q = 0; q < 9; q++) T[q] = X[xbase + q];
            float nrm = 0.f;
#pragma unroll
            for (int q = 0; q < 9; q++) nrm = fmaf(T[q], T[q], nrm);
            const float inv = 1.0f / (nrm + 1.0f);
            float* op = outp + xbase;
#pragma unroll
            for (int r = 0; r < 3; r++)
#pragma unroll
                for (int cc = 0; cc < 3; cc++) {
                    float dd2 = 0.f;
#pragma unroll
                    for (int k = 0; k < 3; k++)
                        dd2 = fmaf(D[r * 3 + k], D[k * 3 + cc], dd2);
                    op[r * 3 + cc] = T[r * 3 + cc] * inv + D[r * 3 + cc] + dd2;
                }
        }
    }
}

// ---------------------------------------------------------------------------
// CSR build.
// ---------------------------------------------------------------------------
__global__ __launch_bounds__(256) void k_count(const int* __restrict__ EI,
                                               int* __restrict__ cnt)
{
    const int e = blockIdx.x * 256 + threadIdx.x;
    atomicAdd(&cnt[EI[e]], 1);
}

__global__ __launch_bounds__(256) void k_scan(const int* __restrict__ cnt,
                                              int* __restrict__ offs,
                                              int* __restrict__ cur)
{
    __shared__ int part[256];
    const int tid = threadIdx.x;
    const int per = (NN + 255) / 256;
    int s = 0;
    for (int i = 0; i < per; i++) {
        const int idx = tid * per + i;
        if (idx < NN) s += cnt[idx];
    }
    part[tid] = s;
    __syncthreads();
    if (tid == 0) {
        int r = 0;
        for (int i = 0; i < 256; i++) { const int t = part[i]; part[i] = r; r += t; }
        offs[NN] = r;
    }
    __syncthreads();
    int run = part[tid];
    for (int i = 0; i < per; i++) {
        const int idx = tid * per + i;
        if (idx < NN) {
            offs[idx] = run;
            cur[idx]  = run;
            run += cnt[idx];
        }
    }
}

__global__ __launch_bounds__(256) void k_fill(const int* __restrict__ EI,
                                              int* __restrict__ cur,
                                              int* __restrict__ EIDS,
                                              int* __restrict__ DSTS)
{
    const int e = blockIdx.x * 256 + threadIdx.x;
    const int s = EI[e];
    const int pos = atomicAdd(&cur[s], 1);
    EIDS[pos] = e;
    DSTS[pos] = EI[EE + e];
}

// ---------------------------------------------------------------------------
// Kernel 2: MFMA edge MLP, ct-parallel waves, SWAPPED operands:
// mfma(W_frag, X_frag) -> C tile transposed: lane holds 4 consecutive
// FEATURES (n = ct*16 + g*4 + r) for one edge (= at*16 + l15).  Epilogue is
// 2 cvt_pk + one 8-byte vector store per (at,ct).  Fragment reads unchanged.
// ---------------------------------------------------------------------------
__global__ __launch_bounds__(256, 2) void k_edge_mfma(
    const float* __restrict__ EA, const float* __restrict__ CH,
    const float* __restrict__ EW, const int*   __restrict__ EI,
    const short* __restrict__ W1b, const float* __restrict__ b1,
    const short* __restrict__ W2b, const float* __restrict__ b2,
    const short* __restrict__ W3b, const float* __restrict__ b3,
    short* __restrict__ XC)
{
    __shared__ __align__(16) short sH2[64 * 256];   // 32 KB; first 8 KB = sIn
    __shared__ __align__(16) short sH1[64 * 128];   // 16 KB
    __shared__ float sCut[64];

    short* sIn = sH2;                               // [64][64] alias
    const int tid = threadIdx.x;
    const int e0  = blockIdx.x * 64;

    {   // zero-fill sIn (pad cols 34..63)
        int4_t z = {0, 0, 0, 0};
        ((int4_t*)sIn)[tid]       = z;
        ((int4_t*)sIn)[tid + 256] = z;
    }
    __syncthreads();
    {   // stage edge_attr + charges (bf16, (e&7)<<3 swizzle) + cutoff
        for (int i = tid; i < 512; i += 256) {
            const float4 v = ((const float4*)(EA + (size_t)e0 * RD))[i];
            const int e = i >> 3;
            const int k = (i & 7) * 4;
            short4 sv;
            sv.x = f2b(v.x); sv.y = f2b(v.y); sv.z = f2b(v.z); sv.w = f2b(v.w);
            *(short4*)&sIn[e * 64 + (k ^ ((e & 7) << 3))] = sv;
        }
        if (tid < 64) {
            const int e = tid;
            const int s = EI[e0 + e];
            const int d = EI[EE + e0 + e];
            const int sw = (e & 7) << 3;
            sIn[e * 64 + (32 ^ sw)] = f2b(CH[s]);
            sIn[e * 64 + (33 ^ sw)] = f2b(CH[d]);
            const float w = EW[e0 + e];
            sCut[e] = (w < 5.0f)
                    ? 0.5f * (__cosf(0.62831853071795864769f * w) + 1.0f) : 0.0f;
        }
    }
    __syncthreads();

    const int lane = tid & 63;
    const int wid  = tid >> 6;
    const int l15  = lane & 15;
    const int g    = lane >> 4;
    const int fsw  = (l15 & 15) << 3;   // feature-XOR for stores (edge = ..+l15)

    // ---- layer 1: 64 edges @ W1 (64->128); wave does cts {wid, wid+4} ----
    {
        short8_t E1[4][2];
#pragma unroll
        for (int at = 0; at < 4; at++) {
            const int row = at * 16 + l15;
            const int x = (row & 7) << 3;
            E1[at][0] = *(const short8_t*)&sIn[row * 64 + ((g * 8) ^ x)];
            E1[at][1] = *(const short8_t*)&sIn[row * 64 + ((32 + g * 8) ^ x)];
        }
#pragma unroll
        for (int c = 0; c < 2; c++) {
            const int ct = c * 4 + wid;
            const float4 b4 = *(const float4*)&b1[ct * 16 + g * 4];
            const short8_t av0 = *(const short8_t*)(W1b + (size_t)((ct * 2 + 0) * 64 + lane) * 8);
            const short8_t av1 = *(const short8_t*)(W1b + (size_t)((ct * 2 + 1) * 64 + lane) * 8);
            const int fcol = ct * 16 + g * 4;
#pragma unroll
            for (int at = 0; at < 4; at++) {
                f32x4_t acc = {b4.x, b4.y, b4.z, b4.w};
                acc = __builtin_amdgcn_mfma_f32_16x16x32_bf16(av0, E1[at][0], acc, 0, 0, 0);
                acc = __builtin_amdgcn_mfma_f32_16x16x32_bf16(av1, E1[at][1], acc, 0, 0, 0);
                const int edge = at * 16 + l15;
                uint2 u;
                u.x = cvt_pk(silu_f(acc[0]), silu_f(acc[1]));
                u.y = cvt_pk(silu_f(acc[2]), silu_f(acc[3]));
                *(uint2*)&sH1[edge * 128 + (fcol ^ fsw)] = u;
            }
        }
    }
    __syncthreads();

    // ---- layer 2: @ W2 (128->256); wave does 4 cts ----
    {
        short8_t E2[4][4];
#pragma unroll
        for (int at = 0; at < 4; at++) {
            const int row = at * 16 + l15;
            const int x = (row & 15) << 3;
#pragma unroll
            for (int kb = 0; kb < 4; kb++)
                E2[at][kb] = *(const short8_t*)&sH1[row * 128 + ((kb * 32 + g * 8) ^ x)];
        }
#pragma unroll
        for (int c = 0; c < 4; c++) {
            const int ct = c * 4 + wid;
            const float4 b4 = *(const float4*)&b2[ct * 16 + g * 4];
            const int fcol = ct * 16 + g * 4;
            f32x4_t acc[4];
#pragma unroll
            for (int at = 0; at < 4; at++) acc[at] = {b4.x, b4.y, b4.z, b4.w};
#pragma unroll
            for (int kb = 0; kb < 4; kb++) {
                const short8_t av = *(const short8_t*)(W2b + (size_t)((ct * 4 + kb) * 64 + lane) * 8);
#pragma unroll
                for (int at = 0; at < 4; at++)
                    acc[at] = __builtin_amdgcn_mfma_f32_16x16x32_bf16(av, E2[at][kb], acc[at], 0, 0, 0);
            }
#pragma unroll
            for (int at = 0; at < 4; at++) {
                const int edge = at * 16 + l15;
                uint2 u;
                u.x = cvt_pk(silu_f(acc[at][0]), silu_f(acc[at][1]));
                u.y = cvt_pk(silu_f(acc[at][2]), silu_f(acc[at][3]));
                *(uint2*)&sH2[edge * 256 + (fcol ^ fsw)] = u;
            }
        }
    }
    __syncthreads();

    // ---- layer 3: @ W3 (256->384); wave does 6 cts; silu*cutoff -> XC ----
    {
        short8_t E3[4][8];
#pragma unroll
        for (int at = 0; at < 4; at++) {
            const int row = at * 16 + l15;
            const int x = (row & 15) << 3;
#pragma unroll
            for (int kb = 0; kb < 8; kb++)
                E3[at][kb] = *(const short8_t*)&sH2[row * 256 + ((kb * 32 + g * 8) ^ x)];
        }
        float cut[4];
#pragma unroll
        for (int at = 0; at < 4; at++) cut[at] = sCut[at * 16 + l15];
        for (int c = 0; c < 6; c++) {
            const int ct = c * 4 + wid;
            const float4 b4 = *(const float4*)&b3[ct * 16 + g * 4];
            const int fcol = ct * 16 + g * 4;
            f32x4_t acc[4];
#pragma unroll
            for (int at = 0; at < 4; at++) acc[at] = {b4.x, b4.y, b4.z, b4.w};
#pragma unroll
            for (int kb = 0; kb < 8; kb++) {
                const short8_t av = *(const short8_t*)(W3b + (size_t)((ct * 8 + kb) * 64 + lane) * 8);
#pragma unroll
                for (int at = 0; at < 4; at++)
                    acc[at] = __builtin_amdgcn_mfma_f32_16x16x32_bf16(av, E3[at][kb], acc[at], 0, 0, 0);
            }
#pragma unroll
            for (int at = 0; at < 4; at++) {
                const int edge = at * 16 + l15;
                const float cv = cut[at];
                uint2 u;
                u.x = cvt_pk(silu_f(acc[at][0]) * cv, silu_f(acc[at][1]) * cv);
                u.y = cvt_pk(silu_f(acc[at][2]) * cv, silu_f(acc[at][3]) * cv);
                *(uint2*)&XC[(size_t)(e0 + edge) * 384 + fcol] = u;
            }
        }
    }
}

// ---------------------------------------------------------------------------
// Fallback (small ws): fused VALU edge MLP + atomic scatter.
// ---------------------------------------------------------------------------
__global__ __launch_bounds__(256) void k_edge_atomic(
    const float* __restrict__ EA, const float* __restrict__ CH,
    const float* __restrict__ EW, const int*   __restrict__ EI,
    const float* __restrict__ W1, const float* __restrict__ b1,
    const float* __restrict__ W2, const float* __restrict__ b2,
    const float* __restrict__ W3, const float* __restrict__ b3,
    const float* __restrict__ Y,  float* __restrict__ MSG)
{
    __shared__ __align__(16) float sInf[32 * 35];
    __shared__ __align__(16) float sH1f[32 * 132];
    __shared__ __align__(16) float sH2f[32 * 260];
    __shared__ __align__(16) float sXcf[32 * 132];
    __shared__ float sCc[32];
    __shared__ int   sS[32], sD[32];

    const int e0  = blockIdx.x * 32;
    const int tid = threadIdx.x;

    {
        const float4 v = ((const float4*)(EA + (size_t)e0 * RD))[tid];
        const int e = tid >> 3;
        const int k = (tid & 7) * 4;
        float* p = sInf + e * 35 + k;
        p[0] = v.x; p[1] = v.y; p[2] = v.z; p[3] = v.w;
    }
    if (tid < 32) {
        const int e = tid;
        const int s = EI[e0 + e];
        const int d = EI[EE + e0 + e];
        sS[e] = s; sD[e] = d;
        sInf[e * 35 + 32] = CH[s];
        sInf[e * 35 + 33] = CH[d];
        const float w = EW[e0 + e];
        sCc[e] = (w < 5.0f) ? 0.5f * (__cosf(0.62831853071795864769f * w) + 1.0f)
                            : 0.0f;
    }
    __syncthreads();

    const int e  = tid & 31;
    const int og = tid >> 5;

    {
        float acc[16];
#pragma unroll
        for (int j = 0; j < 16; j++) acc[j] = b1[og * 16 + j];
        for (int k = 0; k < 34; k++) {
            const float v = sInf[e * 35 + k];
#pragma unroll
            for (int j = 0; j < 16; j++)
                acc[j] = fmaf(v, W1[(og * 16 + j) * 34 + k], acc[j]);
        }
#pragma unroll
        for (int j = 0; j < 16; j++)
            sH1f[e * 132 + og * 16 + j] = silu_f(acc[j]);
    }
    __syncthreads();

    {
        float acc[32];
#pragma unroll
        for (int j = 0; j < 32; j++) acc[j] = b2[og * 32 + j];
        for (int hq = 0; hq < 32; hq++) {
            const float4 v = *(const float4*)&sH1f[e * 132 + hq * 4];
#pragma unroll
            for (int j = 0; j < 32; j++) {
                const float4 w =
                    *(const float4*)&W2[(size_t)(og * 32 + j) * 128 + hq * 4];
                acc[j] = fmaf(v.x, w.x, fmaf(v.y, w.y,
                         fmaf(v.z, w.z, fmaf(v.w, w.w, acc[j]))));
            }
        }
#pragma unroll
        for (int j = 0; j < 32; j++)
            sH2f[e * 260 + og * 32 + j] = silu_f(acc[j]);
    }
    __syncthreads();

    for (int c = 0; c < 3; c++) {
        {
            float acc[16];
#pragma unroll
            for (int j = 0; j < 16; j++) acc[j] = b3[c * 128 + og * 16 + j];
            for (int hq = 0; hq < 64; hq++) {
                const float4 v = *(const float4*)&sH2f[e * 260 + hq * 4];
#pragma unroll
                for (int j = 0; j < 16; j++) {
                    const float4 w = *(const float4*)
                        &W3[(size_t)(c * 128 + og * 16 + j) * 256 + hq * 4];
                    acc[j] = fmaf(v.x, w.x, fmaf(v.y, w.y,
                             fmaf(v.z, w.z, fmaf(v.w, w.w, acc[j]))));
                }
            }
            const float cc = sCc[e];
#pragma unroll
            for (int j = 0; j < 16; j++)
                sXcf[e * 132 + og * 16 + j] = silu_f(acc[j]) * cc;
        }
        __syncthreads();
        {
            const int h  = tid & 127;
            const int eh = tid >> 7;
#pragma unroll 4
            for (int i = 0; i < 16; i++) {
                const int ee = (eh << 4) | i;
                const int s = sS[ee], d = sD[ee];
                const float xv = sXcf[ee * 132 + h];
                const int sb = s * HD + h, db = d * HD + h;
                if (c == 0) {
                    atomicAdd(&MSG[0 * (size_t)NH + sb], xv * Y[0 * (size_t)NH + db]);
                } else if (c == 1) {
#pragma unroll
                    for (int cc2 = 1; cc2 < 4; cc2++)
                        atomicAdd(&MSG[(size_t)cc2 * NH + sb],
                                  xv * Y[(size_t)cc2 * NH + db]);
                } else {
#pragma unroll
                    for (int cc2 = 4; cc2 < 9; cc2++)
                        atomicAdd(&MSG[(size_t)cc2 * NH + sb],
                                  xv * Y[(size_t)cc2 * NH + db]);
                }
            }
        }
        __syncthreads();
    }
}

// ---------------------------------------------------------------------------
// Kernel 2b: node-major gather.  YT = short (bf16 planes) or float.
// ---------------------------------------------------------------------------
__device__ __forceinline__ float ldy(const float* p) { return *p; }
__device__ __forceinline__ float ldy(const short* p) { return b2f(*p); }

template <typename YT>
__global__ __launch_bounds__(256) void k_gather(
    const short* __restrict__ XC, const YT* __restrict__ Y,
    const int* __restrict__ offs, const int* __restrict__ EIDS,
    const int* __restrict__ DSTS, float* __restrict__ MSG)
{
    const int tid = threadIdx.x;
    const int nl  = tid >> 7, h = tid & 127;
    const int n   = blockIdx.x * 2 + nl;
    const int beg = offs[n], end = offs[n + 1];

    float m[9];
#pragma unroll
    for (int c = 0; c < 9; c++) m[c] = 0.f;

    for (int p = beg; p < end; ++p) {
        const int eid = EIDS[p];
        const int dst = DSTS[p];
        const size_t xb = (size_t)eid * 384;
        const float x0 = b2f(XC[xb + h]);
        const float x1 = b2f(XC[xb + 128 + h]);
        const float x2 = b2f(XC[xb + 256 + h]);
        const int yb = dst * HD + h;
        m[0] = fmaf(x0, ldy(Y + 0 * (size_t)NH + yb), m[0]);
        m[1] = fmaf(x1, ldy(Y + 1 * (size_t)NH + yb), m[1]);
        m[2] = fmaf(x1, ldy(Y + 2 * (size_t)NH + yb), m[2]);
        m[3] = fmaf(x1, ldy(Y + 3 * (size_t)NH + yb), m[3]);
        m[4] = fmaf(x2, ldy(Y + 4 * (size_t)NH + yb), m[4]);
        m[5] = fmaf(x2, ldy(Y + 5 * (size_t)NH + yb), m[5]);
        m[6] = fmaf(x2, ldy(Y + 6 * (size_t)NH + yb), m[6]);
        m[7] = fmaf(x2, ldy(Y + 7 * (size_t)NH + yb), m[7]);
        m[8] = fmaf(x2, ldy(Y + 8 * (size_t)NH + yb), m[8]);
    }
    const int base = n * HD + h;
#pragma unroll
    for (int c = 0; c < 9; c++) MSG[(size_t)c * NH + base] = m[c];
}

// ---------------------------------------------------------------------------
static inline size_t align_up(size_t v, size_t a) { return (v + a - 1) & ~(a - 1); }

extern "C" void kernel_launch(void* const* d_in, const int* in_sizes, int n_in,
                              void* d_out, int out_size, void* d_ws, size_t ws_size,
                              hipStream_t stream)
{
    const float* X   = (const float*)d_in[0];
    const float* CH  = (const float*)d_in[1];
    const float* EA  = (const float*)d_in[2];
    const float* EW  = (const float*)d_in[3];
    const float* W1  = (const float*)d_in[4];
    const float* b1  = (const float*)d_in[5];
    const float* W2  = (const float*)d_in[6];
    const float* b2  = (const float*)d_in[7];
    const float* W3  = (const float*)d_in[8];
    const float* b3  = (const float*)d_in[9];
    const float* Wt0 = (const float*)d_in[10];
    const float* Wt1 = (const float*)d_in[11];
    const float* Wt2 = (const float*)d_in[12];
    const float* Wt3 = (const float*)d_in[13];
    const float* Wt4 = (const float*)d_in[14];
    const float* Wt5 = (const float*)d_in[15];
    const int*   EI  = (const int*)d_in[16];
    float* out = (float*)d_out;

    size_t off = 0;
    float* Y    = (float*)((char*)d_ws + off); off = align_up(off + (size_t)9 * NH * 4, 64);
    float* MSG  = (float*)((char*)d_ws + off); off = align_up(off + (size_t)9 * NH * 4, 64);
    int*   cnt  = (int*)((char*)d_ws + off);   off = align_up(off + (size_t)NN * 4, 64);
    int*   cur  = (int*)((char*)d_ws + off);   off = align_up(off + (size_t)NN * 4, 64);
    int*   offs = (int*)((char*)d_ws + off);   off = align_up(off + (size_t)(NN + 1) * 4, 64);
    int*   EIDS = (int*)((char*)d_ws + off);   off = align_up(off + (size_t)EE * 4, 64);
    int*   DSTS = (int*)((char*)d_ws + off);   off = align_up(off + (size_t)EE * 4, 64);
    short* W1b  = (short*)((char*)d_ws + off); off = align_up(off + (size_t)8192 * 2, 64);
    short* W2b  = (short*)((char*)d_ws + off); off = align_up(off + (size_t)32768 * 2, 64);
    short* W3b  = (short*)((char*)d_ws + off); off = align_up(off + (size_t)98304 * 2, 64);
    short* WtPh = (short*)((char*)d_ws + off); off = align_up(off + (size_t)3 * 16384 * 2, 64);
    short* WtPl = (short*)((char*)d_ws + off); off = align_up(off + (size_t)3 * 16384 * 2, 64);
    short* WtFh = (short*)((char*)d_ws + off); off = align_up(off + (size_t)3 * 16384 * 2, 64);
    short* WtFl = (short*)((char*)d_ws + off); off = align_up(off + (size_t)3 * 16384 * 2, 64);
    short* XC   = (short*)((char*)d_ws + off); off = align_up(off + (size_t)EE * 384 * 2, 64);
    const size_t need_plain = off;
    short* Ybf  = (short*)((char*)d_ws + off); off = align_up(off + (size_t)9 * NH * 2, 64);
    const size_t need_ybf = off;

    k_wconv<<<928, 256, 0, stream>>>(W1, W2, W3, Wt0, Wt1, Wt2, Wt3, Wt4, Wt5,
                                     W1b, W2b, W3b, WtPh, WtPl, WtFh, WtFl);

    if (ws_size >= need_plain) {
        const bool use_ybf = (ws_size >= need_ybf);
        if (use_ybf)
            k_mix<false, true><<<NN / 16, 256, 73728, stream>>>(
                X, Y, Y, WtPh, WtPl, Y, Ybf);
        else
            k_mix<false, false><<<NN / 16, 256, 73728, stream>>>(
                X, Y, Y, WtPh, WtPl, Y, nullptr);

        hipMemsetAsync(cnt, 0, (size_t)NN * sizeof(int), stream);
        k_count<<<EE / 256, 256, 0, stream>>>(EI, cnt);
        k_scan<<<1, 256, 0, stream>>>(cnt, offs, cur);
        k_fill<<<EE / 256, 256, 0, stream>>>(EI, cur, EIDS, DSTS);
        k_edge_mfma<<<EE / 64, 256, 0, stream>>>(EA, CH, EW, EI,
                                                 W1b, b1, W2b, b2, W3b, b3, XC);
        if (use_ybf)
            k_gather<short><<<NN / 2, 256, 0, stream>>>(XC, Ybf, offs, EIDS, DSTS, MSG);
        else
            k_gather<float><<<NN / 2, 256, 0, stream>>>(XC, Y, offs, EIDS, DSTS, MSG);
    } else {
        k_mix<false, false><<<NN / 16, 256, 73728, stream>>>(
            X, Y, Y, WtPh, WtPl, Y, nullptr);
        hipMemsetAsync(MSG, 0, (size_t)9 * NH * sizeof(float), stream);
        k_edge_atomic<<<EE / 32, 256, 0, stream>>>(EA, CH, EW, EI,
                                                   W1, b1, W2, b2, W3, b3, Y, MSG);
    }

    k_mix<true, false><<<NN / 16, 256, 73728, stream>>>(X, Y, MSG, WtFh, WtFl, out, nullptr);
}

// Round 9
// 306.322 us; speedup vs baseline: 25.9016x; 1.0406x over previous
//
#include <hip/hip_runtime.h>

#define NN  10000
#define HD  128
#define EE  160000
#define RD  32
#define NH  (NN * HD)

typedef __attribute__((ext_vector_type(8))) short short8_t;
typedef __attribute__((ext_vector_type(4))) float f32x4_t;
typedef __attribute__((ext_vector_type(4))) int   int4_t;

// fast silu: v_rcp_f32 (~1ulp) instead of exact-div sequence
__device__ __forceinline__ float silu_f(float z) {
    return z * __builtin_amdgcn_rcpf(1.0f + __expf(-z));
}
__device__ __forceinline__ short f2b(float v) {   // RNE fp32->bf16
    unsigned u = __float_as_uint(v);
    unsigned r = (u + 0x7FFFu + ((u >> 16) & 1u)) >> 16;
    return (short)r;
}
__device__ __forceinline__ float b2f(short s) {
    return __uint_as_float(((unsigned)(unsigned short)s) << 16);
}
// HW packed convert: bits[15:0]=bf16(a), bits[31:16]=bf16(b), RNE.
__device__ __forceinline__ unsigned cvt_pk(float a, float b) {
    unsigned r;
    asm("v_cvt_pk_bf16_f32 %0, %1, %2" : "=v"(r) : "v"(a), "v"(b));
    return r;
}

// ---------------------------------------------------------------------------
// Weight conversion (unchanged).
// ---------------------------------------------------------------------------
__global__ __launch_bounds__(256) void k_wconv(
    const float* __restrict__ W1, const float* __restrict__ W2,
    const float* __restrict__ W3,
    const float* __restrict__ Wt0, const float* __restrict__ Wt1,
    const float* __restrict__ Wt2, const float* __restrict__ Wt3,
    const float* __restrict__ Wt4, const float* __restrict__ Wt5,
    short* __restrict__ W1b, short* __restrict__ W2b, short* __restrict__ W3b,
    short* __restrict__ WtPh, short* __restrict__ WtPl,
    short* __restrict__ WtFh, short* __restrict__ WtFl)
{
    const int i = blockIdx.x * 256 + threadIdx.x;
    if (i < 8192) {                       // layer1: ct<8, kb<2, K_in=34
        const int j = i & 7, lane = (i >> 3) & 63;
        const int kb = (i >> 9) & 1, ct = i >> 10;
        const int n = ct * 16 + (lane & 15);
        const int k = kb * 32 + (lane >> 4) * 8 + j;
        W1b[i] = (k < 34) ? f2b(W1[n * 34 + k]) : (short)0;
        return;
    }
    int j2 = i - 8192;
    if (j2 < 32768) {                     // layer2: ct<16, kb<4, K_in=128
        const int j = j2 & 7, lane = (j2 >> 3) & 63;
        const int kb = (j2 >> 9) & 3, ct = j2 >> 11;
        const int n = ct * 16 + (lane & 15);
        const int k = kb * 32 + (lane >> 4) * 8 + j;
        W2b[j2] = f2b(W2[n * 128 + k]);
        return;
    }
    j2 -= 32768;
    if (j2 < 98304) {                     // layer3: ct<24, kb<8, K_in=256
        const int j = j2 & 7, lane = (j2 >> 3) & 63;
        const int kb = (j2 >> 9) & 7, ct = j2 >> 12;
        const int n = ct * 16 + (lane & 15);
        const int k = kb * 32 + (lane >> 4) * 8 + j;
        W3b[j2] = f2b(W3[n * 256 + k]);
        return;
    }
    j2 -= 98304;
    if (j2 < 6 * 16384) {
        const int m = j2 >> 14, idx = j2 & 16383;
        const float* src = (m == 0) ? Wt0 : (m == 1) ? Wt1 : (m == 2) ? Wt2
                         : (m == 3) ? Wt3 : (m == 4) ? Wt4 : Wt5;
        const float w = src[idx];
        const short hi = f2b(w);
        const short lo = f2b(w - b2f(hi));
        if (m < 3) { WtPh[m * 16384 + idx] = hi; WtPl[m * 16384 + idx] = lo; }
        else       { WtFh[(m - 3) * 16384 + idx] = hi; WtFl[(m - 3) * 16384 + idx] = lo; }
    }
}

// ---------------------------------------------------------------------------
// k_mix<FIN, WB>: channel-mix MFMA GEMM, hi/lo split.  NOW 512 threads /
// 8 waves: each wave owns ONE 16-wide output slice (o = wid*16 + ...), so
// the 72KB-LDS block hosts 16 waves/CU instead of 8.
// ---------------------------------------------------------------------------
template <bool FIN, bool WB>
__global__ __launch_bounds__(512, 4) void k_mix(
    const float* __restrict__ X,
    const float* __restrict__ Yin, const float* __restrict__ MSGin,
    const short* __restrict__ Wh,  const short* __restrict__ Wl,
    float* __restrict__ outp, short* __restrict__ ybf)
{
    extern __shared__ __align__(16) char smem[];   // 73728 B
    short* sBh = (short*)smem;                     // [144][128] bf16 hi
    short* sBl = sBh + 144 * 128;                  // [144][128] bf16 lo
    float* sC  = (float*)smem;                     // [144][128] f32 (after GEMM)

    const int tid = threadIdx.x;
    const int n0  = blockIdx.x * 16;

#pragma unroll 2
    for (int i = 0; i < 4; i++) {
        const int p  = i * 512 + tid;
        const int nl = p >> 7, h = p & 127;
        float dec[9];
        if constexpr (!FIN) {
            const float* t = X + ((size_t)((n0 + nl) * HD + h)) * 9;
            float T[9];
#pragma unroll
            for (int q = 0; q < 9; q++) T[q] = t[q];
            float nrm = 0.f;
#pragma unroll
            for (int q = 0; q < 9; q++) nrm = fmaf(T[q], T[q], nrm);
            const float inv = 1.0f / (nrm + 1.0f);
#pragma unroll
            for (int q = 0; q < 9; q++) T[q] *= inv;
            const float I = (T[0] + T[4] + T[8]) * (1.0f / 3.0f);
            dec[0] = I;
            dec[1] = 0.5f * (T[7] - T[5]);
            dec[2] = 0.5f * (T[2] - T[6]);
            dec[3] = 0.5f * (T[3] - T[1]);
            dec[4] = T[0] - I;
            dec[5] = 0.5f * (T[1] + T[3]);
            dec[6] = 0.5f * (T[2] + T[6]);
            dec[7] = T[4] - I;
            dec[8] = 0.5f * (T[5] + T[7]);
        } else {
            const int basep = (n0 + nl) * HD + h;
            float yv[9], mv[9];
#pragma unroll
            for (int c = 0; c < 9; c++) {
                yv[c] = Yin[(size_t)c * NH + basep];
                mv[c] = MSGin[(size_t)c * NH + basep];
            }
            float Yt[9], G[9];
            {
                const float I = yv[0], a0 = yv[1], a1 = yv[2], a2 = yv[3];
                const float s00 = yv[4], s01 = yv[5], s02 = yv[6], s11 = yv[7], s12 = yv[8];
                const float s22 = -s00 - s11;
                Yt[0] = I + s00; Yt[1] = s01 - a2; Yt[2] = s02 + a1;
                Yt[3] = s01 + a2; Yt[4] = I + s11; Yt[5] = s12 - a0;
                Yt[6] = s02 - a1; Yt[7] = s12 + a0; Yt[8] = I + s22;
            }
            {
                const float I = mv[0], a0 = mv[1], a1 = mv[2], a2 = mv[3];
                const float s00 = mv[4], s01 = mv[5], s02 = mv[6], s11 = mv[7], s12 = mv[8];
                const float s22 = -s00 - s11;
                G[0] = I + s00; G[1] = s01 - a2; G[2] = s02 + a1;
                G[3] = s01 + a2; G[4] = I + s11; G[5] = s12 - a0;
                G[6] = s02 - a1; G[7] = s12 + a0; G[8] = I + s22;
            }
            float M[9];
#pragma unroll
            for (int r = 0; r < 3; r++)
#pragma unroll
                for (int cc = 0; cc < 3; cc++) {
                    float a = 0.f;
#pragma unroll
                    for (int k = 0; k < 3; k++)
                        a += G[r * 3 + k] * Yt[k * 3 + cc]
                           + Yt[r * 3 + k] * G[k * 3 + cc];
                    M[r * 3 + cc] = a;
                }
            const float I2 = (M[0] + M[4] + M[8]) * (1.0f / 3.0f);
            const float a0 = 0.5f * (M[7] - M[5]);
            const float a1 = 0.5f * (M[2] - M[6]);
            const float a2 = 0.5f * (M[3] - M[1]);
            const float s00 = M[0] - I2, s11 = M[4] - I2;
            const float s01 = 0.5f * (M[1] + M[3]);
            const float s02 = 0.5f * (M[2] + M[6]);
            const float s12 = 0.5f * (M[5] + M[7]);
            const float s22 = -s00 - s11;
            const float nrm = 2.f * (a0 * a0 + a1 * a1 + a2 * a2)
                            + (s00 * s00 + s11 * s11 + s22 * s22)
                            + 2.f * (s01 * s01 + s02 * s02 + s12 * s12)
                            + 3.f * I2 * I2;
            const float inv = 1.0f / (nrm + 1.0f);
            dec[0] = I2 * inv;  dec[1] = a0 * inv;  dec[2] = a1 * inv;
            dec[3] = a2 * inv;  dec[4] = s00 * inv; dec[5] = s01 * inv;
            dec[6] = s02 * inv; dec[7] = s11 * inv; dec[8] = s12 * inv;
        }
        const int sw = (nl & 7) << 3;
        const int hx = h ^ sw;
#pragma unroll
        for (int c = 0; c < 9; c++) {
            const float v  = dec[c];
            const short hi = f2b(v);
            const short lo = f2b(v - b2f(hi));
            const int idx = (c * 16 + nl) * 128 + hx;
            sBh[idx] = hi;
            sBl[idx] = lo;
        }
    }
    __syncthreads();

    const int lane = tid & 63, wid = tid >> 6;   // wid 0..7
    const int l15 = lane & 15, g = lane >> 4;
    f32x4_t acc[9];
#pragma unroll
    for (int c = 0; c < 9; c++) acc[c] = {0.f, 0.f, 0.f, 0.f};

    const int bsw = (l15 & 7) << 3;
    const int o   = wid * 16 + l15;
#pragma unroll
    for (int k = 0; k < 4; k++) {
        const int k0  = k * 32 + g * 8;
        const int ksw = k0 ^ bsw;
#pragma unroll
        for (int w = 0; w < 3; w++) {
            const size_t aoff = (size_t)w * 16384 + (size_t)o * 128 + k0;
            const short8_t Ah = *(const short8_t*)(Wh + aoff);
            const short8_t Al = *(const short8_t*)(Wl + aoff);
            const int ct0 = (w == 0) ? 0 : (w == 1 ? 1 : 4);
            const int ctn = (w == 0) ? 1 : (w == 1 ? 3 : 5);
            for (int cc = 0; cc < ctn; cc++) {
                const int ct = ct0 + cc;
                const int boff = (ct * 16 + l15) * 128 + ksw;
                const short8_t Bh = *(const short8_t*)&sBh[boff];
                const short8_t Bl = *(const short8_t*)&sBl[boff];
                acc[ct] = __builtin_amdgcn_mfma_f32_16x16x32_bf16(Al, Bh, acc[ct], 0, 0, 0);
                acc[ct] = __builtin_amdgcn_mfma_f32_16x16x32_bf16(Ah, Bl, acc[ct], 0, 0, 0);
                acc[ct] = __builtin_amdgcn_mfma_f32_16x16x32_bf16(Ah, Bh, acc[ct], 0, 0, 0);
            }
        }
    }
    __syncthreads();

    const int csw = (l15 & 7) << 2;
    {
        const int o0 = wid * 16 + g * 4;
#pragma unroll
        for (int ct = 0; ct < 9; ct++)
            *(f32x4_t*)&sC[(ct * 16 + l15) * 128 + (o0 ^ csw)] = acc[ct];
    }
    __syncthreads();

    if constexpr (!FIN) {
        for (int i = tid; i < 144 * 32; i += 512) {
            const int row = i >> 5, q = i & 31;
            const int c = row >> 4, nl = row & 15;
            const int sw = (nl & 7) << 2;
            const f32x4_t v = *(const f32x4_t*)&sC[row * 128 + ((q * 4) ^ sw)];
            const size_t oo = (size_t)c * NH + (size_t)(n0 + nl) * HD + q * 4;
            *(f32x4_t*)&outp[oo] = v;
            if constexpr (WB) {
                uint2 u;
                u.x = cvt_pk(v[0], v[1]);
                u.y = cvt_pk(v[2], v[3]);
                *(uint2*)&ybf[oo] = u;
            }
        }
    } else {
#pragma unroll 2
        for (int i = 0; i < 4; i++) {
            const int p  = i * 512 + tid;
            const int nl = p >> 7, oo = p & 127;
            const int sw = (nl & 7) << 2;
            const int ox = oo ^ sw;
            float a9[9];
#pragma unroll
            for (int c = 0; c < 9; c++) a9[c] = sC[(c * 16 + nl) * 128 + ox];
            float D[9];
            {
                const float I = a9[0], a0 = a9[1], a1 = a9[2], a2 = a9[3];
                const float s00 = a9[4], s01 = a9[5], s02 = a9[6];
                const float s11 = a9[7], s12 = a9[8];
                const float s22 = -s00 - s11;
                D[0] = I + s00; D[1] = s01 - a2; D[2] = s02 + a1;
                D[3] = s01 + a2; D[4] = I + s11; D[5] = s12 - a0;
                D[6] = s02 - a1; D[7] = s12 + a0; D[8] = I + s22;
            }
            const size_t xbase = ((size_t)((n0 + nl) * HD + oo)) * 9;
            float T[9];
#pragma unroll
            for (int q = 0; q < 9; q++) T[q] = X[xbase + q];
            float nrm = 0.f;
#pragma unroll
            for (int q = 0; q < 9; q++) nrm = fmaf(T[q], T[q], nrm);
            const float inv = 1.0f / (nrm + 1.0f);
            float* op = outp + xbase;
#pragma unroll
            for (int r = 0; r < 3; r++)
#pragma unroll
                for (int cc = 0; cc < 3; cc++) {
                    float dd2 = 0.f;
#pragma unroll
                    for (int k = 0; k < 3; k++)
                        dd2 = fmaf(D[r * 3 + k], D[k * 3 + cc], dd2);
                    op[r * 3 + cc] = T[r * 3 + cc] * inv + D[r * 3 + cc] + dd2;
                }
        }
    }
}

// ---------------------------------------------------------------------------
// CSR build.
// ---------------------------------------------------------------------------
__global__ __launch_bounds__(256) void k_count(const int* __restrict__ EI,
                                               int* __restrict__ cnt)
{
    const int e = blockIdx.x * 256 + threadIdx.x;
    atomicAdd(&cnt[EI[e]], 1);
}

__global__ __launch_bounds__(256) void k_scan(const int* __restrict__ cnt,
                                              int* __restrict__ offs,
                                              int* __restrict__ cur)
{
    __shared__ int part[256];
    const int tid = threadIdx.x;
    const int per = (NN + 255) / 256;
    int s = 0;
    for (int i = 0; i < per; i++) {
        const int idx = tid * per + i;
        if (idx < NN) s += cnt[idx];
    }
    part[tid] = s;
    __syncthreads();
    if (tid == 0) {
        int r = 0;
        for (int i = 0; i < 256; i++) { const int t = part[i]; part[i] = r; r += t; }
        offs[NN] = r;
    }
    __syncthreads();
    int run = part[tid];
    for (int i = 0; i < per; i++) {
        const int idx = tid * per + i;
        if (idx < NN) {
            offs[idx] = run;
            cur[idx]  = run;
            run += cnt[idx];
        }
    }
}

__global__ __launch_bounds__(256) void k_fill(const int* __restrict__ EI,
                                              int* __restrict__ cur,
                                              int* __restrict__ EIDS,
                                              int* __restrict__ DSTS)
{
    const int e = blockIdx.x * 256 + threadIdx.x;
    const int s = EI[e];
    const int pos = atomicAdd(&cur[s], 1);
    EIDS[pos] = e;
    DSTS[pos] = EI[EE + e];
}

// ---------------------------------------------------------------------------
// Kernel 2: MFMA edge MLP, NOW 512 threads / 8 waves, ct-partitioned:
// same 48.5 KB LDS hosts 2x the waves (16/CU).  Swapped-operand MFMA,
// vectorized uint2 epilogues (round-7 structure).
// ---------------------------------------------------------------------------
__global__ __launch_bounds__(512, 4) void k_edge_mfma(
    const float* __restrict__ EA, const float* __restrict__ CH,
    const float* __restrict__ EW, const int*   __restrict__ EI,
    const short* __restrict__ W1b, const float* __restrict__ b1,
    const short* __restrict__ W2b, const float* __restrict__ b2,
    const short* __restrict__ W3b, const float* __restrict__ b3,
    short* __restrict__ XC)
{
    __shared__ __align__(16) short sH2[64 * 256];   // 32 KB; first 8 KB = sIn
    __shared__ __align__(16) short sH1[64 * 128];   // 16 KB
    __shared__ float sCut[64];

    short* sIn = sH2;                               // [64][64] alias
    const int tid = threadIdx.x;                    // 0..511
    const int e0  = blockIdx.x * 64;

    {   // zero-fill sIn (512 int4 = 8 KB)
        int4_t z = {0, 0, 0, 0};
        ((int4_t*)sIn)[tid] = z;
    }
    __syncthreads();
    {   // stage edge_attr + charges (bf16, (e&7)<<3 swizzle) + cutoff
        const float4 v = ((const float4*)(EA + (size_t)e0 * RD))[tid];
        const int e = tid >> 3;
        const int k = (tid & 7) * 4;
        short4 sv;
        sv.x = f2b(v.x); sv.y = f2b(v.y); sv.z = f2b(v.z); sv.w = f2b(v.w);
        *(short4*)&sIn[e * 64 + (k ^ ((e & 7) << 3))] = sv;
        if (tid < 64) {
            const int ee = tid;
            const int s = EI[e0 + ee];
            const int d = EI[EE + e0 + ee];
            const int sw = (ee & 7) << 3;
            sIn[ee * 64 + (32 ^ sw)] = f2b(CH[s]);
            sIn[ee * 64 + (33 ^ sw)] = f2b(CH[d]);
            const float w = EW[e0 + ee];
            sCut[ee] = (w < 5.0f)
                     ? 0.5f * (__cosf(0.62831853071795864769f * w) + 1.0f) : 0.0f;
        }
    }
    __syncthreads();

    const int lane = tid & 63;
    const int wid  = tid >> 6;          // 0..7
    const int l15  = lane & 15;
    const int g    = lane >> 4;
    const int fsw  = l15 << 3;          // feature-XOR for stores (edge = ..+l15)

    // ---- layer 1: 64 edges @ W1 (64->128); wave does ct = wid ----
    {
        short8_t E1[4][2];
#pragma unroll
        for (int at = 0; at < 4; at++) {
            const int row = at * 16 + l15;
            const int x = (row & 7) << 3;
            E1[at][0] = *(const short8_t*)&sIn[row * 64 + ((g * 8) ^ x)];
            E1[at][1] = *(const short8_t*)&sIn[row * 64 + ((32 + g * 8) ^ x)];
        }
        const int ct = wid;
        const float4 b4 = *(const float4*)&b1[ct * 16 + g * 4];
        const short8_t av0 = *(const short8_t*)(W1b + (size_t)((ct * 2 + 0) * 64 + lane) * 8);
        const short8_t av1 = *(const short8_t*)(W1b + (size_t)((ct * 2 + 1) * 64 + lane) * 8);
        const int fcol = ct * 16 + g * 4;
#pragma unroll
        for (int at = 0; at < 4; at++) {
            f32x4_t acc = {b4.x, b4.y, b4.z, b4.w};
            acc = __builtin_amdgcn_mfma_f32_16x16x32_bf16(av0, E1[at][0], acc, 0, 0, 0);
            acc = __builtin_amdgcn_mfma_f32_16x16x32_bf16(av1, E1[at][1], acc, 0, 0, 0);
            const int edge = at * 16 + l15;
            uint2 u;
            u.x = cvt_pk(silu_f(acc[0]), silu_f(acc[1]));
            u.y = cvt_pk(silu_f(acc[2]), silu_f(acc[3]));
            *(uint2*)&sH1[edge * 128 + (fcol ^ fsw)] = u;
        }
    }
    __syncthreads();

    // ---- layer 2: @ W2 (128->256); wave does cts {wid, wid+8} ----
    {
        short8_t E2[4][4];
#pragma unroll
        for (int at = 0; at < 4; at++) {
            const int row = at * 16 + l15;
            const int x = (row & 15) << 3;
#pragma unroll
            for (int kb = 0; kb < 4; kb++)
                E2[at][kb] = *(const short8_t*)&sH1[row * 128 + ((kb * 32 + g * 8) ^ x)];
        }
#pragma unroll
        for (int c = 0; c < 2; c++) {
            const int ct = c * 8 + wid;
            const float4 b4 = *(const float4*)&b2[ct * 16 + g * 4];
            const int fcol = ct * 16 + g * 4;
            f32x4_t acc[4];
#pragma unroll
            for (int at = 0; at < 4; at++) acc[at] = {b4.x, b4.y, b4.z, b4.w};
#pragma unroll
            for (int kb = 0; kb < 4; kb++) {
                const short8_t av = *(const short8_t*)(W2b + (size_t)((ct * 4 + kb) * 64 + lane) * 8);
#pragma unroll
                for (int at = 0; at < 4; at++)
                    acc[at] = __builtin_amdgcn_mfma_f32_16x16x32_bf16(av, E2[at][kb], acc[at], 0, 0, 0);
            }
#pragma unroll
            for (int at = 0; at < 4; at++) {
                const int edge = at * 16 + l15;
                uint2 u;
                u.x = cvt_pk(silu_f(acc[at][0]), silu_f(acc[at][1]));
                u.y = cvt_pk(silu_f(acc[at][2]), silu_f(acc[at][3]));
                *(uint2*)&sH2[edge * 256 + (fcol ^ fsw)] = u;
            }
        }
    }
    __syncthreads();

    // ---- layer 3: @ W3 (256->384); wave does cts {wid, wid+8, wid+16} ----
    {
        short8_t E3[4][8];
#pragma unroll
        for (int at = 0; at < 4; at++) {
            const int row = at * 16 + l15;
            const int x = (row & 15) << 3;
#pragma unroll
            for (int kb = 0; kb < 8; kb++)
                E3[at][kb] = *(const short8_t*)&sH2[row * 256 + ((kb * 32 + g * 8) ^ x)];
        }
        float cut[4];
#pragma unroll
        for (int at = 0; at < 4; at++) cut[at] = sCut[at * 16 + l15];
        for (int c = 0; c < 3; c++) {
            const int ct = c * 8 + wid;
            const float4 b4 = *(const float4*)&b3[ct * 16 + g * 4];
            const int fcol = ct * 16 + g * 4;
            f32x4_t acc[4];
#pragma unroll
            for (int at = 0; at < 4; at++) acc[at] = {b4.x, b4.y, b4.z, b4.w};
#pragma unroll
            for (int kb = 0; kb < 8; kb++) {
                const short8_t av = *(const short8_t*)(W3b + (size_t)((ct * 8 + kb) * 64 + lane) * 8);
#pragma unroll
                for (int at = 0; at < 4; at++)
                    acc[at] = __builtin_amdgcn_mfma_f32_16x16x32_bf16(av, E3[at][kb], acc[at], 0, 0, 0);
            }
#pragma unroll
            for (int at = 0; at < 4; at++) {
                const int edge = at * 16 + l15;
                const float cv = cut[at];
                uint2 u;
                u.x = cvt_pk(silu_f(acc[at][0]) * cv, silu_f(acc[at][1]) * cv);
                u.y = cvt_pk(silu_f(acc[at][2]) * cv, silu_f(acc[at][3]) * cv);
                *(uint2*)&XC[(size_t)(e0 + edge) * 384 + fcol] = u;
            }
        }
    }
}

// ---------------------------------------------------------------------------
// Fallback (small ws): fused VALU edge MLP + atomic scatter.
// ---------------------------------------------------------------------------
__global__ __launch_bounds__(256) void k_edge_atomic(
    const float* __restrict__ EA, const float* __restrict__ CH,
    const float* __restrict__ EW, const int*   __restrict__ EI,
    const float* __restrict__ W1, const float* __restrict__ b1,
    const float* __restrict__ W2, const float* __restrict__ b2,
    const float* __restrict__ W3, const float* __restrict__ b3,
    const float* __restrict__ Y,  float* __restrict__ MSG)
{
    __shared__ __align__(16) float sInf[32 * 35];
    __shared__ __align__(16) float sH1f[32 * 132];
    __shared__ __align__(16) float sH2f[32 * 260];
    __shared__ __align__(16) float sXcf[32 * 132];
    __shared__ float sCc[32];
    __shared__ int   sS[32], sD[32];

    const int e0  = blockIdx.x * 32;
    const int tid = threadIdx.x;

    {
        const float4 v = ((const float4*)(EA + (size_t)e0 * RD))[tid];
        const int e = tid >> 3;
        const int k = (tid & 7) * 4;
        float* p = sInf + e * 35 + k;
        p[0] = v.x; p[1] = v.y; p[2] = v.z; p[3] = v.w;
    }
    if (tid < 32) {
        const int e = tid;
        const int s = EI[e0 + e];
        const int d = EI[EE + e0 + e];
        sS[e] = s; sD[e] = d;
        sInf[e * 35 + 32] = CH[s];
        sInf[e * 35 + 33] = CH[d];
        const float w = EW[e0 + e];
        sCc[e] = (w < 5.0f) ? 0.5f * (__cosf(0.62831853071795864769f * w) + 1.0f)
                            : 0.0f;
    }
    __syncthreads();

    const int e  = tid & 31;
    const int og = tid >> 5;

    {
        float acc[16];
#pragma unroll
        for (int j = 0; j < 16; j++) acc[j] = b1[og * 16 + j];
        for (int k = 0; k < 34; k++) {
            const float v = sInf[e * 35 + k];
#pragma unroll
            for (int j = 0; j < 16; j++)
                acc[j] = fmaf(v, W1[(og * 16 + j) * 34 + k], acc[j]);
        }
#pragma unroll
        for (int j = 0; j < 16; j++)
            sH1f[e * 132 + og * 16 + j] = silu_f(acc[j]);
    }
    __syncthreads();

    {
        float acc[32];
#pragma unroll
        for (int j = 0; j < 32; j++) acc[j] = b2[og * 32 + j];
        for (int hq = 0; hq < 32; hq++) {
            const float4 v = *(const float4*)&sH1f[e * 132 + hq * 4];
#pragma unroll
            for (int j = 0; j < 32; j++) {
                const float4 w =
                    *(const float4*)&W2[(size_t)(og * 32 + j) * 128 + hq * 4];
                acc[j] = fmaf(v.x, w.x, fmaf(v.y, w.y,
                         fmaf(v.z, w.z, fmaf(v.w, w.w, acc[j]))));
            }
        }
#pragma unroll
        for (int j = 0; j < 32; j++)
            sH2f[e * 260 + og * 32 + j] = silu_f(acc[j]);
    }
    __syncthreads();

    for (int c = 0; c < 3; c++) {
        {
            float acc[16];
#pragma unroll
            for (int j = 0; j < 16; j++) acc[j] = b3[c * 128 + og * 16 + j];
            for (int hq = 0; hq < 64; hq++) {
                const float4 v = *(const float4*)&sH2f[e * 260 + hq * 4];
#pragma unroll
                for (int j = 0; j < 16; j++) {
                    const float4 w = *(const float4*)
                        &W3[(size_t)(c * 128 + og * 16 + j) * 256 + hq * 4];
                    acc[j] = fmaf(v.x, w.x, fmaf(v.y, w.y,
                             fmaf(v.z, w.z, fmaf(v.w, w.w, acc[j]))));
                }
            }
            const float cc = sCc[e];
#pragma unroll
            for (int j = 0; j < 16; j++)
                sXcf[e * 132 + og * 16 + j] = silu_f(acc[j]) * cc;
        }
        __syncthreads();
        {
            const int h  = tid & 127;
            const int eh = tid >> 7;
#pragma unroll 4
            for (int i = 0; i < 16; i++) {
                const int ee = (eh << 4) | i;
                const int s = sS[ee], d = sD[ee];
                const float xv = sXcf[ee * 132 + h];
                const int sb = s * HD + h, db = d * HD + h;
                if (c == 0) {
                    atomicAdd(&MSG[0 * (size_t)NH + sb], xv * Y[0 * (size_t)NH + db]);
                } else if (c == 1) {
#pragma unroll
                    for (int cc2 = 1; cc2 < 4; cc2++)
                        atomicAdd(&MSG[(size_t)cc2 * NH + sb],
                                  xv * Y[(size_t)cc2 * NH + db]);
                } else {
#pragma unroll
                    for (int cc2 = 4; cc2 < 9; cc2++)
                        atomicAdd(&MSG[(size_t)cc2 * NH + sb],
                                  xv * Y[(size_t)cc2 * NH + db]);
                }
            }
        }
        __syncthreads();
    }
}

// ---------------------------------------------------------------------------
// Kernel 2b: node-major gather.  YT = short (bf16 planes) or float.
// ---------------------------------------------------------------------------
__device__ __forceinline__ float ldy(const float* p) { return *p; }
__device__ __forceinline__ float ldy(const short* p) { return b2f(*p); }

template <typename YT>
__global__ __launch_bounds__(256) void k_gather(
    const short* __restrict__ XC, const YT* __restrict__ Y,
    const int* __restrict__ offs, const int* __restrict__ EIDS,
    const int* __restrict__ DSTS, float* __restrict__ MSG)
{
    const int tid = threadIdx.x;
    const int nl  = tid >> 7, h = tid & 127;
    const int n   = blockIdx.x * 2 + nl;
    const int beg = offs[n], end = offs[n + 1];

    float m[9];
#pragma unroll
    for (int c = 0; c < 9; c++) m[c] = 0.f;

    for (int p = beg; p < end; ++p) {
        const int eid = EIDS[p];
        const int dst = DSTS[p];
        const size_t xb = (size_t)eid * 384;
        const float x0 = b2f(XC[xb + h]);
        const float x1 = b2f(XC[xb + 128 + h]);
        const float x2 = b2f(XC[xb + 256 + h]);
        const int yb = dst * HD + h;
        m[0] = fmaf(x0, ldy(Y + 0 * (size_t)NH + yb), m[0]);
        m[1] = fmaf(x1, ldy(Y + 1 * (size_t)NH + yb), m[1]);
        m[2] = fmaf(x1, ldy(Y + 2 * (size_t)NH + yb), m[2]);
        m[3] = fmaf(x1, ldy(Y + 3 * (size_t)NH + yb), m[3]);
        m[4] = fmaf(x2, ldy(Y + 4 * (size_t)NH + yb), m[4]);
        m[5] = fmaf(x2, ldy(Y + 5 * (size_t)NH + yb), m[5]);
        m[6] = fmaf(x2, ldy(Y + 6 * (size_t)NH + yb), m[6]);
        m[7] = fmaf(x2, ldy(Y + 7 * (size_t)NH + yb), m[7]);
        m[8] = fmaf(x2, ldy(Y + 8 * (size_t)NH + yb), m[8]);
    }
    const int base = n * HD + h;
#pragma unroll
    for (int c = 0; c < 9; c++) MSG[(size_t)c * NH + base] = m[c];
}

// ---------------------------------------------------------------------------
static inline size_t align_up(size_t v, size_t a) { return (v + a - 1) & ~(a - 1); }

extern "C" void kernel_launch(void* const* d_in, const int* in_sizes, int n_in,
                              void* d_out, int out_size, void* d_ws, size_t ws_size,
                              hipStream_t stream)
{
    const float* X   = (const float*)d_in[0];
    const float* CH  = (const float*)d_in[1];
    const float* EA  = (const float*)d_in[2];
    const float* EW  = (const float*)d_in[3];
    const float* W1  = (const float*)d_in[4];
    const float* b1  = (const float*)d_in[5];
    const float* W2  = (const float*)d_in[6];
    const float* b2  = (const float*)d_in[7];
    const float* W3  = (const float*)d_in[8];
    const float* b3  = (const float*)d_in[9];
    const float* Wt0 = (const float*)d_in[10];
    const float* Wt1 = (const float*)d_in[11];
    const float* Wt2 = (const float*)d_in[12];
    const float* Wt3 = (const float*)d_in[13];
    const float* Wt4 = (const float*)d_in[14];
    const float* Wt5 = (const float*)d_in[15];
    const int*   EI  = (const int*)d_in[16];
    float* out = (float*)d_out;

    size_t off = 0;
    float* Y    = (float*)((char*)d_ws + off); off = align_up(off + (size_t)9 * NH * 4, 64);
    float* MSG  = (float*)((char*)d_ws + off); off = align_up(off + (size_t)9 * NH * 4, 64);
    int*   cnt  = (int*)((char*)d_ws + off);   off = align_up(off + (size_t)NN * 4, 64);
    int*   cur  = (int*)((char*)d_ws + off);   off = align_up(off + (size_t)NN * 4, 64);
    int*   offs = (int*)((char*)d_ws + off);   off = align_up(off + (size_t)(NN + 1) * 4, 64);
    int*   EIDS = (int*)((char*)d_ws + off);   off = align_up(off + (size_t)EE * 4, 64);
    int*   DSTS = (int*)((char*)d_ws + off);   off = align_up(off + (size_t)EE * 4, 64);
    short* W1b  = (short*)((char*)d_ws + off); off = align_up(off + (size_t)8192 * 2, 64);
    short* W2b  = (short*)((char*)d_ws + off); off = align_up(off + (size_t)32768 * 2, 64);
    short* W3b  = (short*)((char*)d_ws + off); off = align_up(off + (size_t)98304 * 2, 64);
    short* WtPh = (short*)((char*)d_ws + off); off = align_up(off + (size_t)3 * 16384 * 2, 64);
    short* WtPl = (short*)((char*)d_ws + off); off = align_up(off + (size_t)3 * 16384 * 2, 64);
    short* WtFh = (short*)((char*)d_ws + off); off = align_up(off + (size_t)3 * 16384 * 2, 64);
    short* WtFl = (short*)((char*)d_ws + off); off = align_up(off + (size_t)3 * 16384 * 2, 64);
    short* XC   = (short*)((char*)d_ws + off); off = align_up(off + (size_t)EE * 384 * 2, 64);
    const size_t need_plain = off;
    short* Ybf  = (short*)((char*)d_ws + off); off = align_up(off + (size_t)9 * NH * 2, 64);
    const size_t need_ybf = off;

    k_wconv<<<928, 256, 0, stream>>>(W1, W2, W3, Wt0, Wt1, Wt2, Wt3, Wt4, Wt5,
                                     W1b, W2b, W3b, WtPh, WtPl, WtFh, WtFl);

    if (ws_size >= need_plain) {
        const bool use_ybf = (ws_size >= need_ybf);
        if (use_ybf)
            k_mix<false, true><<<NN / 16, 512, 73728, stream>>>(
                X, Y, Y, WtPh, WtPl, Y, Ybf);
        else
            k_mix<false, false><<<NN / 16, 512, 73728, stream>>>(
                X, Y, Y, WtPh, WtPl, Y, nullptr);

        hipMemsetAsync(cnt, 0, (size_t)NN * sizeof(int), stream);
        k_count<<<EE / 256, 256, 0, stream>>>(EI, cnt);
        k_scan<<<1, 256, 0, stream>>>(cnt, offs, cur);
        k_fill<<<EE / 256, 256, 0, stream>>>(EI, cur, EIDS, DSTS);
        k_edge_mfma<<<EE / 64, 512, 0, stream>>>(EA, CH, EW, EI,
                                                 W1b, b1, W2b, b2, W3b, b3, XC);
        if (use_ybf)
            k_gather<short><<<NN / 2, 256, 0, stream>>>(XC, Ybf, offs, EIDS, DSTS, MSG);
        else
            k_gather<float><<<NN / 2, 256, 0, stream>>>(XC, Y, offs, EIDS, DSTS, MSG);
    } else {
        k_mix<false, false><<<NN / 16, 512, 73728, stream>>>(
            X, Y, Y, WtPh, WtPl, Y, nullptr);
        hipMemsetAsync(MSG, 0, (size_t)9 * NH * sizeof(float), stream);
        k_edge_atomic<<<EE / 32, 256, 0, stream>>>(EA, CH, EW, EI,
                                                   W1, b1, W2, b2, W3, b3, Y, MSG);
    }

    k_mix<true, false><<<NN / 16, 512, 73728, stream>>>(X, Y, MSG, WtFh, WtFl, out, nullptr);
}

// Round 10
// 305.361 us; speedup vs baseline: 25.9831x; 1.0031x over previous
//
#include <hip/hip_runtime.h>

#define NN  10000
#define HD  128
#define EE  160000
#define RD  32
#define NH  (NN * HD)

typedef __attribute__((ext_vector_type(8))) short short8_t;
typedef __attribute__((ext_vector_type(4))) float f32x4_t;
typedef __attribute__((ext_vector_type(4))) int   int4_t;

// fast silu: v_rcp_f32 (~1ulp) instead of exact-div sequence
__device__ __forceinline__ float silu_f(float z) {
    return z * __builtin_amdgcn_rcpf(1.0f + __expf(-z));
}
__device__ __forceinline__ short f2b(float v) {   // RNE fp32->bf16
    unsigned u = __float_as_uint(v);
    unsigned r = (u + 0x7FFFu + ((u >> 16) & 1u)) >> 16;
    return (short)r;
}
__device__ __forceinline__ float b2f(short s) {
    return __uint_as_float(((unsigned)(unsigned short)s) << 16);
}
// HW packed convert: bits[15:0]=bf16(a), bits[31:16]=bf16(b), RNE.
__device__ __forceinline__ unsigned cvt_pk(float a, float b) {
    unsigned r;
    asm("v_cvt_pk_bf16_f32 %0, %1, %2" : "=v"(r) : "v"(a), "v"(b));
    return r;
}

// ---------------------------------------------------------------------------
// Weight conversion (unchanged).
// ---------------------------------------------------------------------------
__global__ __launch_bounds__(256) void k_wconv(
    const float* __restrict__ W1, const float* __restrict__ W2,
    const float* __restrict__ W3,
    const float* __restrict__ Wt0, const float* __restrict__ Wt1,
    const float* __restrict__ Wt2, const float* __restrict__ Wt3,
    const float* __restrict__ Wt4, const float* __restrict__ Wt5,
    short* __restrict__ W1b, short* __restrict__ W2b, short* __restrict__ W3b,
    short* __restrict__ WtPh, short* __restrict__ WtPl,
    short* __restrict__ WtFh, short* __restrict__ WtFl)
{
    const int i = blockIdx.x * 256 + threadIdx.x;
    if (i < 8192) {                       // layer1: ct<8, kb<2, K_in=34
        const int j = i & 7, lane = (i >> 3) & 63;
        const int kb = (i >> 9) & 1, ct = i >> 10;
        const int n = ct * 16 + (lane & 15);
        const int k = kb * 32 + (lane >> 4) * 8 + j;
        W1b[i] = (k < 34) ? f2b(W1[n * 34 + k]) : (short)0;
        return;
    }
    int j2 = i - 8192;
    if (j2 < 32768) {                     // layer2: ct<16, kb<4, K_in=128
        const int j = j2 & 7, lane = (j2 >> 3) & 63;
        const int kb = (j2 >> 9) & 3, ct = j2 >> 11;
        const int n = ct * 16 + (lane & 15);
        const int k = kb * 32 + (lane >> 4) * 8 + j;
        W2b[j2] = f2b(W2[n * 128 + k]);
        return;
    }
    j2 -= 32768;
    if (j2 < 98304) {                     // layer3: ct<24, kb<8, K_in=256
        const int j = j2 & 7, lane = (j2 >> 3) & 63;
        const int kb = (j2 >> 9) & 7, ct = j2 >> 12;
        const int n = ct * 16 + (lane & 15);
        const int k = kb * 32 + (lane >> 4) * 8 + j;
        W3b[j2] = f2b(W3[n * 256 + k]);
        return;
    }
    j2 -= 98304;
    if (j2 < 6 * 16384) {
        const int m = j2 >> 14, idx = j2 & 16383;
        const float* src = (m == 0) ? Wt0 : (m == 1) ? Wt1 : (m == 2) ? Wt2
                         : (m == 3) ? Wt3 : (m == 4) ? Wt4 : Wt5;
        const float w = src[idx];
        const short hi = f2b(w);
        const short lo = f2b(w - b2f(hi));
        if (m < 3) { WtPh[m * 16384 + idx] = hi; WtPl[m * 16384 + idx] = lo; }
        else       { WtFh[(m - 3) * 16384 + idx] = hi; WtFl[(m - 3) * 16384 + idx] = lo; }
    }
}

__device__ __forceinline__ float ldy(const float* p) { return *p; }
__device__ __forceinline__ float ldy(const short* p) { return b2f(*p); }

// ---------------------------------------------------------------------------
// k_mix<FIN, WB, MT>: channel-mix MFMA GEMM, hi/lo split. 512 threads/8 waves.
// MT: type of MSGin planes (float or bf16-as-short).
// ---------------------------------------------------------------------------
template <bool FIN, bool WB, typename MT>
__global__ __launch_bounds__(512, 4) void k_mix(
    const float* __restrict__ X,
    const float* __restrict__ Yin, const MT* __restrict__ MSGin,
    const short* __restrict__ Wh,  const short* __restrict__ Wl,
    float* __restrict__ outp, short* __restrict__ ybf)
{
    extern __shared__ __align__(16) char smem[];   // 73728 B
    short* sBh = (short*)smem;                     // [144][128] bf16 hi
    short* sBl = sBh + 144 * 128;                  // [144][128] bf16 lo
    float* sC  = (float*)smem;                     // [144][128] f32 (after GEMM)

    const int tid = threadIdx.x;
    const int n0  = blockIdx.x * 16;

#pragma unroll 2
    for (int i = 0; i < 4; i++) {
        const int p  = i * 512 + tid;
        const int nl = p >> 7, h = p & 127;
        float dec[9];
        if constexpr (!FIN) {
            const float* t = X + ((size_t)((n0 + nl) * HD + h)) * 9;
            float T[9];
#pragma unroll
            for (int q = 0; q < 9; q++) T[q] = t[q];
            float nrm = 0.f;
#pragma unroll
            for (int q = 0; q < 9; q++) nrm = fmaf(T[q], T[q], nrm);
            const float inv = 1.0f / (nrm + 1.0f);
#pragma unroll
            for (int q = 0; q < 9; q++) T[q] *= inv;
            const float I = (T[0] + T[4] + T[8]) * (1.0f / 3.0f);
            dec[0] = I;
            dec[1] = 0.5f * (T[7] - T[5]);
            dec[2] = 0.5f * (T[2] - T[6]);
            dec[3] = 0.5f * (T[3] - T[1]);
            dec[4] = T[0] - I;
            dec[5] = 0.5f * (T[1] + T[3]);
            dec[6] = 0.5f * (T[2] + T[6]);
            dec[7] = T[4] - I;
            dec[8] = 0.5f * (T[5] + T[7]);
        } else {
            const int basep = (n0 + nl) * HD + h;
            float yv[9], mv[9];
#pragma unroll
            for (int c = 0; c < 9; c++) {
                yv[c] = Yin[(size_t)c * NH + basep];
                mv[c] = ldy(MSGin + (size_t)c * NH + basep);
            }
            float Yt[9], G[9];
            {
                const float I = yv[0], a0 = yv[1], a1 = yv[2], a2 = yv[3];
                const float s00 = yv[4], s01 = yv[5], s02 = yv[6], s11 = yv[7], s12 = yv[8];
                const float s22 = -s00 - s11;
                Yt[0] = I + s00; Yt[1] = s01 - a2; Yt[2] = s02 + a1;
                Yt[3] = s01 + a2; Yt[4] = I + s11; Yt[5] = s12 - a0;
                Yt[6] = s02 - a1; Yt[7] = s12 + a0; Yt[8] = I + s22;
            }
            {
                const float I = mv[0], a0 = mv[1], a1 = mv[2], a2 = mv[3];
                const float s00 = mv[4], s01 = mv[5], s02 = mv[6], s11 = mv[7], s12 = mv[8];
                const float s22 = -s00 - s11;
                G[0] = I + s00; G[1] = s01 - a2; G[2] = s02 + a1;
                G[3] = s01 + a2; G[4] = I + s11; G[5] = s12 - a0;
                G[6] = s02 - a1; G[7] = s12 + a0; G[8] = I + s22;
            }
            float M[9];
#pragma unroll
            for (int r = 0; r < 3; r++)
#pragma unroll
                for (int cc = 0; cc < 3; cc++) {
                    float a = 0.f;
#pragma unroll
                    for (int k = 0; k < 3; k++)
                        a += G[r * 3 + k] * Yt[k * 3 + cc]
                           + Yt[r * 3 + k] * G[k * 3 + cc];
                    M[r * 3 + cc] = a;
                }
            const float I2 = (M[0] + M[4] + M[8]) * (1.0f / 3.0f);
            const float a0 = 0.5f * (M[7] - M[5]);
            const float a1 = 0.5f * (M[2] - M[6]);
            const float a2 = 0.5f * (M[3] - M[1]);
            const float s00 = M[0] - I2, s11 = M[4] - I2;
            const float s01 = 0.5f * (M[1] + M[3]);
            const float s02 = 0.5f * (M[2] + M[6]);
            const float s12 = 0.5f * (M[5] + M[7]);
            const float s22 = -s00 - s11;
            const float nrm = 2.f * (a0 * a0 + a1 * a1 + a2 * a2)
                            + (s00 * s00 + s11 * s11 + s22 * s22)
                            + 2.f * (s01 * s01 + s02 * s02 + s12 * s12)
                            + 3.f * I2 * I2;
            const float inv = 1.0f / (nrm + 1.0f);
            dec[0] = I2 * inv;  dec[1] = a0 * inv;  dec[2] = a1 * inv;
            dec[3] = a2 * inv;  dec[4] = s00 * inv; dec[5] = s01 * inv;
            dec[6] = s02 * inv; dec[7] = s11 * inv; dec[8] = s12 * inv;
        }
        const int sw = (nl & 7) << 3;
        const int hx = h ^ sw;
#pragma unroll
        for (int c = 0; c < 9; c++) {
            const float v  = dec[c];
            const short hi = f2b(v);
            const short lo = f2b(v - b2f(hi));
            const int idx = (c * 16 + nl) * 128 + hx;
            sBh[idx] = hi;
            sBl[idx] = lo;
        }
    }
    __syncthreads();

    const int lane = tid & 63, wid = tid >> 6;   // wid 0..7
    const int l15 = lane & 15, g = lane >> 4;
    f32x4_t acc[9];
#pragma unroll
    for (int c = 0; c < 9; c++) acc[c] = {0.f, 0.f, 0.f, 0.f};

    const int bsw = (l15 & 7) << 3;
    const int o   = wid * 16 + l15;
#pragma unroll
    for (int k = 0; k < 4; k++) {
        const int k0  = k * 32 + g * 8;
        const int ksw = k0 ^ bsw;
#pragma unroll
        for (int w = 0; w < 3; w++) {
            const size_t aoff = (size_t)w * 16384 + (size_t)o * 128 + k0;
            const short8_t Ah = *(const short8_t*)(Wh + aoff);
            const short8_t Al = *(const short8_t*)(Wl + aoff);
            const int ct0 = (w == 0) ? 0 : (w == 1 ? 1 : 4);
            const int ctn = (w == 0) ? 1 : (w == 1 ? 3 : 5);
            for (int cc = 0; cc < ctn; cc++) {
                const int ct = ct0 + cc;
                const int boff = (ct * 16 + l15) * 128 + ksw;
                const short8_t Bh = *(const short8_t*)&sBh[boff];
                const short8_t Bl = *(const short8_t*)&sBl[boff];
                acc[ct] = __builtin_amdgcn_mfma_f32_16x16x32_bf16(Al, Bh, acc[ct], 0, 0, 0);
                acc[ct] = __builtin_amdgcn_mfma_f32_16x16x32_bf16(Ah, Bl, acc[ct], 0, 0, 0);
                acc[ct] = __builtin_amdgcn_mfma_f32_16x16x32_bf16(Ah, Bh, acc[ct], 0, 0, 0);
            }
        }
    }
    __syncthreads();

    const int csw = (l15 & 7) << 2;
    {
        const int o0 = wid * 16 + g * 4;
#pragma unroll
        for (int ct = 0; ct < 9; ct++)
            *(f32x4_t*)&sC[(ct * 16 + l15) * 128 + (o0 ^ csw)] = acc[ct];
    }
    __syncthreads();

    if constexpr (!FIN) {
        for (int i = tid; i < 144 * 32; i += 512) {
            const int row = i >> 5, q = i & 31;
            const int c = row >> 4, nl = row & 15;
            const int sw = (nl & 7) << 2;
            const f32x4_t v = *(const f32x4_t*)&sC[row * 128 + ((q * 4) ^ sw)];
            const size_t oo = (size_t)c * NH + (size_t)(n0 + nl) * HD + q * 4;
            *(f32x4_t*)&outp[oo] = v;
            if constexpr (WB) {
                uint2 u;
                u.x = cvt_pk(v[0], v[1]);
                u.y = cvt_pk(v[2], v[3]);
                *(uint2*)&ybf[oo] = u;
            }
        }
    } else {
#pragma unroll 2
        for (int i = 0; i < 4; i++) {
            const int p  = i * 512 + tid;
            const int nl = p >> 7, oo = p & 127;
            const int sw = (nl & 7) << 2;
            const int ox = oo ^ sw;
            float a9[9];
#pragma unroll
            for (int c = 0; c < 9; c++) a9[c] = sC[(c * 16 + nl) * 128 + ox];
            float D[9];
            {
                const float I = a9[0], a0 = a9[1], a1 = a9[2], a2 = a9[3];
                const float s00 = a9[4], s01 = a9[5], s02 = a9[6];
                const float s11 = a9[7], s12 = a9[8];
                const float s22 = -s00 - s11;
                D[0] = I + s00; D[1] = s01 - a2; D[2] = s02 + a1;
                D[3] = s01 + a2; D[4] = I + s11; D[5] = s12 - a0;
                D[6] = s02 - a1; D[7] = s12 + a0; D[8] = I + s22;
            }
            const size_t xbase = ((size_t)((n0 + nl) * HD + oo)) * 9;
            float T[9];
#pragma unroll
            for (int q = 0; q < 9; q++) T[q] = X[xbase + q];
            float nrm = 0.f;
#pragma unroll
            for (int q = 0; q < 9; q++) nrm = fmaf(T[q], T[q], nrm);
            const float inv = 1.0f / (nrm + 1.0f);
            float* op = outp + xbase;
#pragma unroll
            for (int r = 0; r < 3; r++)
#pragma unroll
                for (int cc = 0; cc < 3; cc++) {
                    float dd2 = 0.f;
#pragma unroll
                    for (int k = 0; k < 3; k++)
                        dd2 = fmaf(D[r * 3 + k], D[k * 3 + cc], dd2);
                    op[r * 3 + cc] = T[r * 3 + cc] * inv + D[r * 3 + cc] + dd2;
                }
        }
    }
}

// ---------------------------------------------------------------------------
// CSR build.  k_fill also records PERM[e] = CSR position of edge e.
// ---------------------------------------------------------------------------
__global__ __launch_bounds__(256) void k_count(const int* __restrict__ EI,
                                               int* __restrict__ cnt)
{
    const int e = blockIdx.x * 256 + threadIdx.x;
    atomicAdd(&cnt[EI[e]], 1);
}

__global__ __launch_bounds__(256) void k_scan(const int* __restrict__ cnt,
                                              int* __restrict__ offs,
                                              int* __restrict__ cur)
{
    __shared__ int part[256];
    const int tid = threadIdx.x;
    const int per = (NN + 255) / 256;
    int s = 0;
    for (int i = 0; i < per; i++) {
        const int idx = tid * per + i;
        if (idx < NN) s += cnt[idx];
    }
    part[tid] = s;
    __syncthreads();
    if (tid == 0) {
        int r = 0;
        for (int i = 0; i < 256; i++) { const int t = part[i]; part[i] = r; r += t; }
        offs[NN] = r;
    }
    __syncthreads();
    int run = part[tid];
    for (int i = 0; i < per; i++) {
        const int idx = tid * per + i;
        if (idx < NN) {
            offs[idx] = run;
            cur[idx]  = run;
            run += cnt[idx];
        }
    }
}

__global__ __launch_bounds__(256) void k_fill(const int* __restrict__ EI,
                                              int* __restrict__ cur,
                                              int* __restrict__ PERM,
                                              int* __restrict__ DSTS)
{
    const int e = blockIdx.x * 256 + threadIdx.x;
    const int s = EI[e];
    const int pos = atomicAdd(&cur[s], 1);
    PERM[e] = pos;
    DSTS[pos] = EI[EE + e];
}

// ---------------------------------------------------------------------------
// Kernel 2: MFMA edge MLP (512 threads / 8 waves, swapped operands).
// Writes edge e's output to XC row PERM[e] (CSR position) so the gather
// reads XC sequentially.
// ---------------------------------------------------------------------------
__global__ __launch_bounds__(512, 4) void k_edge_mfma(
    const float* __restrict__ EA, const float* __restrict__ CH,
    const float* __restrict__ EW, const int*   __restrict__ EI,
    const int*   __restrict__ PERM,
    const short* __restrict__ W1b, const float* __restrict__ b1,
    const short* __restrict__ W2b, const float* __restrict__ b2,
    const short* __restrict__ W3b, const float* __restrict__ b3,
    short* __restrict__ XC)
{
    __shared__ __align__(16) short sH2[64 * 256];   // 32 KB; first 8 KB = sIn
    __shared__ __align__(16) short sH1[64 * 128];   // 16 KB
    __shared__ float sCut[64];
    __shared__ int   sPerm[64];

    short* sIn = sH2;                               // [64][64] alias
    const int tid = threadIdx.x;                    // 0..511
    const int e0  = blockIdx.x * 64;

    {   // zero-fill sIn (512 int4 = 8 KB)
        int4_t z = {0, 0, 0, 0};
        ((int4_t*)sIn)[tid] = z;
    }
    __syncthreads();
    {   // stage edge_attr + charges (bf16, (e&7)<<3 swizzle) + cutoff + perm
        const float4 v = ((const float4*)(EA + (size_t)e0 * RD))[tid];
        const int e = tid >> 3;
        const int k = (tid & 7) * 4;
        short4 sv;
        sv.x = f2b(v.x); sv.y = f2b(v.y); sv.z = f2b(v.z); sv.w = f2b(v.w);
        *(short4*)&sIn[e * 64 + (k ^ ((e & 7) << 3))] = sv;
        if (tid < 64) {
            const int ee = tid;
            const int s = EI[e0 + ee];
            const int d = EI[EE + e0 + ee];
            const int sw = (ee & 7) << 3;
            sIn[ee * 64 + (32 ^ sw)] = f2b(CH[s]);
            sIn[ee * 64 + (33 ^ sw)] = f2b(CH[d]);
            const float w = EW[e0 + ee];
            sCut[ee] = (w < 5.0f)
                     ? 0.5f * (__cosf(0.62831853071795864769f * w) + 1.0f) : 0.0f;
            sPerm[ee] = PERM[e0 + ee];
        }
    }
    __syncthreads();

    const int lane = tid & 63;
    const int wid  = tid >> 6;          // 0..7
    const int l15  = lane & 15;
    const int g    = lane >> 4;
    const int fsw  = l15 << 3;          // feature-XOR for LDS stores

    // ---- layer 1: 64 edges @ W1 (64->128); wave does ct = wid ----
    {
        short8_t E1[4][2];
#pragma unroll
        for (int at = 0; at < 4; at++) {
            const int row = at * 16 + l15;
            const int x = (row & 7) << 3;
            E1[at][0] = *(const short8_t*)&sIn[row * 64 + ((g * 8) ^ x)];
            E1[at][1] = *(const short8_t*)&sIn[row * 64 + ((32 + g * 8) ^ x)];
        }
        const int ct = wid;
        const float4 b4 = *(const float4*)&b1[ct * 16 + g * 4];
        const short8_t av0 = *(const short8_t*)(W1b + (size_t)((ct * 2 + 0) * 64 + lane) * 8);
        const short8_t av1 = *(const short8_t*)(W1b + (size_t)((ct * 2 + 1) * 64 + lane) * 8);
        const int fcol = ct * 16 + g * 4;
#pragma unroll
        for (int at = 0; at < 4; at++) {
            f32x4_t acc = {b4.x, b4.y, b4.z, b4.w};
            acc = __builtin_amdgcn_mfma_f32_16x16x32_bf16(av0, E1[at][0], acc, 0, 0, 0);
            acc = __builtin_amdgcn_mfma_f32_16x16x32_bf16(av1, E1[at][1], acc, 0, 0, 0);
            const int edge = at * 16 + l15;
            uint2 u;
            u.x = cvt_pk(silu_f(acc[0]), silu_f(acc[1]));
            u.y = cvt_pk(silu_f(acc[2]), silu_f(acc[3]));
            *(uint2*)&sH1[edge * 128 + (fcol ^ fsw)] = u;
        }
    }
    __syncthreads();

    // ---- layer 2: @ W2 (128->256); wave does cts {wid, wid+8} ----
    {
        short8_t E2[4][4];
#pragma unroll
        for (int at = 0; at < 4; at++) {
            const int row = at * 16 + l15;
            const int x = (row & 15) << 3;
#pragma unroll
            for (int kb = 0; kb < 4; kb++)
                E2[at][kb] = *(const short8_t*)&sH1[row * 128 + ((kb * 32 + g * 8) ^ x)];
        }
#pragma unroll
        for (int c = 0; c < 2; c++) {
            const int ct = c * 8 + wid;
            const float4 b4 = *(const float4*)&b2[ct * 16 + g * 4];
            const int fcol = ct * 16 + g * 4;
            f32x4_t acc[4];
#pragma unroll
            for (int at = 0; at < 4; at++) acc[at] = {b4.x, b4.y, b4.z, b4.w};
#pragma unroll
            for (int kb = 0; kb < 4; kb++) {
                const short8_t av = *(const short8_t*)(W2b + (size_t)((ct * 4 + kb) * 64 + lane) * 8);
#pragma unroll
                for (int at = 0; at < 4; at++)
                    acc[at] = __builtin_amdgcn_mfma_f32_16x16x32_bf16(av, E2[at][kb], acc[at], 0, 0, 0);
            }
#pragma unroll
            for (int at = 0; at < 4; at++) {
                const int edge = at * 16 + l15;
                uint2 u;
                u.x = cvt_pk(silu_f(acc[at][0]), silu_f(acc[at][1]));
                u.y = cvt_pk(silu_f(acc[at][2]), silu_f(acc[at][3]));
                *(uint2*)&sH2[edge * 256 + (fcol ^ fsw)] = u;
            }
        }
    }
    __syncthreads();

    // ---- layer 3: @ W3 (256->384); wave does cts {wid, wid+8, wid+16} ----
    {
        short8_t E3[4][8];
#pragma unroll
        for (int at = 0; at < 4; at++) {
            const int row = at * 16 + l15;
            const int x = (row & 15) << 3;
#pragma unroll
            for (int kb = 0; kb < 8; kb++)
                E3[at][kb] = *(const short8_t*)&sH2[row * 256 + ((kb * 32 + g * 8) ^ x)];
        }
        float cut[4];
        int   prm[4];
#pragma unroll
        for (int at = 0; at < 4; at++) {
            cut[at] = sCut[at * 16 + l15];
            prm[at] = sPerm[at * 16 + l15];
        }
        for (int c = 0; c < 3; c++) {
            const int ct = c * 8 + wid;
            const float4 b4 = *(const float4*)&b3[ct * 16 + g * 4];
            const int fcol = ct * 16 + g * 4;
            f32x4_t acc[4];
#pragma unroll
            for (int at = 0; at < 4; at++) acc[at] = {b4.x, b4.y, b4.z, b4.w};
#pragma unroll
            for (int kb = 0; kb < 8; kb++) {
                const short8_t av = *(const short8_t*)(W3b + (size_t)((ct * 8 + kb) * 64 + lane) * 8);
#pragma unroll
                for (int at = 0; at < 4; at++)
                    acc[at] = __builtin_amdgcn_mfma_f32_16x16x32_bf16(av, E3[at][kb], acc[at], 0, 0, 0);
            }
#pragma unroll
            for (int at = 0; at < 4; at++) {
                const float cv = cut[at];
                uint2 u;
                u.x = cvt_pk(silu_f(acc[at][0]) * cv, silu_f(acc[at][1]) * cv);
                u.y = cvt_pk(silu_f(acc[at][2]) * cv, silu_f(acc[at][3]) * cv);
                *(uint2*)&XC[(size_t)prm[at] * 384 + fcol] = u;
            }
        }
    }
}

// ---------------------------------------------------------------------------
// Fallback (small ws): fused VALU edge MLP + atomic scatter (fp32 MSG).
// ---------------------------------------------------------------------------
__global__ __launch_bounds__(256) void k_edge_atomic(
    const float* __restrict__ EA, const float* __restrict__ CH,
    const float* __restrict__ EW, const int*   __restrict__ EI,
    const float* __restrict__ W1, const float* __restrict__ b1,
    const float* __restrict__ W2, const float* __restrict__ b2,
    const float* __restrict__ W3, const float* __restrict__ b3,
    const float* __restrict__ Y,  float* __restrict__ MSG)
{
    __shared__ __align__(16) float sInf[32 * 35];
    __shared__ __align__(16) float sH1f[32 * 132];
    __shared__ __align__(16) float sH2f[32 * 260];
    __shared__ __align__(16) float sXcf[32 * 132];
    __shared__ float sCc[32];
    __shared__ int   sS[32], sD[32];

    const int e0  = blockIdx.x * 32;
    const int tid = threadIdx.x;

    {
        const float4 v = ((const float4*)(EA + (size_t)e0 * RD))[tid];
        const int e = tid >> 3;
        const int k = (tid & 7) * 4;
        float* p = sInf + e * 35 + k;
        p[0] = v.x; p[1] = v.y; p[2] = v.z; p[3] = v.w;
    }
    if (tid < 32) {
        const int e = tid;
        const int s = EI[e0 + e];
        const int d = EI[EE + e0 + e];
        sS[e] = s; sD[e] = d;
        sInf[e * 35 + 32] = CH[s];
        sInf[e * 35 + 33] = CH[d];
        const float w = EW[e0 + e];
        sCc[e] = (w < 5.0f) ? 0.5f * (__cosf(0.62831853071795864769f * w) + 1.0f)
                            : 0.0f;
    }
    __syncthreads();

    const int e  = tid & 31;
    const int og = tid >> 5;

    {
        float acc[16];
#pragma unroll
        for (int j = 0; j < 16; j++) acc[j] = b1[og * 16 + j];
        for (int k = 0; k < 34; k++) {
            const float v = sInf[e * 35 + k];
#pragma unroll
            for (int j = 0; j < 16; j++)
                acc[j] = fmaf(v, W1[(og * 16 + j) * 34 + k], acc[j]);
        }
#pragma unroll
        for (int j = 0; j < 16; j++)
            sH1f[e * 132 + og * 16 + j] = silu_f(acc[j]);
    }
    __syncthreads();

    {
        float acc[32];
#pragma unroll
        for (int j = 0; j < 32; j++) acc[j] = b2[og * 32 + j];
        for (int hq = 0; hq < 32; hq++) {
            const float4 v = *(const float4*)&sH1f[e * 132 + hq * 4];
#pragma unroll
            for (int j = 0; j < 32; j++) {
                const float4 w =
                    *(const float4*)&W2[(size_t)(og * 32 + j) * 128 + hq * 4];
                acc[j] = fmaf(v.x, w.x, fmaf(v.y, w.y,
                         fmaf(v.z, w.z, fmaf(v.w, w.w, acc[j]))));
            }
        }
#pragma unroll
        for (int j = 0; j < 32; j++)
            sH2f[e * 260 + og * 32 + j] = silu_f(acc[j]);
    }
    __syncthreads();

    for (int c = 0; c < 3; c++) {
        {
            float acc[16];
#pragma unroll
            for (int j = 0; j < 16; j++) acc[j] = b3[c * 128 + og * 16 + j];
            for (int hq = 0; hq < 64; hq++) {
                const float4 v = *(const float4*)&sH2f[e * 260 + hq * 4];
#pragma unroll
                for (int j = 0; j < 16; j++) {
                    const float4 w = *(const float4*)
                        &W3[(size_t)(c * 128 + og * 16 + j) * 256 + hq * 4];
                    acc[j] = fmaf(v.x, w.x, fmaf(v.y, w.y,
                             fmaf(v.z, w.z, fmaf(v.w, w.w, acc[j]))));
                }
            }
            const float cc = sCc[e];
#pragma unroll
            for (int j = 0; j < 16; j++)
                sXcf[e * 132 + og * 16 + j] = silu_f(acc[j]) * cc;
        }
        __syncthreads();
        {
            const int h  = tid & 127;
            const int eh = tid >> 7;
#pragma unroll 4
            for (int i = 0; i < 16; i++) {
                const int ee = (eh << 4) | i;
                const int s = sS[ee], d = sD[ee];
                const float xv = sXcf[ee * 132 + h];
                const int sb = s * HD + h, db = d * HD + h;
                if (c == 0) {
                    atomicAdd(&MSG[0 * (size_t)NH + sb], xv * Y[0 * (size_t)NH + db]);
                } else if (c == 1) {
#pragma unroll
                    for (int cc2 = 1; cc2 < 4; cc2++)
                        atomicAdd(&MSG[(size_t)cc2 * NH + sb],
                                  xv * Y[(size_t)cc2 * NH + db]);
                } else {
#pragma unroll
                    for (int cc2 = 4; cc2 < 9; cc2++)
                        atomicAdd(&MSG[(size_t)cc2 * NH + sb],
                                  xv * Y[(size_t)cc2 * NH + db]);
                }
            }
        }
        __syncthreads();
    }
}

// ---------------------------------------------------------------------------
// Kernel 2b: node-major gather.  XC now in CSR order -> sequential reads.
// Writes bf16 MSG planes.
// ---------------------------------------------------------------------------
__global__ __launch_bounds__(256) void k_gather(
    const short* __restrict__ XC, const short* __restrict__ Y,
    const int* __restrict__ offs, const int* __restrict__ DSTS,
    short* __restrict__ MSGb)
{
    const int tid = threadIdx.x;
    const int nl  = tid >> 7, h = tid & 127;
    const int n   = blockIdx.x * 2 + nl;
    const int beg = offs[n], end = offs[n + 1];

    float m[9];
#pragma unroll
    for (int c = 0; c < 9; c++) m[c] = 0.f;

    for (int p = beg; p < end; ++p) {
        const int dst = DSTS[p];
        const size_t xb = (size_t)p * 384;
        const float x0 = b2f(XC[xb + h]);
        const float x1 = b2f(XC[xb + 128 + h]);
        const float x2 = b2f(XC[xb + 256 + h]);
        const int yb = dst * HD + h;
        m[0] = fmaf(x0, b2f(Y[0 * (size_t)NH + yb]), m[0]);
        m[1] = fmaf(x1, b2f(Y[1 * (size_t)NH + yb]), m[1]);
        m[2] = fmaf(x1, b2f(Y[2 * (size_t)NH + yb]), m[2]);
        m[3] = fmaf(x1, b2f(Y[3 * (size_t)NH + yb]), m[3]);
        m[4] = fmaf(x2, b2f(Y[4 * (size_t)NH + yb]), m[4]);
        m[5] = fmaf(x2, b2f(Y[5 * (size_t)NH + yb]), m[5]);
        m[6] = fmaf(x2, b2f(Y[6 * (size_t)NH + yb]), m[6]);
        m[7] = fmaf(x2, b2f(Y[7 * (size_t)NH + yb]), m[7]);
        m[8] = fmaf(x2, b2f(Y[8 * (size_t)NH + yb]), m[8]);
    }
    const int base = n * HD + h;
#pragma unroll
    for (int c = 0; c < 9; c++) MSGb[(size_t)c * NH + base] = f2b(m[c]);
}

// ---------------------------------------------------------------------------
static inline size_t align_up(size_t v, size_t a) { return (v + a - 1) & ~(a - 1); }

extern "C" void kernel_launch(void* const* d_in, const int* in_sizes, int n_in,
                              void* d_out, int out_size, void* d_ws, size_t ws_size,
                              hipStream_t stream)
{
    const float* X   = (const float*)d_in[0];
    const float* CH  = (const float*)d_in[1];
    const float* EA  = (const float*)d_in[2];
    const float* EW  = (const float*)d_in[3];
    const float* W1  = (const float*)d_in[4];
    const float* b1  = (const float*)d_in[5];
    const float* W2  = (const float*)d_in[6];
    const float* b2  = (const float*)d_in[7];
    const float* W3  = (const float*)d_in[8];
    const float* b3  = (const float*)d_in[9];
    const float* Wt0 = (const float*)d_in[10];
    const float* Wt1 = (const float*)d_in[11];
    const float* Wt2 = (const float*)d_in[12];
    const float* Wt3 = (const float*)d_in[13];
    const float* Wt4 = (const float*)d_in[14];
    const float* Wt5 = (const float*)d_in[15];
    const int*   EI  = (const int*)d_in[16];
    float* out = (float*)d_out;

    size_t off = 0;
    float* Y    = (float*)((char*)d_ws + off); off = align_up(off + (size_t)9 * NH * 4, 64);
    float* MSG  = (float*)((char*)d_ws + off); off = align_up(off + (size_t)9 * NH * 4, 64);
    short* MSGb = (short*)MSG;   // alias: bf16 MSG planes (fast path only)
    int*   cnt  = (int*)((char*)d_ws + off);   off = align_up(off + (size_t)NN * 4, 64);
    int*   cur  = (int*)((char*)d_ws + off);   off = align_up(off + (size_t)NN * 4, 64);
    int*   offs = (int*)((char*)d_ws + off);   off = align_up(off + (size_t)(NN + 1) * 4, 64);
    int*   PERM = (int*)((char*)d_ws + off);   off = align_up(off + (size_t)EE * 4, 64);
    int*   DSTS = (int*)((char*)d_ws + off);   off = align_up(off + (size_t)EE * 4, 64);
    short* W1b  = (short*)((char*)d_ws + off); off = align_up(off + (size_t)8192 * 2, 64);
    short* W2b  = (short*)((char*)d_ws + off); off = align_up(off + (size_t)32768 * 2, 64);
    short* W3b  = (short*)((char*)d_ws + off); off = align_up(off + (size_t)98304 * 2, 64);
    short* WtPh = (short*)((char*)d_ws + off); off = align_up(off + (size_t)3 * 16384 * 2, 64);
    short* WtPl = (short*)((char*)d_ws + off); off = align_up(off + (size_t)3 * 16384 * 2, 64);
    short* WtFh = (short*)((char*)d_ws + off); off = align_up(off + (size_t)3 * 16384 * 2, 64);
    short* WtFl = (short*)((char*)d_ws + off); off = align_up(off + (size_t)3 * 16384 * 2, 64);
    short* XC   = (short*)((char*)d_ws + off); off = align_up(off + (size_t)EE * 384 * 2, 64);
    short* Ybf  = (short*)((char*)d_ws + off); off = align_up(off + (size_t)9 * NH * 2, 64);
    const size_t need_fast = off;

    k_wconv<<<928, 256, 0, stream>>>(W1, W2, W3, Wt0, Wt1, Wt2, Wt3, Wt4, Wt5,
                                     W1b, W2b, W3b, WtPh, WtPl, WtFh, WtFl);

    if (ws_size >= need_fast) {
        k_mix<false, true, float><<<NN / 16, 512, 73728, stream>>>(
            X, Y, Y, WtPh, WtPl, Y, Ybf);

        hipMemsetAsync(cnt, 0, (size_t)NN * sizeof(int), stream);
        k_count<<<EE / 256, 256, 0, stream>>>(EI, cnt);
        k_scan<<<1, 256, 0, stream>>>(cnt, offs, cur);
        k_fill<<<EE / 256, 256, 0, stream>>>(EI, cur, PERM, DSTS);
        k_edge_mfma<<<EE / 64, 512, 0, stream>>>(EA, CH, EW, EI, PERM,
                                                 W1b, b1, W2b, b2, W3b, b3, XC);
        k_gather<<<NN / 2, 256, 0, stream>>>(XC, Ybf, offs, DSTS, MSGb);

        k_mix<true, false, short><<<NN / 16, 512, 73728, stream>>>(
            X, Y, MSGb, WtFh, WtFl, out, nullptr);
    } else {
        k_mix<false, false, float><<<NN / 16, 512, 73728, stream>>>(
            X, Y, Y, WtPh, WtPl, Y, nullptr);
        hipMemsetAsync(MSG, 0, (size_t)9 * NH * sizeof(float), stream);
        k_edge_atomic<<<EE / 32, 256, 0, stream>>>(EA, CH, EW, EI,
                                                   W1, b1, W2, b2, W3, b3, Y, MSG);
        k_mix<true, false, float><<<NN / 16, 512, 73728, stream>>>(
            X, Y, MSG, WtFh, WtFl, out, nullptr);
    }
}